// Round 2
// baseline (1172.325 us; speedup 1.0000x reference)
//
#include <hip/hip_runtime.h>
#include <math.h>

#define NN 50000
#define NE 800000
#define FF 768
#define HH 256

typedef __attribute__((ext_vector_type(8))) short short8;
typedef __attribute__((ext_vector_type(4))) float f32x4;

__device__ inline unsigned short f2bf(float f) {
  unsigned u = __float_as_uint(f);
  u = u + 0x7fffu + ((u >> 16) & 1u);
  return (unsigned short)(u >> 16);
}
__device__ inline float bf2f(unsigned short b) {
  return __uint_as_float(((unsigned)b) << 16);
}

// ---------------- CSR build ----------------
__global__ void k_count(const int* __restrict__ dstv, int* __restrict__ deg) {
  int e = blockIdx.x * 256 + threadIdx.x;
  if (e < NE) atomicAdd(&deg[dstv[e]], 1);
}

// single-block thread-coarsened scan: 1024 threads x 49 elems
__global__ void k_scan(const int* __restrict__ deg, int* __restrict__ rowptr) {
  const int CH = 49;  // 1024*49 = 50176 >= NN
  int tid = threadIdx.x;
  int lane = tid & 63, w = tid >> 6;
  int base = tid * CH;
  int sum = 0;
  for (int i = 0; i < CH; i++) {
    int idx = base + i;
    if (idx < NN) sum += deg[idx];
  }
  int incl = sum;
  for (int off = 1; off < 64; off <<= 1) {
    int tv = __shfl_up(incl, off, 64);
    if (lane >= off) incl += tv;
  }
  __shared__ int ws[16];
  if (lane == 63) ws[w] = incl;
  __syncthreads();
  if (tid == 0) {
    int c = 0;
    for (int i = 0; i < 16; i++) { int tv = ws[i]; ws[i] = c; c += tv; }
  }
  __syncthreads();
  int run = ws[w] + (incl - sum);
  if (tid == 0) rowptr[0] = 0;
  for (int i = 0; i < CH; i++) {
    int idx = base + i;
    if (idx < NN) { run += deg[idx]; rowptr[idx + 1] = run; }
  }
}

__global__ void k_scatter(const int* __restrict__ srcv, const int* __restrict__ dstv,
                          int* __restrict__ cursor, int* __restrict__ csr_src) {
  int e = blockIdx.x * 256 + threadIdx.x;
  if (e < NE) {
    int d = dstv[e];
    int pos = atomicAdd(&cursor[d], 1);
    csr_src[pos] = srcv[e];
  }
}

// ------------- aggregation (bf16 gather): mb = bf16((1+eps)*hb + sum hb[src]) -------------
__global__ void k_agg(const unsigned short* __restrict__ hb, const int* __restrict__ rowptr,
                      const int* __restrict__ csr_src, const float* __restrict__ eps,
                      int layer, unsigned short* __restrict__ mb) {
  int node = (blockIdx.x * blockDim.x + threadIdx.x) >> 6;
  int lane = threadIdx.x & 63;
  if (node >= NN) return;
  int beg = rowptr[node], end = rowptr[node + 1];
  const ushort4* hv = (const ushort4*)hb;
  float ax = 0.f, ay = 0.f, az = 0.f, aw = 0.f;
  for (int e = beg; e < end; ++e) {
    int s = csr_src[e];
    ushort4 v = hv[(size_t)s * 64 + lane];
    ax += bf2f(v.x); ay += bf2f(v.y); az += bf2f(v.z); aw += bf2f(v.w);
  }
  float ep = 1.0f + eps[layer];
  ushort4 h0 = hv[(size_t)node * 64 + lane];
  ax += ep * bf2f(h0.x); ay += ep * bf2f(h0.y);
  az += ep * bf2f(h0.z); aw += ep * bf2f(h0.w);
  ushort4 o;
  o.x = f2bf(ax); o.y = f2bf(ay); o.z = f2bf(az); o.w = f2bf(aw);
  *(ushort4*)&mb[(size_t)node * 256 + lane * 4] = o;
}

// ------------- transpose + cast: dst[c][r] = bf16(src[r][c]), src is R x C, batched over z -------------
__global__ void k_tcast(const float* __restrict__ src0, unsigned short* __restrict__ dst0,
                        int R, int C) {
  const float* src = src0 + (size_t)blockIdx.z * R * C;
  unsigned short* dst = dst0 + (size_t)blockIdx.z * R * C;
  __shared__ float tile[32][33];
  int bx = blockIdx.x * 32, by = blockIdx.y * 32;
  int tx = threadIdx.x & 31, ty = threadIdx.x >> 5;  // 32 x 8
  for (int i = 0; i < 32; i += 8) {
    int r = by + ty + i, c = bx + tx;
    tile[ty + i][tx] = (r < R && c < C) ? src[(size_t)r * C + c] : 0.f;
  }
  __syncthreads();
  for (int i = 0; i < 32; i += 8) {
    int c = bx + ty + i, r = by + tx;
    if (c < C && r < R) dst[(size_t)c * R + r] = f2bf(tile[tx][ty + i]);
  }
}

// ---------------- input projection GEMM: K=768, fp32 A cast in staging ----------------
// Round-0 B-in-LDS structure + issue-early register prefetch of next chunk.
__global__ __launch_bounds__(256) void k_mmff0(
    const float* __restrict__ x, const unsigned short* __restrict__ Bt,
    const float* __restrict__ bias, float* __restrict__ outf,
    unsigned short* __restrict__ outb) {
  __shared__ unsigned short As[64 * 40];   // 64 rows x 32 k, padded to 40
  __shared__ unsigned short Bs[256 * 40];  // 256 n-rows x 32 k, padded to 40
  int t = threadIdx.x, lane = t & 63, wave = t >> 6;
  int row0 = blockIdx.x * 64;
  int m16 = lane & 15, kq = lane >> 4;
  f32x4 acc[4][4];
#pragma unroll
  for (int i = 0; i < 4; i++)
#pragma unroll
    for (int j = 0; j < 4; j++) acc[i][j] = (f32x4)(0.f);
  int arow = t >> 2, ac = t & 3;
  int agr = row0 + arow; if (agr >= NN) agr = NN - 1;
  // prefetch registers
  float4 pa0, pa1, pb[4];
  {
    const float* Af = x + (size_t)agr * FF + ac * 8;
    pa0 = *(const float4*)Af;
    pa1 = *(const float4*)(Af + 4);
#pragma unroll
    for (int it = 0; it < 4; it++) {
      int idx = t + it * 256;
      int br = idx >> 2, bc = idx & 3;
      pb[it] = *(const float4*)&Bt[(size_t)br * FF + bc * 8];
    }
  }
  for (int kc = 0; kc < 24; kc++) {
    // write staged regs to LDS
    short8 v;
    v[0] = (short)f2bf(pa0.x); v[1] = (short)f2bf(pa0.y);
    v[2] = (short)f2bf(pa0.z); v[3] = (short)f2bf(pa0.w);
    v[4] = (short)f2bf(pa1.x); v[5] = (short)f2bf(pa1.y);
    v[6] = (short)f2bf(pa1.z); v[7] = (short)f2bf(pa1.w);
    *(short8*)&As[arow * 40 + ac * 8] = v;
#pragma unroll
    for (int it = 0; it < 4; it++) {
      int idx = t + it * 256;
      int br = idx >> 2, bc = idx & 3;
      *(float4*)&Bs[br * 40 + bc * 8] = pb[it];
    }
    // issue next chunk loads (overlap with compute below)
    if (kc < 23) {
      int k0 = (kc + 1) * 32;
      const float* Af = x + (size_t)agr * FF + k0 + ac * 8;
      pa0 = *(const float4*)Af;
      pa1 = *(const float4*)(Af + 4);
#pragma unroll
      for (int it = 0; it < 4; it++) {
        int idx = t + it * 256;
        int br = idx >> 2, bc = idx & 3;
        pb[it] = *(const float4*)&Bt[(size_t)br * FF + k0 + bc * 8];
      }
    }
    __syncthreads();
    short8 a[4], b[4];
#pragma unroll
    for (int rt = 0; rt < 4; rt++) a[rt] = *(const short8*)&As[(rt * 16 + m16) * 40 + kq * 8];
#pragma unroll
    for (int ct = 0; ct < 4; ct++)
      b[ct] = *(const short8*)&Bs[(wave * 64 + ct * 16 + m16) * 40 + kq * 8];
#pragma unroll
    for (int rt = 0; rt < 4; rt++)
#pragma unroll
      for (int ct = 0; ct < 4; ct++)
        acc[rt][ct] = __builtin_amdgcn_mfma_f32_16x16x32_bf16(a[rt], b[ct], acc[rt][ct], 0, 0, 0);
    __syncthreads();
  }
  int colbase = wave * 64 + m16;
  float bv[4];
#pragma unroll
  for (int ct = 0; ct < 4; ct++) bv[ct] = bias[colbase + ct * 16];
#pragma unroll
  for (int rt = 0; rt < 4; rt++)
#pragma unroll
    for (int reg = 0; reg < 4; reg++) {
      int r = row0 + rt * 16 + kq * 4 + reg;
      if (r < NN) {
#pragma unroll
        for (int ct = 0; ct < 4; ct++) {
          float vv = acc[rt][ct][reg] + bv[ct];
          outf[(size_t)r * 256 + colbase + ct * 16] = vv;
          outb[(size_t)r * 256 + colbase + ct * 16] = f2bf(vv);
        }
      }
    }
}

// ---------------- shared K=256 GEMM loop: A-frags from T1 (padded 264), ----------------
// B staged per-32k-chunk into swizzled 16KB Bs, with issue-early prefetch.
// Swizzle: LDS[row][slot ^ ((row>>1)&3)] holds global slot (16B units); 2-way conflicts only.
__device__ __forceinline__ void gemm_k256(
    const unsigned short* __restrict__ Bt, const unsigned short* __restrict__ T1,
    unsigned short* __restrict__ Bs, f32x4 (&acc)[4][4],
    int t, int wave, int m16, int kq) {
  int r4 = t >> 2, slot = t & 3;
  float4 pf[4];
#pragma unroll
  for (int i = 0; i < 4; i++) {
    int row = i * 64 + r4;
    pf[i] = *(const float4*)&Bt[(size_t)row * 256 + slot * 8];
  }
#pragma unroll
  for (int kc = 0; kc < 8; kc++) {
#pragma unroll
    for (int i = 0; i < 4; i++) {
      int row = i * 64 + r4;
      int s2 = slot ^ ((row >> 1) & 3);
      *(float4*)((char*)Bs + row * 64 + s2 * 16) = pf[i];
    }
    if (kc < 7) {
#pragma unroll
      for (int i = 0; i < 4; i++) {
        int row = i * 64 + r4;
        pf[i] = *(const float4*)&Bt[(size_t)row * 256 + (kc + 1) * 32 + slot * 8];
      }
    }
    __syncthreads();
    short8 a[4], b[4];
#pragma unroll
    for (int rt = 0; rt < 4; rt++)
      a[rt] = *(const short8*)&T1[(rt * 16 + m16) * 264 + kc * 32 + kq * 8];
#pragma unroll
    for (int ct = 0; ct < 4; ct++) {
      int brow = wave * 64 + ct * 16 + m16;
      int s2 = kq ^ ((brow >> 1) & 3);
      b[ct] = *(const short8*)((const char*)Bs + brow * 64 + s2 * 16);
    }
#pragma unroll
    for (int rt = 0; rt < 4; rt++)
#pragma unroll
      for (int ct = 0; ct < 4; ct++)
        acc[rt][ct] = __builtin_amdgcn_mfma_f32_16x16x32_bf16(a[rt], b[ct], acc[rt][ct], 0, 0, 0);
    __syncthreads();
  }
}

// ---------------- fused GIN layer ----------------
// T1 <- A(mb1) ; GEMM1(W1)+bias+LN+ReLU -> T1 ; GEMM2(W2)+bias+LN+ReLU+resid -> h/hb
// if ATT: T1 <- bf16(h') ; 2 passes of GEMM3(attW1 half)+tanh.w2 reduce -> logitsT
template <bool WF, bool ATT>
__global__ __launch_bounds__(256) void k_fused(
    const unsigned short* __restrict__ Ab,
    const unsigned short* __restrict__ B1t, const float* __restrict__ bias1,
    const float* __restrict__ g1v, const float* __restrict__ be1,
    const unsigned short* __restrict__ B2t, const float* __restrict__ bias2,
    const float* __restrict__ g2v, const float* __restrict__ be2,
    const float* __restrict__ resid, float* __restrict__ outf,
    unsigned short* __restrict__ outb,
    const unsigned short* __restrict__ aW1T, const float* __restrict__ ab1,
    const float* __restrict__ aW2v, const float* __restrict__ ab2,
    float* __restrict__ logitsT) {
  __shared__ unsigned short T1[64 * 264];   // 33792 B : A / T1 / hb-tile
  __shared__ unsigned short Bs[256 * 32];   // 16384 B : swizzled B chunk
  __shared__ float redS[4][64];
  __shared__ float redQ[4][64];
  __shared__ float mvM[64], mvI[64];
  __shared__ float lg[4][64];
  int t = threadIdx.x, lane = t & 63, wave = t >> 6;
  int row0 = blockIdx.x * 64;
  int m16 = lane & 15, kq = lane >> 4;
  int colbase = wave * 64 + m16;

  // ---- stage A once into T1 ----
  {
    int sr = t >> 5, sc = (t & 31) * 8;
#pragma unroll
    for (int j = 0; j < 8; j++) {
      int rr = j * 8 + sr;
      int gr = row0 + rr; if (gr >= NN) gr = NN - 1;
      *(float4*)&T1[rr * 264 + sc] = *(const float4*)&Ab[(size_t)gr * 256 + sc];
    }
  }
  // (first barrier inside gemm_k256 orders these writes before any T1 read)

  f32x4 acc[4][4];
#pragma unroll
  for (int i = 0; i < 4; i++)
#pragma unroll
    for (int j = 0; j < 4; j++) acc[i][j] = (f32x4)(0.f);
  gemm_k256(B1t, T1, Bs, acc, t, wave, m16, kq);

  // ---- epilogue 1: bias + LN + ReLU -> T1 ----
  {
    float bv[4];
#pragma unroll
    for (int ct = 0; ct < 4; ct++) bv[ct] = bias1[colbase + ct * 16];
    float s[4][4], q[4][4];
#pragma unroll
    for (int rt = 0; rt < 4; rt++)
#pragma unroll
      for (int reg = 0; reg < 4; reg++) { s[rt][reg] = 0.f; q[rt][reg] = 0.f; }
#pragma unroll
    for (int rt = 0; rt < 4; rt++)
#pragma unroll
      for (int ct = 0; ct < 4; ct++)
#pragma unroll
        for (int reg = 0; reg < 4; reg++) {
          float v = acc[rt][ct][reg] + bv[ct];
          acc[rt][ct][reg] = v;
          s[rt][reg] += v;
          q[rt][reg] += v * v;
        }
#pragma unroll
    for (int off = 1; off < 16; off <<= 1) {
#pragma unroll
      for (int rt = 0; rt < 4; rt++)
#pragma unroll
        for (int reg = 0; reg < 4; reg++) {
          s[rt][reg] += __shfl_xor(s[rt][reg], off, 64);
          q[rt][reg] += __shfl_xor(q[rt][reg], off, 64);
        }
    }
    if (m16 == 0) {
#pragma unroll
      for (int rt = 0; rt < 4; rt++)
#pragma unroll
        for (int reg = 0; reg < 4; reg++) {
          redS[wave][rt * 16 + kq * 4 + reg] = s[rt][reg];
          redQ[wave][rt * 16 + kq * 4 + reg] = q[rt][reg];
        }
    }
    __syncthreads();
    if (t < 64) {
      float ss = redS[0][t] + redS[1][t] + redS[2][t] + redS[3][t];
      float qq = redQ[0][t] + redQ[1][t] + redQ[2][t] + redQ[3][t];
      float mean = ss * (1.f / 256.f);
      float var = qq * (1.f / 256.f) - mean * mean;
      mvM[t] = mean;
      mvI[t] = rsqrtf(var + 1e-5f);
    }
    __syncthreads();
    float gv[4], bev[4];
#pragma unroll
    for (int ct = 0; ct < 4; ct++) { gv[ct] = g1v[colbase + ct * 16]; bev[ct] = be1[colbase + ct * 16]; }
#pragma unroll
    for (int rt = 0; rt < 4; rt++)
#pragma unroll
      for (int reg = 0; reg < 4; reg++) {
        int rr = rt * 16 + kq * 4 + reg;
        float mean = mvM[rr], inv = mvI[rr];
#pragma unroll
        for (int ct = 0; ct < 4; ct++) {
          float val = fmaxf((acc[rt][ct][reg] - mean) * inv * gv[ct] + bev[ct], 0.f);
          T1[rr * 264 + colbase + ct * 16] = f2bf(val);
        }
      }
    __syncthreads();
  }

  // ---- GEMM2 ----
#pragma unroll
  for (int i = 0; i < 4; i++)
#pragma unroll
    for (int j = 0; j < 4; j++) acc[i][j] = (f32x4)(0.f);
  gemm_k256(B2t, T1, Bs, acc, t, wave, m16, kq);

  // ---- epilogue 2: bias + LN + ReLU + resid -> outf/outb (+T1 if ATT) ----
  {
    float bv[4];
#pragma unroll
    for (int ct = 0; ct < 4; ct++) bv[ct] = bias2[colbase + ct * 16];
    float s[4][4], q[4][4];
#pragma unroll
    for (int rt = 0; rt < 4; rt++)
#pragma unroll
      for (int reg = 0; reg < 4; reg++) { s[rt][reg] = 0.f; q[rt][reg] = 0.f; }
#pragma unroll
    for (int rt = 0; rt < 4; rt++)
#pragma unroll
      for (int ct = 0; ct < 4; ct++)
#pragma unroll
        for (int reg = 0; reg < 4; reg++) {
          float v = acc[rt][ct][reg] + bv[ct];
          acc[rt][ct][reg] = v;
          s[rt][reg] += v;
          q[rt][reg] += v * v;
        }
#pragma unroll
    for (int off = 1; off < 16; off <<= 1) {
#pragma unroll
      for (int rt = 0; rt < 4; rt++)
#pragma unroll
        for (int reg = 0; reg < 4; reg++) {
          s[rt][reg] += __shfl_xor(s[rt][reg], off, 64);
          q[rt][reg] += __shfl_xor(q[rt][reg], off, 64);
        }
    }
    if (m16 == 0) {
#pragma unroll
      for (int rt = 0; rt < 4; rt++)
#pragma unroll
        for (int reg = 0; reg < 4; reg++) {
          redS[wave][rt * 16 + kq * 4 + reg] = s[rt][reg];
          redQ[wave][rt * 16 + kq * 4 + reg] = q[rt][reg];
        }
    }
    __syncthreads();
    if (t < 64) {
      float ss = redS[0][t] + redS[1][t] + redS[2][t] + redS[3][t];
      float qq = redQ[0][t] + redQ[1][t] + redQ[2][t] + redQ[3][t];
      float mean = ss * (1.f / 256.f);
      float var = qq * (1.f / 256.f) - mean * mean;
      mvM[t] = mean;
      mvI[t] = rsqrtf(var + 1e-5f);
    }
    __syncthreads();
    float gv[4], bev[4];
#pragma unroll
    for (int ct = 0; ct < 4; ct++) { gv[ct] = g2v[colbase + ct * 16]; bev[ct] = be2[colbase + ct * 16]; }
#pragma unroll
    for (int rt = 0; rt < 4; rt++)
#pragma unroll
      for (int reg = 0; reg < 4; reg++) {
        int rr = rt * 16 + kq * 4 + reg;
        int r = row0 + rr;
        float mean = mvM[rr], inv = mvI[rr];
#pragma unroll
        for (int ct = 0; ct < 4; ct++) {
          int col = colbase + ct * 16;
          float val = fmaxf((acc[rt][ct][reg] - mean) * inv * gv[ct] + bev[ct], 0.f);
          float rv = (r < NN) ? resid[(size_t)r * 256 + col] : 0.f;
          val += rv;
          if (r < NN) {
            if (WF) outf[(size_t)r * 256 + col] = val;
            outb[(size_t)r * 256 + col] = f2bf(val);
          }
          if (ATT) T1[rr * 264 + col] = f2bf(val);
        }
      }
  }

  // ---- attention logits (layer 1 only) ----
  if (ATT) {
    ((float*)lg)[t] = 0.f;  // 4*64 = 256 cells
    // barriers inside gemm_k256 order T1 writes / lg zero before reads / adds
#pragma unroll
    for (int pass = 0; pass < 2; pass++) {
#pragma unroll
      for (int i = 0; i < 4; i++)
#pragma unroll
        for (int j = 0; j < 4; j++) acc[i][j] = (f32x4)(0.f);
      gemm_k256(aW1T + (size_t)pass * 256 * 256, T1, Bs, acc, t, wave, m16, kq);
      int head = pass * 2 + (wave >> 1);
      const float* b1k = ab1 + head * 128;
      const float* w2k = aW2v + head * 128;
      float p[4][4];
#pragma unroll
      for (int rt = 0; rt < 4; rt++)
#pragma unroll
        for (int reg = 0; reg < 4; reg++) p[rt][reg] = 0.f;
#pragma unroll
      for (int ct = 0; ct < 4; ct++) {
        int hcol = (wave & 1) * 64 + ct * 16 + m16;
        float b1v = b1k[hcol], w2v = w2k[hcol];
#pragma unroll
        for (int rt = 0; rt < 4; rt++)
#pragma unroll
          for (int reg = 0; reg < 4; reg++) {
            float xv = acc[rt][ct][reg] + b1v;
            xv = fminf(fmaxf(xv, -10.f), 10.f);
            float ex = __expf(2.f * xv);
            p[rt][reg] += (ex - 1.f) / (ex + 1.f) * w2v;
          }
      }
#pragma unroll
      for (int off = 1; off < 16; off <<= 1)
#pragma unroll
        for (int rt = 0; rt < 4; rt++)
#pragma unroll
          for (int reg = 0; reg < 4; reg++) p[rt][reg] += __shfl_xor(p[rt][reg], off, 64);
      if (m16 == 0) {
#pragma unroll
        for (int rt = 0; rt < 4; rt++)
#pragma unroll
          for (int reg = 0; reg < 4; reg++)
            atomicAdd(&lg[head][rt * 16 + kq * 4 + reg], p[rt][reg]);
      }
    }
    __syncthreads();
    int hh = t >> 6, rr2 = t & 63;
    int r = row0 + rr2;
    if (r < NN) logitsT[(size_t)hh * NN + r] = lg[hh][rr2] + ab2[hh];
  }
}

// ---------------- softmax over N per head ----------------
__global__ void k_smax1(const float* __restrict__ logitsT, float* __restrict__ pmax,
                        float* __restrict__ psum) {
  int k = blockIdx.y;
  int tid = threadIdx.x;
  const float* L = logitsT + (size_t)k * NN;
  __shared__ float sm[256];
  float mx = -1e30f;
  for (int i = blockIdx.x * 256 + tid; i < NN; i += 128 * 256) mx = fmaxf(mx, L[i]);
  sm[tid] = mx; __syncthreads();
  for (int o = 128; o >= 1; o >>= 1) { if (tid < o) sm[tid] = fmaxf(sm[tid], sm[tid + o]); __syncthreads(); }
  float bmax = sm[0];
  __syncthreads();
  float s = 0.f;
  for (int i = blockIdx.x * 256 + tid; i < NN; i += 128 * 256) s += __expf(L[i] - bmax);
  sm[tid] = s; __syncthreads();
  for (int o = 128; o >= 1; o >>= 1) { if (tid < o) sm[tid] += sm[tid + o]; __syncthreads(); }
  if (tid == 0) { pmax[k * 128 + blockIdx.x] = bmax; psum[k * 128 + blockIdx.x] = sm[0]; }
}

__global__ void k_smax2(const float* __restrict__ pmax, const float* __restrict__ psum,
                        float* __restrict__ gs) {
  int k = blockIdx.x;
  int tid = threadIdx.x;  // 128
  __shared__ float sm[128], sv[128];
  float m = pmax[k * 128 + tid];
  sm[tid] = m; __syncthreads();
  for (int o = 64; o >= 1; o >>= 1) { if (tid < o) sm[tid] = fmaxf(sm[tid], sm[tid + o]); __syncthreads(); }
  float gm = sm[0];
  __syncthreads();
  sv[tid] = psum[k * 128 + tid] * __expf(m - gm);
  __syncthreads();
  for (int o = 64; o >= 1; o >>= 1) { if (tid < o) sv[tid] += sv[tid + o]; __syncthreads(); }
  if (tid == 0) { gs[k * 2] = gm; gs[k * 2 + 1] = sv[0]; }
}

// ------------- a = softmax, attn output, z[k][d] partials -------------
__global__ void k_attnz(const float* __restrict__ logitsT, const float* __restrict__ gs,
                        const unsigned short* __restrict__ hb, float* __restrict__ out_attn,
                        float* __restrict__ z) {
  int n0 = blockIdx.x * 128;
  int tid = threadIdx.x;
  __shared__ float a[4][128];
  for (int i = tid; i < 512; i += 256) {
    int k = i >> 7, n = i & 127;
    float v = 0.f;
    if (n0 + n < NN) v = __expf(logitsT[(size_t)k * NN + n0 + n] - gs[k * 2]) / gs[k * 2 + 1];
    a[k][n] = v;
  }
  __syncthreads();
  for (int i = tid; i < 512; i += 256) {
    int n = i >> 2, k = i & 3;
    if (n0 + n < NN) out_attn[(size_t)(n0 + n) * 4 + k] = a[k][n];
  }
  float z0 = 0.f, z1 = 0.f, z2 = 0.f, z3 = 0.f;
  int d = tid;  // 256 dims
  int nmax = NN - n0; if (nmax > 128) nmax = 128;
  for (int n = 0; n < nmax; n++) {
    float hv = bf2f(hb[(size_t)(n0 + n) * 256 + d]);
    z0 += a[0][n] * hv; z1 += a[1][n] * hv; z2 += a[2][n] * hv; z3 += a[3][n] * hv;
  }
  atomicAdd(&z[0 * 256 + d], z0);
  atomicAdd(&z[1 * 256 + d], z1);
  atomicAdd(&z[2 * 256 + d], z2);
  atomicAdd(&z[3 * 256 + d], z3);
}

// ---------------- tiny classifier ----------------
__global__ void k_cls(const float* __restrict__ z, const float* __restrict__ Wc1,
                      const float* __restrict__ bc1, const float* __restrict__ g1,
                      const float* __restrict__ b1, const float* __restrict__ Wc2,
                      const float* __restrict__ bc2, const float* __restrict__ g2,
                      const float* __restrict__ b2, const float* __restrict__ Wc3,
                      const float* __restrict__ bc3, float* __restrict__ out) {
  int tid = threadIdx.x;  // 256
  __shared__ float za[256];
  __shared__ float buf[256];
  __shared__ float c1s[128];
  __shared__ float c2s[64];
  za[tid] = 0.25f * (z[tid] + z[256 + tid] + z[512 + tid] + z[768 + tid]);
  __syncthreads();
  float v1 = 0.f;
  if (tid < 128) {
    for (int d = 0; d < 256; d++) v1 += za[d] * Wc1[d * 128 + tid];
    v1 += bc1[tid];
  }
  buf[tid] = (tid < 128) ? v1 : 0.f; __syncthreads();
  for (int o = 128; o >= 1; o >>= 1) { if (tid < o) buf[tid] += buf[tid + o]; __syncthreads(); }
  float mean1 = buf[0] * (1.f / 128.f);
  __syncthreads();
  buf[tid] = (tid < 128) ? (v1 - mean1) * (v1 - mean1) : 0.f; __syncthreads();
  for (int o = 128; o >= 1; o >>= 1) { if (tid < o) buf[tid] += buf[tid + o]; __syncthreads(); }
  float inv1 = rsqrtf(buf[0] * (1.f / 128.f) + 1e-5f);
  __syncthreads();
  if (tid < 128) c1s[tid] = fmaxf((v1 - mean1) * inv1 * g1[tid] + b1[tid], 0.f);
  __syncthreads();
  float v2 = 0.f;
  if (tid < 64) {
    for (int d = 0; d < 128; d++) v2 += c1s[d] * Wc2[d * 64 + tid];
    v2 += bc2[tid];
  }
  buf[tid] = (tid < 64) ? v2 : 0.f; __syncthreads();
  for (int o = 128; o >= 1; o >>= 1) { if (tid < o) buf[tid] += buf[tid + o]; __syncthreads(); }
  float mean2 = buf[0] * (1.f / 64.f);
  __syncthreads();
  buf[tid] = (tid < 64) ? (v2 - mean2) * (v2 - mean2) : 0.f; __syncthreads();
  for (int o = 128; o >= 1; o >>= 1) { if (tid < o) buf[tid] += buf[tid + o]; __syncthreads(); }
  float inv2 = rsqrtf(buf[0] * (1.f / 64.f) + 1e-5f);
  __syncthreads();
  if (tid < 64) c2s[tid] = fmaxf((v2 - mean2) * inv2 * g2[tid] + b2[tid], 0.f);
  __syncthreads();
  if (tid < 7) {
    float l = 0.f;
    for (int d = 0; d < 64; d++) l += c2s[d] * Wc3[d * 7 + tid];
    buf[tid] = l + bc3[tid];
  }
  __syncthreads();
  if (tid == 0) {
    float mx = -1e30f;
    for (int i = 0; i < 7; i++) mx = fmaxf(mx, buf[i]);
    float s = 0.f;
    for (int i = 0; i < 7; i++) s += __expf(buf[i] - mx);
    for (int i = 0; i < 7; i++) out[i] = __expf(buf[i] - mx) / s;
  }
}

extern "C" void kernel_launch(void* const* d_in, const int* in_sizes, int n_in,
                              void* d_out, int out_size, void* d_ws, size_t ws_size,
                              hipStream_t stream) {
  const float* x       = (const float*)d_in[0];
  const int*   ei      = (const int*)d_in[1];
  const float* W_in    = (const float*)d_in[2];
  const float* b_in    = (const float*)d_in[3];
  const float* gin_W1  = (const float*)d_in[4];
  const float* gin_b1  = (const float*)d_in[5];
  const float* gin_lng = (const float*)d_in[6];
  const float* gin_lnb = (const float*)d_in[7];
  const float* gin_W2  = (const float*)d_in[8];
  const float* gin_b2  = (const float*)d_in[9];
  const float* eps     = (const float*)d_in[10];
  const float* ln_g    = (const float*)d_in[11];
  const float* ln_b    = (const float*)d_in[12];
  const float* att_W1  = (const float*)d_in[13];
  const float* att_b1  = (const float*)d_in[14];
  const float* att_W2  = (const float*)d_in[15];
  const float* att_b2  = (const float*)d_in[16];
  const float* Wc1     = (const float*)d_in[17];
  const float* bc1     = (const float*)d_in[18];
  const float* lnc1_g  = (const float*)d_in[19];
  const float* lnc1_b  = (const float*)d_in[20];
  const float* Wc2     = (const float*)d_in[21];
  const float* bc2     = (const float*)d_in[22];
  const float* lnc2_g  = (const float*)d_in[23];
  const float* lnc2_b  = (const float*)d_in[24];
  const float* Wc3     = (const float*)d_in[25];
  const float* bc3     = (const float*)d_in[26];
  float* out = (float*)d_out;
  (void)in_sizes; (void)n_in; (void)out_size; (void)ws_size;

  char* wsb = (char*)d_ws;
  size_t off = 0;
  auto alloc = [&](size_t bytes) {
    char* p = wsb + off;
    off += (bytes + 255) & ~(size_t)255;
    return p;
  };
  float*          h       = (float*)alloc((size_t)NN * HH * 4);
  unsigned short* hb      = (unsigned short*)alloc((size_t)NN * HH * 2);
  unsigned short* mb1     = (unsigned short*)alloc((size_t)NN * HH * 2);
  unsigned short* WinT    = (unsigned short*)alloc((size_t)HH * FF * 2);
  unsigned short* g1T     = (unsigned short*)alloc((size_t)2 * HH * HH * 2);
  unsigned short* g2T     = (unsigned short*)alloc((size_t)2 * HH * HH * 2);
  unsigned short* aW1T    = (unsigned short*)alloc((size_t)4 * 128 * HH * 2);
  float*          logitsT = (float*)alloc((size_t)4 * NN * 4);
  int*            deg     = (int*)alloc((size_t)NN * 4);
  int*            rowptr  = (int*)alloc((size_t)(NN + 1) * 4);
  int*            cursor  = (int*)alloc((size_t)NN * 4);
  int*            csr_src = (int*)alloc((size_t)NE * 4);
  float*          pmax    = (float*)alloc(4 * 128 * 4);
  float*          psum    = (float*)alloc(4 * 128 * 4);
  float*          gs      = (float*)alloc(8 * 4);
  float*          z       = (float*)alloc(4 * 256 * 4);

  const int* srcv = ei;
  const int* dstv = ei + NE;

  // weight transposes + casts (tiny, batched over blockIdx.z)
  k_tcast<<<dim3((HH + 31) / 32, (FF + 31) / 32, 1), 256, 0, stream>>>(W_in, WinT, FF, HH);
  k_tcast<<<dim3(8, 8, 2), 256, 0, stream>>>(gin_W1, g1T, HH, HH);
  k_tcast<<<dim3(8, 8, 2), 256, 0, stream>>>(gin_W2, g2T, HH, HH);
  k_tcast<<<dim3(4, 8, 4), 256, 0, stream>>>(att_W1, aW1T, HH, 128);

  // CSR build
  hipMemsetAsync(deg, 0, (size_t)NN * 4, stream);
  hipMemsetAsync(z, 0, 4 * 256 * 4, stream);
  k_count<<<(NE + 255) / 256, 256, 0, stream>>>(dstv, deg);
  k_scan<<<1, 1024, 0, stream>>>(deg, rowptr);
  hipMemcpyAsync(cursor, rowptr, (size_t)NN * 4, hipMemcpyDeviceToDevice, stream);
  k_scatter<<<(NE + 255) / 256, 256, 0, stream>>>(srcv, dstv, cursor, csr_src);

  int gblocks = (NN + 63) / 64;  // 782
  // h = x @ W_in + b_in  (fp32 A cast to bf16 in staging); also emit hb
  k_mmff0<<<gblocks, 256, 0, stream>>>(x, WinT, b_in, h, hb);

  for (int l = 0; l < 2; l++) {
    k_agg<<<(NN + 3) / 4, 256, 0, stream>>>(hb, rowptr, csr_src, eps, l, mb1);
    const unsigned short* B1 = g1T + (size_t)l * HH * HH;
    const unsigned short* B2 = g2T + (size_t)l * HH * HH;
    if (l == 0)
      k_fused<true, false><<<gblocks, 256, 0, stream>>>(
          mb1, B1, gin_b1 + l * HH, gin_lng + l * HH, gin_lnb + l * HH,
          B2, gin_b2 + l * HH, ln_g + l * HH, ln_b + l * HH,
          h, h, hb, nullptr, nullptr, nullptr, nullptr, nullptr);
    else
      k_fused<false, true><<<gblocks, 256, 0, stream>>>(
          mb1, B1, gin_b1 + l * HH, gin_lng + l * HH, gin_lnb + l * HH,
          B2, gin_b2 + l * HH, ln_g + l * HH, ln_b + l * HH,
          h, h, hb, aW1T, att_b1, att_W2, att_b2, logitsT);
  }

  k_smax1<<<dim3(128, 4), 256, 0, stream>>>(logitsT, pmax, psum);
  k_smax2<<<4, 128, 0, stream>>>(pmax, psum, gs);
  k_attnz<<<(NN + 127) / 128, 256, 0, stream>>>(logitsT, gs, hb, out + 7, z);
  k_cls<<<1, 256, 0, stream>>>(z, Wc1, bc1, lnc1_g, lnc1_b, Wc2, bc2, lnc2_g, lnc2_b,
                               Wc3, bc3, out);
}

// Round 4
// 979.666 us; speedup vs baseline: 1.1967x; 1.1967x over previous
//
#include <hip/hip_runtime.h>
#include <math.h>

#define NN 50000
#define NE 800000
#define FF 768
#define HH 256

typedef __attribute__((ext_vector_type(8))) short short8;
typedef __attribute__((ext_vector_type(4))) float f32x4;

__device__ inline unsigned short f2bf(float f) {
  unsigned u = __float_as_uint(f);
  u = u + 0x7fffu + ((u >> 16) & 1u);
  return (unsigned short)(u >> 16);
}
__device__ inline float bf2f(unsigned short b) {
  return __uint_as_float(((unsigned)b) << 16);
}

// ---------------- CSR build ----------------
__global__ void k_count(const int* __restrict__ dstv, int* __restrict__ deg) {
  int e = blockIdx.x * 256 + threadIdx.x;
  if (e < NE) atomicAdd(&deg[dstv[e]], 1);
}

// single-block thread-coarsened scan: 1024 threads x 49 elems
__global__ void k_scan(const int* __restrict__ deg, int* __restrict__ rowptr) {
  const int CH = 49;  // 1024*49 = 50176 >= NN
  int tid = threadIdx.x;
  int lane = tid & 63, w = tid >> 6;
  int base = tid * CH;
  int sum = 0;
  for (int i = 0; i < CH; i++) {
    int idx = base + i;
    if (idx < NN) sum += deg[idx];
  }
  int incl = sum;
  for (int off = 1; off < 64; off <<= 1) {
    int tv = __shfl_up(incl, off, 64);
    if (lane >= off) incl += tv;
  }
  __shared__ int ws[16];
  if (lane == 63) ws[w] = incl;
  __syncthreads();
  if (tid == 0) {
    int c = 0;
    for (int i = 0; i < 16; i++) { int tv = ws[i]; ws[i] = c; c += tv; }
  }
  __syncthreads();
  int run = ws[w] + (incl - sum);
  if (tid == 0) rowptr[0] = 0;
  for (int i = 0; i < CH; i++) {
    int idx = base + i;
    if (idx < NN) { run += deg[idx]; rowptr[idx + 1] = run; }
  }
}

__global__ void k_scatter(const int* __restrict__ srcv, const int* __restrict__ dstv,
                          int* __restrict__ cursor, int* __restrict__ csr_src) {
  int e = blockIdx.x * 256 + threadIdx.x;
  if (e < NE) {
    int d = dstv[e];
    int pos = atomicAdd(&cursor[d], 1);
    csr_src[pos] = srcv[e];
  }
}

// ------------- aggregation (bf16 gather): mb = bf16((1+eps)*hb + sum hb[src]) -------------
__global__ void k_agg(const unsigned short* __restrict__ hb, const int* __restrict__ rowptr,
                      const int* __restrict__ csr_src, const float* __restrict__ eps,
                      int layer, unsigned short* __restrict__ mb) {
  int node = (blockIdx.x * blockDim.x + threadIdx.x) >> 6;
  int lane = threadIdx.x & 63;
  if (node >= NN) return;
  int beg = rowptr[node], end = rowptr[node + 1];
  const ushort4* hv = (const ushort4*)hb;
  float ax = 0.f, ay = 0.f, az = 0.f, aw = 0.f;
  for (int e = beg; e < end; ++e) {
    int s = csr_src[e];
    ushort4 v = hv[(size_t)s * 64 + lane];
    ax += bf2f(v.x); ay += bf2f(v.y); az += bf2f(v.z); aw += bf2f(v.w);
  }
  float ep = 1.0f + eps[layer];
  ushort4 h0 = hv[(size_t)node * 64 + lane];
  ax += ep * bf2f(h0.x); ay += ep * bf2f(h0.y);
  az += ep * bf2f(h0.z); aw += ep * bf2f(h0.w);
  ushort4 o;
  o.x = f2bf(ax); o.y = f2bf(ay); o.z = f2bf(az); o.w = f2bf(aw);
  *(ushort4*)&mb[(size_t)node * 256 + lane * 4] = o;
}

// ------------- transpose + cast: dst[c][r] = bf16(src[r][c]), src is R x C, batched over z -------------
__global__ void k_tcast(const float* __restrict__ src0, unsigned short* __restrict__ dst0,
                        int R, int C) {
  const float* src = src0 + (size_t)blockIdx.z * R * C;
  unsigned short* dst = dst0 + (size_t)blockIdx.z * R * C;
  __shared__ float tile[32][33];
  int bx = blockIdx.x * 32, by = blockIdx.y * 32;
  int tx = threadIdx.x & 31, ty = threadIdx.x >> 5;  // 32 x 8
  for (int i = 0; i < 32; i += 8) {
    int r = by + ty + i, c = bx + tx;
    tile[ty + i][tx] = (r < R && c < C) ? src[(size_t)r * C + c] : 0.f;
  }
  __syncthreads();
  for (int i = 0; i < 32; i += 8) {
    int c = bx + ty + i, r = by + tx;
    if (c < C && r < R) dst[(size_t)c * R + r] = f2bf(tile[tx][ty + i]);
  }
}

// ---------------- bf16 MFMA GEMM: block tile 32 x 256, BK=32 ----------------
// Round-0 proven structure, M-tile halved 64->32 to double grid (782->1563 blocks)
// for latency hiding. LDS ~24KB -> 6 blocks/CU by LDS (was 3).
// EPI 0: outf = A@B + bias (fp32) and outb = bf16(same)
// EPI 1: outb = bf16(relu(LN(A@B + bias; g,be)))
// EPI 2: v = relu(LN(A@B+bias; g,be)) + resid; outf = v (if WF); outb = bf16(v)
template <int KTOT, int EPI, bool AF32, bool WF>
__global__ __launch_bounds__(256) void k_mm(
    const void* __restrict__ Ap, const unsigned short* __restrict__ Bt,
    const float* __restrict__ bias, const float* __restrict__ g,
    const float* __restrict__ be, const float* __restrict__ resid,
    float* __restrict__ outf, unsigned short* __restrict__ outb) {
  __shared__ unsigned short As[32 * 40];   // 32 rows x 32 k, padded to 40
  __shared__ unsigned short Bs[256 * 40];  // 256 n-rows x 32 k, padded to 40
  __shared__ float redS[4][32];
  __shared__ float redQ[4][32];
  __shared__ float mvM[32], mvI[32];
  int t = threadIdx.x, lane = t & 63, wave = t >> 6;
  int row0 = blockIdx.x * 32;
  f32x4 acc[2][4];
#pragma unroll
  for (int i = 0; i < 2; i++)
#pragma unroll
    for (int j = 0; j < 4; j++) acc[i][j] = (f32x4)(0.f);
  int arow = t >> 2, ac = t & 3;               // valid for t<128: arow 0..31
  int agr = row0 + arow; if (agr >= NN) agr = NN - 1;
  int m16 = lane & 15, kq = lane >> 4;

  for (int k0 = 0; k0 < KTOT; k0 += 32) {
    if (t < 128) {
      if (AF32) {
        const float* Af = (const float*)Ap + (size_t)agr * KTOT + k0 + ac * 8;
        float4 f0 = *(const float4*)Af;
        float4 f1 = *(const float4*)(Af + 4);
        short8 v;
        v[0] = (short)f2bf(f0.x); v[1] = (short)f2bf(f0.y);
        v[2] = (short)f2bf(f0.z); v[3] = (short)f2bf(f0.w);
        v[4] = (short)f2bf(f1.x); v[5] = (short)f2bf(f1.y);
        v[6] = (short)f2bf(f1.z); v[7] = (short)f2bf(f1.w);
        *(short8*)&As[arow * 40 + ac * 8] = v;
      } else {
        const unsigned short* Ab = (const unsigned short*)Ap + (size_t)agr * KTOT + k0 + ac * 8;
        *(float4*)&As[arow * 40 + ac * 8] = *(const float4*)Ab;
      }
    }
#pragma unroll
    for (int it = 0; it < 4; it++) {
      int idx = t + it * 256;
      int br = idx >> 2, bc = idx & 3;
      *(float4*)&Bs[br * 40 + bc * 8] = *(const float4*)&Bt[(size_t)br * KTOT + k0 + bc * 8];
    }
    __syncthreads();
    short8 a[2], b[4];
#pragma unroll
    for (int rt = 0; rt < 2; rt++) a[rt] = *(const short8*)&As[(rt * 16 + m16) * 40 + kq * 8];
#pragma unroll
    for (int ct = 0; ct < 4; ct++)
      b[ct] = *(const short8*)&Bs[(wave * 64 + ct * 16 + m16) * 40 + kq * 8];
#pragma unroll
    for (int rt = 0; rt < 2; rt++)
#pragma unroll
      for (int ct = 0; ct < 4; ct++)
        acc[rt][ct] = __builtin_amdgcn_mfma_f32_16x16x32_bf16(a[rt], b[ct], acc[rt][ct], 0, 0, 0);
    __syncthreads();
  }

  int colbase = wave * 64 + m16;
  float bv[4];
#pragma unroll
  for (int ct = 0; ct < 4; ct++) bv[ct] = bias[colbase + ct * 16];

  if (EPI == 0) {
#pragma unroll
    for (int rt = 0; rt < 2; rt++)
#pragma unroll
      for (int reg = 0; reg < 4; reg++) {
        int r = row0 + rt * 16 + kq * 4 + reg;
        if (r < NN) {
#pragma unroll
          for (int ct = 0; ct < 4; ct++) {
            float v = acc[rt][ct][reg] + bv[ct];
            outf[(size_t)r * 256 + colbase + ct * 16] = v;
            outb[(size_t)r * 256 + colbase + ct * 16] = f2bf(v);
          }
        }
      }
    return;
  }

  float s[2][4], q[2][4];
#pragma unroll
  for (int rt = 0; rt < 2; rt++)
#pragma unroll
    for (int reg = 0; reg < 4; reg++) { s[rt][reg] = 0.f; q[rt][reg] = 0.f; }
#pragma unroll
  for (int rt = 0; rt < 2; rt++)
#pragma unroll
    for (int ct = 0; ct < 4; ct++)
#pragma unroll
      for (int reg = 0; reg < 4; reg++) {
        float v = acc[rt][ct][reg] + bv[ct];
        acc[rt][ct][reg] = v;
        s[rt][reg] += v;
        q[rt][reg] += v * v;
      }
#pragma unroll
  for (int off = 1; off < 16; off <<= 1) {
#pragma unroll
    for (int rt = 0; rt < 2; rt++)
#pragma unroll
      for (int reg = 0; reg < 4; reg++) {
        s[rt][reg] += __shfl_xor(s[rt][reg], off, 64);
        q[rt][reg] += __shfl_xor(q[rt][reg], off, 64);
      }
  }
  if (m16 == 0) {
#pragma unroll
    for (int rt = 0; rt < 2; rt++)
#pragma unroll
      for (int reg = 0; reg < 4; reg++) {
        redS[wave][rt * 16 + kq * 4 + reg] = s[rt][reg];
        redQ[wave][rt * 16 + kq * 4 + reg] = q[rt][reg];
      }
  }
  __syncthreads();
  if (t < 32) {
    float ss = redS[0][t] + redS[1][t] + redS[2][t] + redS[3][t];
    float qq = redQ[0][t] + redQ[1][t] + redQ[2][t] + redQ[3][t];
    float mean = ss * (1.f / 256.f);
    float var = qq * (1.f / 256.f) - mean * mean;
    mvM[t] = mean;
    mvI[t] = rsqrtf(var + 1e-5f);
  }
  __syncthreads();
  float gv[4], bev[4];
#pragma unroll
  for (int ct = 0; ct < 4; ct++) { gv[ct] = g[colbase + ct * 16]; bev[ct] = be[colbase + ct * 16]; }
#pragma unroll
  for (int rt = 0; rt < 2; rt++)
#pragma unroll
    for (int reg = 0; reg < 4; reg++) {
      int rr = rt * 16 + kq * 4 + reg;
      int r = row0 + rr;
      if (r >= NN) continue;
      float mean = mvM[rr], inv = mvI[rr];
#pragma unroll
      for (int ct = 0; ct < 4; ct++) {
        int col = colbase + ct * 16;
        float val = fmaxf((acc[rt][ct][reg] - mean) * inv * gv[ct] + bev[ct], 0.f);
        if (EPI == 2) {
          val += resid[(size_t)r * 256 + col];
          if (WF) outf[(size_t)r * 256 + col] = val;
        }
        outb[(size_t)r * 256 + col] = f2bf(val);
      }
    }
}

// ------------- attention logits, 4 heads fused: block 64 rows x (4x128) cols -------------
// wave w computes head w; logits written straight from registers. (round-0 proven)
__global__ __launch_bounds__(256) void k_att(const unsigned short* __restrict__ hb,
    const unsigned short* __restrict__ W1T, const float* __restrict__ b1,
    const float* __restrict__ W2, const float* __restrict__ b2,
    float* __restrict__ logitsT) {
  __shared__ unsigned short As[64 * 40];
  __shared__ unsigned short Bs[512 * 40];
  int t = threadIdx.x, lane = t & 63, wave = t >> 6;  // wave == head
  int row0 = blockIdx.x * 64;
  f32x4 acc[4][8];
#pragma unroll
  for (int i = 0; i < 4; i++)
#pragma unroll
    for (int j = 0; j < 8; j++) acc[i][j] = (f32x4)(0.f);
  int arow = t >> 2, ac = t & 3;
  int agr = row0 + arow; if (agr >= NN) agr = NN - 1;
  int m16 = lane & 15, kq = lane >> 4;
  for (int k0 = 0; k0 < 256; k0 += 32) {
    *(float4*)&As[arow * 40 + ac * 8] = *(const float4*)&hb[(size_t)agr * 256 + k0 + ac * 8];
#pragma unroll
    for (int it = 0; it < 8; it++) {
      int idx = t + it * 256;
      int br = idx >> 2, bc = idx & 3;
      *(float4*)&Bs[br * 40 + bc * 8] = *(const float4*)&W1T[(size_t)br * 256 + k0 + bc * 8];
    }
    __syncthreads();
    short8 a[4];
#pragma unroll
    for (int rt = 0; rt < 4; rt++) a[rt] = *(const short8*)&As[(rt * 16 + m16) * 40 + kq * 8];
#pragma unroll
    for (int ct = 0; ct < 8; ct++) {
      short8 b = *(const short8*)&Bs[(wave * 128 + ct * 16 + m16) * 40 + kq * 8];
#pragma unroll
      for (int rt = 0; rt < 4; rt++)
        acc[rt][ct] = __builtin_amdgcn_mfma_f32_16x16x32_bf16(a[rt], b, acc[rt][ct], 0, 0, 0);
    }
    __syncthreads();
  }
  const float* b1k = b1 + wave * 128;
  const float* w2k = W2 + wave * 128;
  float p[4][4];
#pragma unroll
  for (int rt = 0; rt < 4; rt++)
#pragma unroll
    for (int reg = 0; reg < 4; reg++) p[rt][reg] = 0.f;
#pragma unroll
  for (int ct = 0; ct < 8; ct++) {
    int col = ct * 16 + m16;
    float b1v = b1k[col], w2v = w2k[col];
#pragma unroll
    for (int rt = 0; rt < 4; rt++)
#pragma unroll
      for (int reg = 0; reg < 4; reg++) {
        float xv = acc[rt][ct][reg] + b1v;
        xv = fminf(fmaxf(xv, -10.f), 10.f);
        float ex = __expf(2.f * xv);
        p[rt][reg] += (ex - 1.f) / (ex + 1.f) * w2v;
      }
  }
#pragma unroll
  for (int off = 1; off < 16; off <<= 1)
#pragma unroll
    for (int rt = 0; rt < 4; rt++)
#pragma unroll
      for (int reg = 0; reg < 4; reg++) p[rt][reg] += __shfl_xor(p[rt][reg], off, 64);
  if (m16 == 0) {
    float b2v = b2[wave];
#pragma unroll
    for (int rt = 0; rt < 4; rt++)
#pragma unroll
      for (int reg = 0; reg < 4; reg++) {
        int r = row0 + rt * 16 + kq * 4 + reg;
        if (r < NN) logitsT[(size_t)wave * NN + r] = p[rt][reg] + b2v;
      }
  }
}

// ---------------- softmax over N per head ----------------
__global__ void k_smax1(const float* __restrict__ logitsT, float* __restrict__ pmax,
                        float* __restrict__ psum) {
  int k = blockIdx.y;
  int tid = threadIdx.x;
  const float* L = logitsT + (size_t)k * NN;
  __shared__ float sm[256];
  float mx = -1e30f;
  for (int i = blockIdx.x * 256 + tid; i < NN; i += 128 * 256) mx = fmaxf(mx, L[i]);
  sm[tid] = mx; __syncthreads();
  for (int o = 128; o >= 1; o >>= 1) { if (tid < o) sm[tid] = fmaxf(sm[tid], sm[tid + o]); __syncthreads(); }
  float bmax = sm[0];
  __syncthreads();
  float s = 0.f;
  for (int i = blockIdx.x * 256 + tid; i < NN; i += 128 * 256) s += __expf(L[i] - bmax);
  sm[tid] = s; __syncthreads();
  for (int o = 128; o >= 1; o >>= 1) { if (tid < o) sm[tid] += sm[tid + o]; __syncthreads(); }
  if (tid == 0) { pmax[k * 128 + blockIdx.x] = bmax; psum[k * 128 + blockIdx.x] = sm[0]; }
}

__global__ void k_smax2(const float* __restrict__ pmax, const float* __restrict__ psum,
                        float* __restrict__ gs) {
  int k = blockIdx.x;
  int tid = threadIdx.x;  // 128
  __shared__ float sm[128], sv[128];
  float m = pmax[k * 128 + tid];
  sm[tid] = m; __syncthreads();
  for (int o = 64; o >= 1; o >>= 1) { if (tid < o) sm[tid] = fmaxf(sm[tid], sm[tid + o]); __syncthreads(); }
  float gm = sm[0];
  __syncthreads();
  sv[tid] = psum[k * 128 + tid] * __expf(m - gm);
  __syncthreads();
  for (int o = 64; o >= 1; o >>= 1) { if (tid < o) sv[tid] += sv[tid + o]; __syncthreads(); }
  if (tid == 0) { gs[k * 2] = gm; gs[k * 2 + 1] = sv[0]; }
}

// ------------- a = softmax, attn output, z[k][d] partials -------------
__global__ void k_attnz(const float* __restrict__ logitsT, const float* __restrict__ gs,
                        const unsigned short* __restrict__ hb, float* __restrict__ out_attn,
                        float* __restrict__ z) {
  int n0 = blockIdx.x * 128;
  int tid = threadIdx.x;
  __shared__ float a[4][128];
  for (int i = tid; i < 512; i += 256) {
    int k = i >> 7, n = i & 127;
    float v = 0.f;
    if (n0 + n < NN) v = __expf(logitsT[(size_t)k * NN + n0 + n] - gs[k * 2]) / gs[k * 2 + 1];
    a[k][n] = v;
  }
  __syncthreads();
  for (int i = tid; i < 512; i += 256) {
    int n = i >> 2, k = i & 3;
    if (n0 + n < NN) out_attn[(size_t)(n0 + n) * 4 + k] = a[k][n];
  }
  float z0 = 0.f, z1 = 0.f, z2 = 0.f, z3 = 0.f;
  int d = tid;  // 256 dims
  int nmax = NN - n0; if (nmax > 128) nmax = 128;
  for (int n = 0; n < nmax; n++) {
    float hv = bf2f(hb[(size_t)(n0 + n) * 256 + d]);
    z0 += a[0][n] * hv; z1 += a[1][n] * hv; z2 += a[2][n] * hv; z3 += a[3][n] * hv;
  }
  atomicAdd(&z[0 * 256 + d], z0);
  atomicAdd(&z[1 * 256 + d], z1);
  atomicAdd(&z[2 * 256 + d], z2);
  atomicAdd(&z[3 * 256 + d], z3);
}

// ---------------- tiny classifier ----------------
__global__ void k_cls(const float* __restrict__ z, const float* __restrict__ Wc1,
                      const float* __restrict__ bc1, const float* __restrict__ g1,
                      const float* __restrict__ b1, const float* __restrict__ Wc2,
                      const float* __restrict__ bc2, const float* __restrict__ g2,
                      const float* __restrict__ b2, const float* __restrict__ Wc3,
                      const float* __restrict__ bc3, float* __restrict__ out) {
  int tid = threadIdx.x;  // 256
  __shared__ float za[256];
  __shared__ float buf[256];
  __shared__ float c1s[128];
  __shared__ float c2s[64];
  za[tid] = 0.25f * (z[tid] + z[256 + tid] + z[512 + tid] + z[768 + tid]);
  __syncthreads();
  float v1 = 0.f;
  if (tid < 128) {
    for (int d = 0; d < 256; d++) v1 += za[d] * Wc1[d * 128 + tid];
    v1 += bc1[tid];
  }
  buf[tid] = (tid < 128) ? v1 : 0.f; __syncthreads();
  for (int o = 128; o >= 1; o >>= 1) { if (tid < o) buf[tid] += buf[tid + o]; __syncthreads(); }
  float mean1 = buf[0] * (1.f / 128.f);
  __syncthreads();
  buf[tid] = (tid < 128) ? (v1 - mean1) * (v1 - mean1) : 0.f; __syncthreads();
  for (int o = 128; o >= 1; o >>= 1) { if (tid < o) buf[tid] += buf[tid + o]; __syncthreads(); }
  float inv1 = rsqrtf(buf[0] * (1.f / 128.f) + 1e-5f);
  __syncthreads();
  if (tid < 128) c1s[tid] = fmaxf((v1 - mean1) * inv1 * g1[tid] + b1[tid], 0.f);
  __syncthreads();
  float v2 = 0.f;
  if (tid < 64) {
    for (int d = 0; d < 128; d++) v2 += c1s[d] * Wc2[d * 64 + tid];
    v2 += bc2[tid];
  }
  buf[tid] = (tid < 64) ? v2 : 0.f; __syncthreads();
  for (int o = 128; o >= 1; o >>= 1) { if (tid < o) buf[tid] += buf[tid + o]; __syncthreads(); }
  float mean2 = buf[0] * (1.f / 64.f);
  __syncthreads();
  buf[tid] = (tid < 64) ? (v2 - mean2) * (v2 - mean2) : 0.f; __syncthreads();
  for (int o = 128; o >= 1; o >>= 1) { if (tid < o) buf[tid] += buf[tid + o]; __syncthreads(); }
  float inv2 = rsqrtf(buf[0] * (1.f / 64.f) + 1e-5f);
  __syncthreads();
  if (tid < 64) c2s[tid] = fmaxf((v2 - mean2) * inv2 * g2[tid] + b2[tid], 0.f);
  __syncthreads();
  if (tid < 7) {
    float l = 0.f;
    for (int d = 0; d < 64; d++) l += c2s[d] * Wc3[d * 7 + tid];
    buf[tid] = l + bc3[tid];
  }
  __syncthreads();
  if (tid == 0) {
    float mx = -1e30f;
    for (int i = 0; i < 7; i++) mx = fmaxf(mx, buf[i]);
    float s = 0.f;
    for (int i = 0; i < 7; i++) s += __expf(buf[i] - mx);
    for (int i = 0; i < 7; i++) out[i] = __expf(buf[i] - mx) / s;
  }
}

extern "C" void kernel_launch(void* const* d_in, const int* in_sizes, int n_in,
                              void* d_out, int out_size, void* d_ws, size_t ws_size,
                              hipStream_t stream) {
  const float* x       = (const float*)d_in[0];
  const int*   ei      = (const int*)d_in[1];
  const float* W_in    = (const float*)d_in[2];
  const float* b_in    = (const float*)d_in[3];
  const float* gin_W1  = (const float*)d_in[4];
  const float* gin_b1  = (const float*)d_in[5];
  const float* gin_lng = (const float*)d_in[6];
  const float* gin_lnb = (const float*)d_in[7];
  const float* gin_W2  = (const float*)d_in[8];
  const float* gin_b2  = (const float*)d_in[9];
  const float* eps     = (const float*)d_in[10];
  const float* ln_g    = (const float*)d_in[11];
  const float* ln_b    = (const float*)d_in[12];
  const float* att_W1  = (const float*)d_in[13];
  const float* att_b1  = (const float*)d_in[14];
  const float* att_W2  = (const float*)d_in[15];
  const float* att_b2  = (const float*)d_in[16];
  const float* Wc1     = (const float*)d_in[17];
  const float* bc1     = (const float*)d_in[18];
  const float* lnc1_g  = (const float*)d_in[19];
  const float* lnc1_b  = (const float*)d_in[20];
  const float* Wc2     = (const float*)d_in[21];
  const float* bc2     = (const float*)d_in[22];
  const float* lnc2_g  = (const float*)d_in[23];
  const float* lnc2_b  = (const float*)d_in[24];
  const float* Wc3     = (const float*)d_in[25];
  const float* bc3     = (const float*)d_in[26];
  float* out = (float*)d_out;
  (void)in_sizes; (void)n_in; (void)out_size; (void)ws_size;

  char* wsb = (char*)d_ws;
  size_t off = 0;
  auto alloc = [&](size_t bytes) {
    char* p = wsb + off;
    off += (bytes + 255) & ~(size_t)255;
    return p;
  };
  float*          h       = (float*)alloc((size_t)NN * HH * 4);
  unsigned short* hb      = (unsigned short*)alloc((size_t)NN * HH * 2);
  unsigned short* mb1     = (unsigned short*)alloc((size_t)NN * HH * 2);
  unsigned short* mb2     = (unsigned short*)alloc((size_t)NN * HH * 2);
  unsigned short* WinT    = (unsigned short*)alloc((size_t)HH * FF * 2);
  unsigned short* g1T     = (unsigned short*)alloc((size_t)2 * HH * HH * 2);
  unsigned short* g2T     = (unsigned short*)alloc((size_t)2 * HH * HH * 2);
  unsigned short* aW1T    = (unsigned short*)alloc((size_t)4 * 128 * HH * 2);
  float*          logitsT = (float*)alloc((size_t)4 * NN * 4);
  int*            deg     = (int*)alloc((size_t)NN * 4);
  int*            rowptr  = (int*)alloc((size_t)(NN + 1) * 4);
  int*            cursor  = (int*)alloc((size_t)NN * 4);
  int*            csr_src = (int*)alloc((size_t)NE * 4);
  float*          pmax    = (float*)alloc(4 * 128 * 4);
  float*          psum    = (float*)alloc(4 * 128 * 4);
  float*          gs      = (float*)alloc(8 * 4);
  float*          z       = (float*)alloc(4 * 256 * 4);

  const int* srcv = ei;
  const int* dstv = ei + NE;

  // weight transposes + casts (tiny, batched over blockIdx.z)
  k_tcast<<<dim3((HH + 31) / 32, (FF + 31) / 32, 1), 256, 0, stream>>>(W_in, WinT, FF, HH);
  k_tcast<<<dim3(8, 8, 2), 256, 0, stream>>>(gin_W1, g1T, HH, HH);
  k_tcast<<<dim3(8, 8, 2), 256, 0, stream>>>(gin_W2, g2T, HH, HH);
  k_tcast<<<dim3(4, 8, 4), 256, 0, stream>>>(att_W1, aW1T, HH, 128);

  // CSR build
  hipMemsetAsync(deg, 0, (size_t)NN * 4, stream);
  hipMemsetAsync(z, 0, 4 * 256 * 4, stream);
  k_count<<<(NE + 255) / 256, 256, 0, stream>>>(dstv, deg);
  k_scan<<<1, 1024, 0, stream>>>(deg, rowptr);
  hipMemcpyAsync(cursor, rowptr, (size_t)NN * 4, hipMemcpyDeviceToDevice, stream);
  k_scatter<<<(NE + 255) / 256, 256, 0, stream>>>(srcv, dstv, cursor, csr_src);

  int gb32 = (NN + 31) / 32;   // 1563 blocks for 32-row GEMM tiles
  int gb64 = (NN + 63) / 64;   // 782 for k_att
  // h = x @ W_in + b_in  (fp32 A cast to bf16 in staging); also emit hb
  k_mm<FF, 0, true, true><<<gb32, 256, 0, stream>>>(x, WinT, b_in, nullptr, nullptr, nullptr, h, hb);

  for (int l = 0; l < 2; l++) {
    k_agg<<<(NN + 3) / 4, 256, 0, stream>>>(hb, rowptr, csr_src, eps, l, mb1);
    // mb2 = bf16(relu(LN(mb1 @ W1 + b1)))
    k_mm<HH, 1, false, true><<<gb32, 256, 0, stream>>>(mb1, g1T + (size_t)l * HH * HH,
        gin_b1 + l * HH, gin_lng + l * HH, gin_lnb + l * HH, nullptr, nullptr, mb2);
    // h = relu(LN(mb2 @ W2 + b2)) + h ; hb = bf16(h). Last layer: skip fp32 h write.
    if (l == 0)
      k_mm<HH, 2, false, true><<<gb32, 256, 0, stream>>>(mb2, g2T + (size_t)l * HH * HH,
          gin_b2 + l * HH, ln_g + l * HH, ln_b + l * HH, h, h, hb);
    else
      k_mm<HH, 2, false, false><<<gb32, 256, 0, stream>>>(mb2, g2T + (size_t)l * HH * HH,
          gin_b2 + l * HH, ln_g + l * HH, ln_b + l * HH, h, nullptr, hb);
  }

  k_att<<<gb64, 256, 0, stream>>>(hb, aW1T, att_b1, att_W2, att_b2, logitsT);
  k_smax1<<<dim3(128, 4), 256, 0, stream>>>(logitsT, pmax, psum);
  k_smax2<<<4, 128, 0, stream>>>(pmax, psum, gs);
  k_attnz<<<(NN + 127) / 128, 256, 0, stream>>>(logitsT, gs, hb, out + 7, z);
  k_cls<<<1, 256, 0, stream>>>(z, Wc1, bc1, lnc1_g, lnc1_b, Wc2, bc2, lnc2_g, lnc2_b,
                               Wc3, bc3, out);
}

// Round 5
// 935.214 us; speedup vs baseline: 1.2535x; 1.0475x over previous
//
#include <hip/hip_runtime.h>
#include <math.h>

#define NN 50000
#define NE 800000
#define FF 768
#define HH 256

typedef __attribute__((ext_vector_type(8))) short short8;
typedef __attribute__((ext_vector_type(4))) float f32x4;

__device__ inline unsigned short f2bf(float f) {
  unsigned u = __float_as_uint(f);
  u = u + 0x7fffu + ((u >> 16) & 1u);
  return (unsigned short)(u >> 16);
}
__device__ inline float bf2f(unsigned short b) {
  return __uint_as_float(((unsigned)b) << 16);
}

// async global->LDS, 16B per lane. Dest is wave-uniform base + lane*16 (HW).
__device__ __forceinline__ void ldsload16(const unsigned short* g, unsigned short* l) {
  __builtin_amdgcn_global_load_lds(
      (const __attribute__((address_space(1))) void*)g,
      (__attribute__((address_space(3))) void*)l, 16, 0, 0);
}

// ---------------- CSR build ----------------
__global__ void k_count(const int* __restrict__ dstv, int* __restrict__ deg) {
  int e = blockIdx.x * 256 + threadIdx.x;
  if (e < NE) atomicAdd(&deg[dstv[e]], 1);
}

// single-block thread-coarsened scan: 1024 threads x 49 elems
__global__ void k_scan(const int* __restrict__ deg, int* __restrict__ rowptr) {
  const int CH = 49;  // 1024*49 = 50176 >= NN
  int tid = threadIdx.x;
  int lane = tid & 63, w = tid >> 6;
  int base = tid * CH;
  int sum = 0;
  for (int i = 0; i < CH; i++) {
    int idx = base + i;
    if (idx < NN) sum += deg[idx];
  }
  int incl = sum;
  for (int off = 1; off < 64; off <<= 1) {
    int tv = __shfl_up(incl, off, 64);
    if (lane >= off) incl += tv;
  }
  __shared__ int ws[16];
  if (lane == 63) ws[w] = incl;
  __syncthreads();
  if (tid == 0) {
    int c = 0;
    for (int i = 0; i < 16; i++) { int tv = ws[i]; ws[i] = c; c += tv; }
  }
  __syncthreads();
  int run = ws[w] + (incl - sum);
  if (tid == 0) rowptr[0] = 0;
  for (int i = 0; i < CH; i++) {
    int idx = base + i;
    if (idx < NN) { run += deg[idx]; rowptr[idx + 1] = run; }
  }
}

__global__ void k_scatter(const int* __restrict__ srcv, const int* __restrict__ dstv,
                          int* __restrict__ cursor, int* __restrict__ csr_src) {
  int e = blockIdx.x * 256 + threadIdx.x;
  if (e < NE) {
    int d = dstv[e];
    int pos = atomicAdd(&cursor[d], 1);
    csr_src[pos] = srcv[e];
  }
}

// ------------- aggregation (bf16 gather): mb = bf16((1+eps)*hb + sum hb[src]) -------------
__global__ void k_agg(const unsigned short* __restrict__ hb, const int* __restrict__ rowptr,
                      const int* __restrict__ csr_src, const float* __restrict__ eps,
                      int layer, unsigned short* __restrict__ mb) {
  int node = (blockIdx.x * blockDim.x + threadIdx.x) >> 6;
  int lane = threadIdx.x & 63;
  if (node >= NN) return;
  int beg = rowptr[node], end = rowptr[node + 1];
  const ushort4* hv = (const ushort4*)hb;
  float ax = 0.f, ay = 0.f, az = 0.f, aw = 0.f;
  for (int e = beg; e < end; ++e) {
    int s = csr_src[e];
    ushort4 v = hv[(size_t)s * 64 + lane];
    ax += bf2f(v.x); ay += bf2f(v.y); az += bf2f(v.z); aw += bf2f(v.w);
  }
  float ep = 1.0f + eps[layer];
  ushort4 h0 = hv[(size_t)node * 64 + lane];
  ax += ep * bf2f(h0.x); ay += ep * bf2f(h0.y);
  az += ep * bf2f(h0.z); aw += ep * bf2f(h0.w);
  ushort4 o;
  o.x = f2bf(ax); o.y = f2bf(ay); o.z = f2bf(az); o.w = f2bf(aw);
  *(ushort4*)&mb[(size_t)node * 256 + lane * 4] = o;
}

// ------------- transpose + cast: dst[c][r] = bf16(src[r][c]), src is R x C, batched over z -------------
__global__ void k_tcast(const float* __restrict__ src0, unsigned short* __restrict__ dst0,
                        int R, int C) {
  const float* src = src0 + (size_t)blockIdx.z * R * C;
  unsigned short* dst = dst0 + (size_t)blockIdx.z * R * C;
  __shared__ float tile[32][33];
  int bx = blockIdx.x * 32, by = blockIdx.y * 32;
  int tx = threadIdx.x & 31, ty = threadIdx.x >> 5;  // 32 x 8
  for (int i = 0; i < 32; i += 8) {
    int r = by + ty + i, c = bx + tx;
    tile[ty + i][tx] = (r < R && c < C) ? src[(size_t)r * C + c] : 0.f;
  }
  __syncthreads();
  for (int i = 0; i < 32; i += 8) {
    int c = bx + ty + i, r = by + tx;
    if (c < C && r < R) dst[(size_t)c * R + r] = f2bf(tile[tx][ty + i]);
  }
}

// ---------------- bf16 MFMA GEMM: block tile 64 x 256, BK=32 ----------------
// Round-0 geometry; staging via global_load_lds (16B) into linear LDS with
// slot-XOR swizzle: physical 16B slot p of row r holds logical slot p^(r&3).
// Source is inverse-swizzled per-lane global addr; reads apply the same XOR.
// EPI 0: outf = A@B + bias (fp32) and outb = bf16(same)
// EPI 1: outb = bf16(relu(LN(A@B + bias; g,be)))
// EPI 2: v = relu(LN(A@B+bias; g,be)) + resid; outf = v (if WF); outb = bf16(v)
template <int KTOT, int EPI, bool AF32, bool WF>
__global__ __launch_bounds__(256) void k_mm(
    const void* __restrict__ Ap, const unsigned short* __restrict__ Bt,
    const float* __restrict__ bias, const float* __restrict__ g,
    const float* __restrict__ be, const float* __restrict__ resid,
    float* __restrict__ outf, unsigned short* __restrict__ outb) {
  __shared__ unsigned short As[64 * 32];   // 4 KB, linear (swizzled slots)
  __shared__ unsigned short Bs[256 * 32];  // 16 KB, linear (swizzled slots)
  __shared__ float redS[4][64];
  __shared__ float redQ[4][64];
  __shared__ float mvM[64], mvI[64];
  int t = threadIdx.x, lane = t & 63, wave = t >> 6;
  int row0 = blockIdx.x * 64;
  f32x4 acc[4][4];
#pragma unroll
  for (int i = 0; i < 4; i++)
#pragma unroll
    for (int j = 0; j < 4; j++) acc[i][j] = (f32x4)(0.f);
  int m16 = lane & 15, kq = lane >> 4;

  // staging geometry: A slot = t (row t>>2, phys slot t&3); per-wave dest base
  int arow = t >> 2, a2 = t & 3;
  int asl = a2 ^ (arow & 3);                  // logical k-slot this lane fetches
  int agr = row0 + arow; if (agr >= NN) agr = NN - 1;
  unsigned short* AsDst = &As[wave * 512];    // wave covers slots w*64..w*64+63
  // B: 4 instrs/thread; instr j covers slots j*256 + w*64 + lane
  int brow_[4], bsl_[4];
#pragma unroll
  for (int j = 0; j < 4; j++) {
    int s = j * 256 + t;
    brow_[j] = s >> 2;
    bsl_[j] = (s & 3) ^ (brow_[j] & 3);
  }

  for (int k0 = 0; k0 < KTOT; k0 += 32) {
    if (AF32) {
      const float* Af = (const float*)Ap + (size_t)agr * KTOT + k0 + asl * 8;
      float4 f0 = *(const float4*)Af;
      float4 f1 = *(const float4*)(Af + 4);
      short8 v;
      v[0] = (short)f2bf(f0.x); v[1] = (short)f2bf(f0.y);
      v[2] = (short)f2bf(f0.z); v[3] = (short)f2bf(f0.w);
      v[4] = (short)f2bf(f1.x); v[5] = (short)f2bf(f1.y);
      v[6] = (short)f2bf(f1.z); v[7] = (short)f2bf(f1.w);
      *(short8*)&As[arow * 32 + a2 * 8] = v;
    } else {
      ldsload16((const unsigned short*)Ap + (size_t)agr * KTOT + k0 + asl * 8, AsDst);
    }
#pragma unroll
    for (int j = 0; j < 4; j++)
      ldsload16(&Bt[(size_t)brow_[j] * KTOT + k0 + bsl_[j] * 8],
                &Bs[(j * 256 + wave * 64) * 8]);
    __syncthreads();
    short8 a[4], b[4];
#pragma unroll
    for (int rt = 0; rt < 4; rt++) {
      int row = rt * 16 + m16;
      a[rt] = *(const short8*)&As[row * 32 + ((kq ^ (row & 3)) * 8)];
    }
#pragma unroll
    for (int ct = 0; ct < 4; ct++) {
      int row = wave * 64 + ct * 16 + m16;
      b[ct] = *(const short8*)&Bs[row * 32 + ((kq ^ (row & 3)) * 8)];
    }
#pragma unroll
    for (int rt = 0; rt < 4; rt++)
#pragma unroll
      for (int ct = 0; ct < 4; ct++)
        acc[rt][ct] = __builtin_amdgcn_mfma_f32_16x16x32_bf16(a[rt], b[ct], acc[rt][ct], 0, 0, 0);
    __syncthreads();
  }

  int colbase = wave * 64 + m16;
  float bv[4];
#pragma unroll
  for (int ct = 0; ct < 4; ct++) bv[ct] = bias[colbase + ct * 16];

  if (EPI == 0) {
#pragma unroll
    for (int rt = 0; rt < 4; rt++)
#pragma unroll
      for (int reg = 0; reg < 4; reg++) {
        int r = row0 + rt * 16 + kq * 4 + reg;
        if (r < NN) {
#pragma unroll
          for (int ct = 0; ct < 4; ct++) {
            float v = acc[rt][ct][reg] + bv[ct];
            outf[(size_t)r * 256 + colbase + ct * 16] = v;
            outb[(size_t)r * 256 + colbase + ct * 16] = f2bf(v);
          }
        }
      }
    return;
  }

  float s[4][4], q[4][4];
#pragma unroll
  for (int rt = 0; rt < 4; rt++)
#pragma unroll
    for (int reg = 0; reg < 4; reg++) { s[rt][reg] = 0.f; q[rt][reg] = 0.f; }
#pragma unroll
  for (int rt = 0; rt < 4; rt++)
#pragma unroll
    for (int ct = 0; ct < 4; ct++)
#pragma unroll
      for (int reg = 0; reg < 4; reg++) {
        float v = acc[rt][ct][reg] + bv[ct];
        acc[rt][ct][reg] = v;
        s[rt][reg] += v;
        q[rt][reg] += v * v;
      }
#pragma unroll
  for (int off = 1; off < 16; off <<= 1) {
#pragma unroll
    for (int rt = 0; rt < 4; rt++)
#pragma unroll
      for (int reg = 0; reg < 4; reg++) {
        s[rt][reg] += __shfl_xor(s[rt][reg], off, 64);
        q[rt][reg] += __shfl_xor(q[rt][reg], off, 64);
      }
  }
  if (m16 == 0) {
#pragma unroll
    for (int rt = 0; rt < 4; rt++)
#pragma unroll
      for (int reg = 0; reg < 4; reg++) {
        redS[wave][rt * 16 + kq * 4 + reg] = s[rt][reg];
        redQ[wave][rt * 16 + kq * 4 + reg] = q[rt][reg];
      }
  }
  __syncthreads();
  if (t < 64) {
    float ss = redS[0][t] + redS[1][t] + redS[2][t] + redS[3][t];
    float qq = redQ[0][t] + redQ[1][t] + redQ[2][t] + redQ[3][t];
    float mean = ss * (1.f / 256.f);
    float var = qq * (1.f / 256.f) - mean * mean;
    mvM[t] = mean;
    mvI[t] = rsqrtf(var + 1e-5f);
  }
  __syncthreads();
  float gv[4], bev[4];
#pragma unroll
  for (int ct = 0; ct < 4; ct++) { gv[ct] = g[colbase + ct * 16]; bev[ct] = be[colbase + ct * 16]; }
#pragma unroll
  for (int rt = 0; rt < 4; rt++)
#pragma unroll
    for (int reg = 0; reg < 4; reg++) {
      int rr = rt * 16 + kq * 4 + reg;
      int r = row0 + rr;
      if (r >= NN) continue;
      float mean = mvM[rr], inv = mvI[rr];
#pragma unroll
      for (int ct = 0; ct < 4; ct++) {
        int col = colbase + ct * 16;
        float val = fmaxf((acc[rt][ct][reg] - mean) * inv * gv[ct] + bev[ct], 0.f);
        if (EPI == 2) {
          val += resid[(size_t)r * 256 + col];
          if (WF) outf[(size_t)r * 256 + col] = val;
        }
        outb[(size_t)r * 256 + col] = f2bf(val);
      }
    }
}

// ------------- attention logits, 4 heads fused: block 64 rows x (4x128) cols -------------
// wave w computes head w; same global_load_lds + swizzle staging.
__global__ __launch_bounds__(256) void k_att(const unsigned short* __restrict__ hb,
    const unsigned short* __restrict__ W1T, const float* __restrict__ b1,
    const float* __restrict__ W2, const float* __restrict__ b2,
    float* __restrict__ logitsT) {
  __shared__ unsigned short As[64 * 32];    // 4 KB
  __shared__ unsigned short Bs[512 * 32];   // 32 KB
  int t = threadIdx.x, lane = t & 63, wave = t >> 6;  // wave == head
  int row0 = blockIdx.x * 64;
  f32x4 acc[4][8];
#pragma unroll
  for (int i = 0; i < 4; i++)
#pragma unroll
    for (int j = 0; j < 8; j++) acc[i][j] = (f32x4)(0.f);
  int m16 = lane & 15, kq = lane >> 4;
  int arow = t >> 2, a2 = t & 3;
  int asl = a2 ^ (arow & 3);
  int agr = row0 + arow; if (agr >= NN) agr = NN - 1;
  unsigned short* AsDst = &As[wave * 512];
  int brow_[8], bsl_[8];
#pragma unroll
  for (int j = 0; j < 8; j++) {
    int s = j * 256 + t;
    brow_[j] = s >> 2;
    bsl_[j] = (s & 3) ^ (brow_[j] & 3);
  }
  for (int k0 = 0; k0 < 256; k0 += 32) {
    ldsload16(&hb[(size_t)agr * 256 + k0 + asl * 8], AsDst);
#pragma unroll
    for (int j = 0; j < 8; j++)
      ldsload16(&W1T[(size_t)brow_[j] * 256 + k0 + bsl_[j] * 8],
                &Bs[(j * 256 + wave * 64) * 8]);
    __syncthreads();
    short8 a[4];
#pragma unroll
    for (int rt = 0; rt < 4; rt++) {
      int row = rt * 16 + m16;
      a[rt] = *(const short8*)&As[row * 32 + ((kq ^ (row & 3)) * 8)];
    }
#pragma unroll
    for (int ct = 0; ct < 8; ct++) {
      int row = wave * 128 + ct * 16 + m16;
      short8 b = *(const short8*)&Bs[row * 32 + ((kq ^ (row & 3)) * 8)];
#pragma unroll
      for (int rt = 0; rt < 4; rt++)
        acc[rt][ct] = __builtin_amdgcn_mfma_f32_16x16x32_bf16(a[rt], b, acc[rt][ct], 0, 0, 0);
    }
    __syncthreads();
  }
  const float* b1k = b1 + wave * 128;
  const float* w2k = W2 + wave * 128;
  float p[4][4];
#pragma unroll
  for (int rt = 0; rt < 4; rt++)
#pragma unroll
    for (int reg = 0; reg < 4; reg++) p[rt][reg] = 0.f;
#pragma unroll
  for (int ct = 0; ct < 8; ct++) {
    int col = ct * 16 + m16;
    float b1v = b1k[col], w2v = w2k[col];
#pragma unroll
    for (int rt = 0; rt < 4; rt++)
#pragma unroll
      for (int reg = 0; reg < 4; reg++) {
        float xv = acc[rt][ct][reg] + b1v;
        xv = fminf(fmaxf(xv, -10.f), 10.f);
        float ex = __expf(2.f * xv);
        p[rt][reg] += (ex - 1.f) / (ex + 1.f) * w2v;
      }
  }
#pragma unroll
  for (int off = 1; off < 16; off <<= 1)
#pragma unroll
    for (int rt = 0; rt < 4; rt++)
#pragma unroll
      for (int reg = 0; reg < 4; reg++) p[rt][reg] += __shfl_xor(p[rt][reg], off, 64);
  if (m16 == 0) {
    float b2v = b2[wave];
#pragma unroll
    for (int rt = 0; rt < 4; rt++)
#pragma unroll
      for (int reg = 0; reg < 4; reg++) {
        int r = row0 + rt * 16 + kq * 4 + reg;
        if (r < NN) logitsT[(size_t)wave * NN + r] = p[rt][reg] + b2v;
      }
  }
}

// ---------------- softmax over N per head ----------------
__global__ void k_smax1(const float* __restrict__ logitsT, float* __restrict__ pmax,
                        float* __restrict__ psum) {
  int k = blockIdx.y;
  int tid = threadIdx.x;
  const float* L = logitsT + (size_t)k * NN;
  __shared__ float sm[256];
  float mx = -1e30f;
  for (int i = blockIdx.x * 256 + tid; i < NN; i += 128 * 256) mx = fmaxf(mx, L[i]);
  sm[tid] = mx; __syncthreads();
  for (int o = 128; o >= 1; o >>= 1) { if (tid < o) sm[tid] = fmaxf(sm[tid], sm[tid + o]); __syncthreads(); }
  float bmax = sm[0];
  __syncthreads();
  float s = 0.f;
  for (int i = blockIdx.x * 256 + tid; i < NN; i += 128 * 256) s += __expf(L[i] - bmax);
  sm[tid] = s; __syncthreads();
  for (int o = 128; o >= 1; o >>= 1) { if (tid < o) sm[tid] += sm[tid + o]; __syncthreads(); }
  if (tid == 0) { pmax[k * 128 + blockIdx.x] = bmax; psum[k * 128 + blockIdx.x] = sm[0]; }
}

__global__ void k_smax2(const float* __restrict__ pmax, const float* __restrict__ psum,
                        float* __restrict__ gs) {
  int k = blockIdx.x;
  int tid = threadIdx.x;  // 128
  __shared__ float sm[128], sv[128];
  float m = pmax[k * 128 + tid];
  sm[tid] = m; __syncthreads();
  for (int o = 64; o >= 1; o >>= 1) { if (tid < o) sm[tid] = fmaxf(sm[tid], sm[tid + o]); __syncthreads(); }
  float gm = sm[0];
  __syncthreads();
  sv[tid] = psum[k * 128 + tid] * __expf(m - gm);
  __syncthreads();
  for (int o = 64; o >= 1; o >>= 1) { if (tid < o) sv[tid] += sv[tid + o]; __syncthreads(); }
  if (tid == 0) { gs[k * 2] = gm; gs[k * 2 + 1] = sv[0]; }
}

// ------------- a = softmax, attn output, z[k][d] partials -------------
__global__ void k_attnz(const float* __restrict__ logitsT, const float* __restrict__ gs,
                        const unsigned short* __restrict__ hb, float* __restrict__ out_attn,
                        float* __restrict__ z) {
  int n0 = blockIdx.x * 128;
  int tid = threadIdx.x;
  __shared__ float a[4][128];
  for (int i = tid; i < 512; i += 256) {
    int k = i >> 7, n = i & 127;
    float v = 0.f;
    if (n0 + n < NN) v = __expf(logitsT[(size_t)k * NN + n0 + n] - gs[k * 2]) / gs[k * 2 + 1];
    a[k][n] = v;
  }
  __syncthreads();
  for (int i = tid; i < 512; i += 256) {
    int n = i >> 2, k = i & 3;
    if (n0 + n < NN) out_attn[(size_t)(n0 + n) * 4 + k] = a[k][n];
  }
  float z0 = 0.f, z1 = 0.f, z2 = 0.f, z3 = 0.f;
  int d = tid;  // 256 dims
  int nmax = NN - n0; if (nmax > 128) nmax = 128;
  for (int n = 0; n < nmax; n++) {
    float hv = bf2f(hb[(size_t)(n0 + n) * 256 + d]);
    z0 += a[0][n] * hv; z1 += a[1][n] * hv; z2 += a[2][n] * hv; z3 += a[3][n] * hv;
  }
  atomicAdd(&z[0 * 256 + d], z0);
  atomicAdd(&z[1 * 256 + d], z1);
  atomicAdd(&z[2 * 256 + d], z2);
  atomicAdd(&z[3 * 256 + d], z3);
}

// ---------------- tiny classifier ----------------
__global__ void k_cls(const float* __restrict__ z, const float* __restrict__ Wc1,
                      const float* __restrict__ bc1, const float* __restrict__ g1,
                      const float* __restrict__ b1, const float* __restrict__ Wc2,
                      const float* __restrict__ bc2, const float* __restrict__ g2,
                      const float* __restrict__ b2, const float* __restrict__ Wc3,
                      const float* __restrict__ bc3, float* __restrict__ out) {
  int tid = threadIdx.x;  // 256
  __shared__ float za[256];
  __shared__ float buf[256];
  __shared__ float c1s[128];
  __shared__ float c2s[64];
  za[tid] = 0.25f * (z[tid] + z[256 + tid] + z[512 + tid] + z[768 + tid]);
  __syncthreads();
  float v1 = 0.f;
  if (tid < 128) {
    for (int d = 0; d < 256; d++) v1 += za[d] * Wc1[d * 128 + tid];
    v1 += bc1[tid];
  }
  buf[tid] = (tid < 128) ? v1 : 0.f; __syncthreads();
  for (int o = 128; o >= 1; o >>= 1) { if (tid < o) buf[tid] += buf[tid + o]; __syncthreads(); }
  float mean1 = buf[0] * (1.f / 128.f);
  __syncthreads();
  buf[tid] = (tid < 128) ? (v1 - mean1) * (v1 - mean1) : 0.f; __syncthreads();
  for (int o = 128; o >= 1; o >>= 1) { if (tid < o) buf[tid] += buf[tid + o]; __syncthreads(); }
  float inv1 = rsqrtf(buf[0] * (1.f / 128.f) + 1e-5f);
  __syncthreads();
  if (tid < 128) c1s[tid] = fmaxf((v1 - mean1) * inv1 * g1[tid] + b1[tid], 0.f);
  __syncthreads();
  float v2 = 0.f;
  if (tid < 64) {
    for (int d = 0; d < 128; d++) v2 += c1s[d] * Wc2[d * 64 + tid];
    v2 += bc2[tid];
  }
  buf[tid] = (tid < 64) ? v2 : 0.f; __syncthreads();
  for (int o = 128; o >= 1; o >>= 1) { if (tid < o) buf[tid] += buf[tid + o]; __syncthreads(); }
  float mean2 = buf[0] * (1.f / 64.f);
  __syncthreads();
  buf[tid] = (tid < 64) ? (v2 - mean2) * (v2 - mean2) : 0.f; __syncthreads();
  for (int o = 128; o >= 1; o >>= 1) { if (tid < o) buf[tid] += buf[tid + o]; __syncthreads(); }
  float inv2 = rsqrtf(buf[0] * (1.f / 64.f) + 1e-5f);
  __syncthreads();
  if (tid < 64) c2s[tid] = fmaxf((v2 - mean2) * inv2 * g2[tid] + b2[tid], 0.f);
  __syncthreads();
  if (tid < 7) {
    float l = 0.f;
    for (int d = 0; d < 64; d++) l += c2s[d] * Wc3[d * 7 + tid];
    buf[tid] = l + bc3[tid];
  }
  __syncthreads();
  if (tid == 0) {
    float mx = -1e30f;
    for (int i = 0; i < 7; i++) mx = fmaxf(mx, buf[i]);
    float s = 0.f;
    for (int i = 0; i < 7; i++) s += __expf(buf[i] - mx);
    for (int i = 0; i < 7; i++) out[i] = __expf(buf[i] - mx) / s;
  }
}

extern "C" void kernel_launch(void* const* d_in, const int* in_sizes, int n_in,
                              void* d_out, int out_size, void* d_ws, size_t ws_size,
                              hipStream_t stream) {
  const float* x       = (const float*)d_in[0];
  const int*   ei      = (const int*)d_in[1];
  const float* W_in    = (const float*)d_in[2];
  const float* b_in    = (const float*)d_in[3];
  const float* gin_W1  = (const float*)d_in[4];
  const float* gin_b1  = (const float*)d_in[5];
  const float* gin_lng = (const float*)d_in[6];
  const float* gin_lnb = (const float*)d_in[7];
  const float* gin_W2  = (const float*)d_in[8];
  const float* gin_b2  = (const float*)d_in[9];
  const float* eps     = (const float*)d_in[10];
  const float* ln_g    = (const float*)d_in[11];
  const float* ln_b    = (const float*)d_in[12];
  const float* att_W1  = (const float*)d_in[13];
  const float* att_b1  = (const float*)d_in[14];
  const float* att_W2  = (const float*)d_in[15];
  const float* att_b2  = (const float*)d_in[16];
  const float* Wc1     = (const float*)d_in[17];
  const float* bc1     = (const float*)d_in[18];
  const float* lnc1_g  = (const float*)d_in[19];
  const float* lnc1_b  = (const float*)d_in[20];
  const float* Wc2     = (const float*)d_in[21];
  const float* bc2     = (const float*)d_in[22];
  const float* lnc2_g  = (const float*)d_in[23];
  const float* lnc2_b  = (const float*)d_in[24];
  const float* Wc3     = (const float*)d_in[25];
  const float* bc3     = (const float*)d_in[26];
  float* out = (float*)d_out;
  (void)in_sizes; (void)n_in; (void)out_size; (void)ws_size;

  char* wsb = (char*)d_ws;
  size_t off = 0;
  auto alloc = [&](size_t bytes) {
    char* p = wsb + off;
    off += (bytes + 255) & ~(size_t)255;
    return p;
  };
  float*          h       = (float*)alloc((size_t)NN * HH * 4);
  unsigned short* hb      = (unsigned short*)alloc((size_t)NN * HH * 2);
  unsigned short* mb1     = (unsigned short*)alloc((size_t)NN * HH * 2);
  unsigned short* mb2     = (unsigned short*)alloc((size_t)NN * HH * 2);
  unsigned short* WinT    = (unsigned short*)alloc((size_t)HH * FF * 2);
  unsigned short* g1T     = (unsigned short*)alloc((size_t)2 * HH * HH * 2);
  unsigned short* g2T     = (unsigned short*)alloc((size_t)2 * HH * HH * 2);
  unsigned short* aW1T    = (unsigned short*)alloc((size_t)4 * 128 * HH * 2);
  float*          logitsT = (float*)alloc((size_t)4 * NN * 4);
  int*            deg     = (int*)alloc((size_t)NN * 4);
  int*            rowptr  = (int*)alloc((size_t)(NN + 1) * 4);
  int*            cursor  = (int*)alloc((size_t)NN * 4);
  int*            csr_src = (int*)alloc((size_t)NE * 4);
  float*          pmax    = (float*)alloc(4 * 128 * 4);
  float*          psum    = (float*)alloc(4 * 128 * 4);
  float*          gs      = (float*)alloc(8 * 4);
  float*          z       = (float*)alloc(4 * 256 * 4);

  const int* srcv = ei;
  const int* dstv = ei + NE;

  // weight transposes + casts (tiny, batched over blockIdx.z)
  k_tcast<<<dim3((HH + 31) / 32, (FF + 31) / 32, 1), 256, 0, stream>>>(W_in, WinT, FF, HH);
  k_tcast<<<dim3(8, 8, 2), 256, 0, stream>>>(gin_W1, g1T, HH, HH);
  k_tcast<<<dim3(8, 8, 2), 256, 0, stream>>>(gin_W2, g2T, HH, HH);
  k_tcast<<<dim3(4, 8, 4), 256, 0, stream>>>(att_W1, aW1T, HH, 128);

  // CSR build
  hipMemsetAsync(deg, 0, (size_t)NN * 4, stream);
  hipMemsetAsync(z, 0, 4 * 256 * 4, stream);
  k_count<<<(NE + 255) / 256, 256, 0, stream>>>(dstv, deg);
  k_scan<<<1, 1024, 0, stream>>>(deg, rowptr);
  hipMemcpyAsync(cursor, rowptr, (size_t)NN * 4, hipMemcpyDeviceToDevice, stream);
  k_scatter<<<(NE + 255) / 256, 256, 0, stream>>>(srcv, dstv, cursor, csr_src);

  int gblocks = (NN + 63) / 64;  // 782
  // h = x @ W_in + b_in  (fp32 A cast to bf16 in staging); also emit hb
  k_mm<FF, 0, true, true><<<gblocks, 256, 0, stream>>>(x, WinT, b_in, nullptr, nullptr, nullptr, h, hb);

  for (int l = 0; l < 2; l++) {
    k_agg<<<(NN + 3) / 4, 256, 0, stream>>>(hb, rowptr, csr_src, eps, l, mb1);
    // mb2 = bf16(relu(LN(mb1 @ W1 + b1)))
    k_mm<HH, 1, false, true><<<gblocks, 256, 0, stream>>>(mb1, g1T + (size_t)l * HH * HH,
        gin_b1 + l * HH, gin_lng + l * HH, gin_lnb + l * HH, nullptr, nullptr, mb2);
    // h = relu(LN(mb2 @ W2 + b2)) + h ; hb = bf16(h). Last layer: skip fp32 h write.
    if (l == 0)
      k_mm<HH, 2, false, true><<<gblocks, 256, 0, stream>>>(mb2, g2T + (size_t)l * HH * HH,
          gin_b2 + l * HH, ln_g + l * HH, ln_b + l * HH, h, h, hb);
    else
      k_mm<HH, 2, false, false><<<gblocks, 256, 0, stream>>>(mb2, g2T + (size_t)l * HH * HH,
          gin_b2 + l * HH, ln_g + l * HH, ln_b + l * HH, h, nullptr, hb);
  }

  k_att<<<gblocks, 256, 0, stream>>>(hb, aW1T, att_b1, att_W2, att_b2, logitsT);
  k_smax1<<<dim3(128, 4), 256, 0, stream>>>(logitsT, pmax, psum);
  k_smax2<<<4, 128, 0, stream>>>(pmax, psum, gs);
  k_attnz<<<(NN + 127) / 128, 256, 0, stream>>>(logitsT, gs, hb, out + 7, z);
  k_cls<<<1, 256, 0, stream>>>(z, Wc1, bc1, lnc1_g, lnc1_b, Wc2, bc2, lnc2_g, lnc2_b,
                               Wc3, bc3, out);
}

// Round 6
// 931.361 us; speedup vs baseline: 1.2587x; 1.0041x over previous
//
#include <hip/hip_runtime.h>
#include <math.h>

#define NN 50000
#define NE 800000
#define FF 768
#define HH 256

typedef __attribute__((ext_vector_type(8))) short short8;
typedef __attribute__((ext_vector_type(4))) float f32x4;

__device__ inline unsigned short f2bf(float f) {
  unsigned u = __float_as_uint(f);
  u = u + 0x7fffu + ((u >> 16) & 1u);
  return (unsigned short)(u >> 16);
}
__device__ inline float bf2f(unsigned short b) {
  return __uint_as_float(((unsigned)b) << 16);
}

// async global->LDS, 16B per lane. Dest is wave-uniform base + lane*16 (HW).
__device__ __forceinline__ void ldsload16(const unsigned short* g, unsigned short* l) {
  __builtin_amdgcn_global_load_lds(
      (const __attribute__((address_space(1))) void*)g,
      (__attribute__((address_space(3))) void*)l, 16, 0, 0);
}

// ---------------- CSR build ----------------
__global__ void k_count(const int* __restrict__ dstv, int* __restrict__ deg) {
  int e = blockIdx.x * 256 + threadIdx.x;
  if (e < NE) atomicAdd(&deg[dstv[e]], 1);
}

// single-block thread-coarsened scan: 1024 threads x 49 elems
__global__ void k_scan(const int* __restrict__ deg, int* __restrict__ rowptr) {
  const int CH = 49;  // 1024*49 = 50176 >= NN
  int tid = threadIdx.x;
  int lane = tid & 63, w = tid >> 6;
  int base = tid * CH;
  int sum = 0;
  for (int i = 0; i < CH; i++) {
    int idx = base + i;
    if (idx < NN) sum += deg[idx];
  }
  int incl = sum;
  for (int off = 1; off < 64; off <<= 1) {
    int tv = __shfl_up(incl, off, 64);
    if (lane >= off) incl += tv;
  }
  __shared__ int ws[16];
  if (lane == 63) ws[w] = incl;
  __syncthreads();
  if (tid == 0) {
    int c = 0;
    for (int i = 0; i < 16; i++) { int tv = ws[i]; ws[i] = c; c += tv; }
  }
  __syncthreads();
  int run = ws[w] + (incl - sum);
  if (tid == 0) rowptr[0] = 0;
  for (int i = 0; i < CH; i++) {
    int idx = base + i;
    if (idx < NN) { run += deg[idx]; rowptr[idx + 1] = run; }
  }
}

__global__ void k_scatter(const int* __restrict__ srcv, const int* __restrict__ dstv,
                          int* __restrict__ cursor, int* __restrict__ csr_src) {
  int e = blockIdx.x * 256 + threadIdx.x;
  if (e < NE) {
    int d = dstv[e];
    int pos = atomicAdd(&cursor[d], 1);
    csr_src[pos] = srcv[e];
  }
}

// ------------- aggregation (bf16 gather): mb = bf16((1+eps)*hb + sum hb[src]) -------------
__global__ void k_agg(const unsigned short* __restrict__ hb, const int* __restrict__ rowptr,
                      const int* __restrict__ csr_src, const float* __restrict__ eps,
                      int layer, unsigned short* __restrict__ mb) {
  int node = (blockIdx.x * blockDim.x + threadIdx.x) >> 6;
  int lane = threadIdx.x & 63;
  if (node >= NN) return;
  int beg = rowptr[node], end = rowptr[node + 1];
  const ushort4* hv = (const ushort4*)hb;
  float ax = 0.f, ay = 0.f, az = 0.f, aw = 0.f;
  for (int e = beg; e < end; ++e) {
    int s = csr_src[e];
    ushort4 v = hv[(size_t)s * 64 + lane];
    ax += bf2f(v.x); ay += bf2f(v.y); az += bf2f(v.z); aw += bf2f(v.w);
  }
  float ep = 1.0f + eps[layer];
  ushort4 h0 = hv[(size_t)node * 64 + lane];
  ax += ep * bf2f(h0.x); ay += ep * bf2f(h0.y);
  az += ep * bf2f(h0.z); aw += ep * bf2f(h0.w);
  ushort4 o;
  o.x = f2bf(ax); o.y = f2bf(ay); o.z = f2bf(az); o.w = f2bf(aw);
  *(ushort4*)&mb[(size_t)node * 256 + lane * 4] = o;
}

// ------------- transpose + cast: dst[c][r] = bf16(src[r][c]), src is R x C, batched over z -------------
__global__ void k_tcast(const float* __restrict__ src0, unsigned short* __restrict__ dst0,
                        int R, int C) {
  const float* src = src0 + (size_t)blockIdx.z * R * C;
  unsigned short* dst = dst0 + (size_t)blockIdx.z * R * C;
  __shared__ float tile[32][33];
  int bx = blockIdx.x * 32, by = blockIdx.y * 32;
  int tx = threadIdx.x & 31, ty = threadIdx.x >> 5;  // 32 x 8
  for (int i = 0; i < 32; i += 8) {
    int r = by + ty + i, c = bx + tx;
    tile[ty + i][tx] = (r < R && c < C) ? src[(size_t)r * C + c] : 0.f;
  }
  __syncthreads();
  for (int i = 0; i < 32; i += 8) {
    int c = bx + ty + i, r = by + tx;
    if (c < C && r < R) dst[(size_t)c * R + r] = f2bf(tile[tx][ty + i]);
  }
}

// ---------------- input projection GEMM: K=768, fp32 A cast in staging (R5 path) ----------------
__global__ __launch_bounds__(256) void k_mmff(
    const float* __restrict__ x, const unsigned short* __restrict__ Bt,
    const float* __restrict__ bias, float* __restrict__ outf,
    unsigned short* __restrict__ outb) {
  __shared__ unsigned short As[64 * 32];   // 4 KB, linear (swizzled slots)
  __shared__ unsigned short Bs[256 * 32];  // 16 KB, linear (swizzled slots)
  int t = threadIdx.x, lane = t & 63, wave = t >> 6;
  int row0 = blockIdx.x * 64;
  f32x4 acc[4][4];
#pragma unroll
  for (int i = 0; i < 4; i++)
#pragma unroll
    for (int j = 0; j < 4; j++) acc[i][j] = (f32x4)(0.f);
  int m16 = lane & 15, kq = lane >> 4;
  int arow = t >> 2, a2 = t & 3;
  int asl = a2 ^ (arow & 3);
  int agr = row0 + arow; if (agr >= NN) agr = NN - 1;
  int brow_[4], bsl_[4];
#pragma unroll
  for (int j = 0; j < 4; j++) {
    int s = j * 256 + t;
    brow_[j] = s >> 2;
    bsl_[j] = (s & 3) ^ (brow_[j] & 3);
  }
  for (int k0 = 0; k0 < FF; k0 += 32) {
    {
      const float* Af = x + (size_t)agr * FF + k0 + asl * 8;
      float4 f0 = *(const float4*)Af;
      float4 f1 = *(const float4*)(Af + 4);
      short8 v;
      v[0] = (short)f2bf(f0.x); v[1] = (short)f2bf(f0.y);
      v[2] = (short)f2bf(f0.z); v[3] = (short)f2bf(f0.w);
      v[4] = (short)f2bf(f1.x); v[5] = (short)f2bf(f1.y);
      v[6] = (short)f2bf(f1.z); v[7] = (short)f2bf(f1.w);
      *(short8*)&As[arow * 32 + a2 * 8] = v;
    }
#pragma unroll
    for (int j = 0; j < 4; j++)
      ldsload16(&Bt[(size_t)brow_[j] * FF + k0 + bsl_[j] * 8],
                &Bs[(j * 256 + wave * 64) * 8]);
    __syncthreads();
    short8 a[4], b[4];
#pragma unroll
    for (int rt = 0; rt < 4; rt++) {
      int row = rt * 16 + m16;
      a[rt] = *(const short8*)&As[row * 32 + ((kq ^ (row & 3)) * 8)];
    }
#pragma unroll
    for (int ct = 0; ct < 4; ct++) {
      int row = wave * 64 + ct * 16 + m16;
      b[ct] = *(const short8*)&Bs[row * 32 + ((kq ^ (row & 3)) * 8)];
    }
#pragma unroll
    for (int rt = 0; rt < 4; rt++)
#pragma unroll
      for (int ct = 0; ct < 4; ct++)
        acc[rt][ct] = __builtin_amdgcn_mfma_f32_16x16x32_bf16(a[rt], b[ct], acc[rt][ct], 0, 0, 0);
    __syncthreads();
  }
  int colbase = wave * 64 + m16;
  float bv[4];
#pragma unroll
  for (int ct = 0; ct < 4; ct++) bv[ct] = bias[colbase + ct * 16];
#pragma unroll
  for (int rt = 0; rt < 4; rt++)
#pragma unroll
    for (int reg = 0; reg < 4; reg++) {
      int r = row0 + rt * 16 + kq * 4 + reg;
      if (r < NN) {
#pragma unroll
        for (int ct = 0; ct < 4; ct++) {
          float v = acc[rt][ct][reg] + bv[ct];
          outf[(size_t)r * 256 + colbase + ct * 16] = v;
          outb[(size_t)r * 256 + colbase + ct * 16] = f2bf(v);
        }
      }
    }
}

// ---------------- H-GEMM (K=256, bf16 A): counted-vmcnt double-buffered pipeline ----------------
// Per chunk: wait vmcnt(5) (next chunk's 5 global_load_lds stay in flight), raw barrier,
// ds_read+MFMA, barrier, issue chunk c+2 into freed buffer. Never vmcnt(0) until last chunk.
// EPI 1: outb = bf16(relu(LN(A@B + bias; g,be)))
// EPI 2: v = relu(LN(A@B+bias; g,be)) + resid; outf = v (if WF); outb = bf16(v)
template <int EPI, bool WF>
__global__ __launch_bounds__(256) void k_mmh(
    const unsigned short* __restrict__ Ab, const unsigned short* __restrict__ Bt,
    const float* __restrict__ bias, const float* __restrict__ g,
    const float* __restrict__ be, const float* __restrict__ resid,
    float* __restrict__ outf, unsigned short* __restrict__ outb) {
  __shared__ unsigned short As[2][64 * 32];   // 2 x 4 KB
  __shared__ unsigned short Bs[2][256 * 32];  // 2 x 16 KB
  __shared__ float redS[4][64];
  __shared__ float redQ[4][64];
  __shared__ float mvM[64], mvI[64];
  int t = threadIdx.x, lane = t & 63, wave = t >> 6;
  int row0 = blockIdx.x * 64;
  int m16 = lane & 15, kq = lane >> 4;
  int arow = t >> 2, a2 = t & 3;
  int asl = a2 ^ (arow & 3);
  int agr = row0 + arow; if (agr >= NN) agr = NN - 1;
  const unsigned short* Ag = Ab + (size_t)agr * 256 + asl * 8;
  int brow_[4], bsl_[4];
#pragma unroll
  for (int j = 0; j < 4; j++) {
    int s = j * 256 + t;
    brow_[j] = s >> 2;
    bsl_[j] = (s & 3) ^ (brow_[j] & 3);
  }
  // stage chunk c into buffer p: exactly 5 global_load_lds per thread
  auto stage = [&](int c, int p) {
    int k0 = c * 32;
    ldsload16(Ag + k0, &As[p][wave * 512]);
#pragma unroll
    for (int j = 0; j < 4; j++)
      ldsload16(&Bt[(size_t)brow_[j] * 256 + k0 + bsl_[j] * 8],
                &Bs[p][(j * 256 + wave * 64) * 8]);
  };

  f32x4 acc[4][4];
#pragma unroll
  for (int i = 0; i < 4; i++)
#pragma unroll
    for (int j = 0; j < 4; j++) acc[i][j] = (f32x4)(0.f);

  stage(0, 0);
  stage(1, 1);
#pragma unroll
  for (int c = 0; c < 8; c++) {
    if (c < 7) asm volatile("s_waitcnt vmcnt(5)" ::: "memory");
    else       asm volatile("s_waitcnt vmcnt(0)" ::: "memory");
    __builtin_amdgcn_s_barrier();
    asm volatile("" ::: "memory");
    const unsigned short* Ap = As[c & 1];
    const unsigned short* Bp = Bs[c & 1];
    short8 a[4], b[4];
#pragma unroll
    for (int rt = 0; rt < 4; rt++) {
      int row = rt * 16 + m16;
      a[rt] = *(const short8*)&Ap[row * 32 + ((kq ^ (row & 3)) * 8)];
    }
#pragma unroll
    for (int ct = 0; ct < 4; ct++) {
      int row = wave * 64 + ct * 16 + m16;
      b[ct] = *(const short8*)&Bp[row * 32 + ((kq ^ (row & 3)) * 8)];
    }
#pragma unroll
    for (int rt = 0; rt < 4; rt++)
#pragma unroll
      for (int ct = 0; ct < 4; ct++)
        acc[rt][ct] = __builtin_amdgcn_mfma_f32_16x16x32_bf16(a[rt], b[ct], acc[rt][ct], 0, 0, 0);
    asm volatile("" ::: "memory");
    __builtin_amdgcn_s_barrier();
    asm volatile("" ::: "memory");
    if (c + 2 < 8) stage(c + 2, c & 1);
  }

  int colbase = wave * 64 + m16;
  float bv[4];
#pragma unroll
  for (int ct = 0; ct < 4; ct++) bv[ct] = bias[colbase + ct * 16];

  float s[4][4], q[4][4];
#pragma unroll
  for (int rt = 0; rt < 4; rt++)
#pragma unroll
    for (int reg = 0; reg < 4; reg++) { s[rt][reg] = 0.f; q[rt][reg] = 0.f; }
#pragma unroll
  for (int rt = 0; rt < 4; rt++)
#pragma unroll
    for (int ct = 0; ct < 4; ct++)
#pragma unroll
      for (int reg = 0; reg < 4; reg++) {
        float v = acc[rt][ct][reg] + bv[ct];
        acc[rt][ct][reg] = v;
        s[rt][reg] += v;
        q[rt][reg] += v * v;
      }
#pragma unroll
  for (int off = 1; off < 16; off <<= 1) {
#pragma unroll
    for (int rt = 0; rt < 4; rt++)
#pragma unroll
      for (int reg = 0; reg < 4; reg++) {
        s[rt][reg] += __shfl_xor(s[rt][reg], off, 64);
        q[rt][reg] += __shfl_xor(q[rt][reg], off, 64);
      }
  }
  if (m16 == 0) {
#pragma unroll
    for (int rt = 0; rt < 4; rt++)
#pragma unroll
      for (int reg = 0; reg < 4; reg++) {
        redS[wave][rt * 16 + kq * 4 + reg] = s[rt][reg];
        redQ[wave][rt * 16 + kq * 4 + reg] = q[rt][reg];
      }
  }
  __syncthreads();
  if (t < 64) {
    float ss = redS[0][t] + redS[1][t] + redS[2][t] + redS[3][t];
    float qq = redQ[0][t] + redQ[1][t] + redQ[2][t] + redQ[3][t];
    float mean = ss * (1.f / 256.f);
    float var = qq * (1.f / 256.f) - mean * mean;
    mvM[t] = mean;
    mvI[t] = rsqrtf(var + 1e-5f);
  }
  __syncthreads();
  float gv[4], bev[4];
#pragma unroll
  for (int ct = 0; ct < 4; ct++) { gv[ct] = g[colbase + ct * 16]; bev[ct] = be[colbase + ct * 16]; }
#pragma unroll
  for (int rt = 0; rt < 4; rt++)
#pragma unroll
    for (int reg = 0; reg < 4; reg++) {
      int rr = rt * 16 + kq * 4 + reg;
      int r = row0 + rr;
      if (r >= NN) continue;
      float mean = mvM[rr], inv = mvI[rr];
#pragma unroll
      for (int ct = 0; ct < 4; ct++) {
        int col = colbase + ct * 16;
        float val = fmaxf((acc[rt][ct][reg] - mean) * inv * gv[ct] + bev[ct], 0.f);
        if (EPI == 2) {
          val += resid[(size_t)r * 256 + col];
          if (WF) outf[(size_t)r * 256 + col] = val;
        }
        outb[(size_t)r * 256 + col] = f2bf(val);
      }
    }
}

// ------------- attention logits, 4 heads fused (R5 path, gload_lds staging) -------------
__global__ __launch_bounds__(256) void k_att(const unsigned short* __restrict__ hb,
    const unsigned short* __restrict__ W1T, const float* __restrict__ b1,
    const float* __restrict__ W2, const float* __restrict__ b2,
    float* __restrict__ logitsT) {
  __shared__ unsigned short As[64 * 32];    // 4 KB
  __shared__ unsigned short Bs[512 * 32];   // 32 KB
  int t = threadIdx.x, lane = t & 63, wave = t >> 6;  // wave == head
  int row0 = blockIdx.x * 64;
  f32x4 acc[4][8];
#pragma unroll
  for (int i = 0; i < 4; i++)
#pragma unroll
    for (int j = 0; j < 8; j++) acc[i][j] = (f32x4)(0.f);
  int m16 = lane & 15, kq = lane >> 4;
  int arow = t >> 2, a2 = t & 3;
  int asl = a2 ^ (arow & 3);
  int agr = row0 + arow; if (agr >= NN) agr = NN - 1;
  unsigned short* AsDst = &As[wave * 512];
  int brow_[8], bsl_[8];
#pragma unroll
  for (int j = 0; j < 8; j++) {
    int s = j * 256 + t;
    brow_[j] = s >> 2;
    bsl_[j] = (s & 3) ^ (brow_[j] & 3);
  }
  for (int k0 = 0; k0 < 256; k0 += 32) {
    ldsload16(&hb[(size_t)agr * 256 + k0 + asl * 8], AsDst);
#pragma unroll
    for (int j = 0; j < 8; j++)
      ldsload16(&W1T[(size_t)brow_[j] * 256 + k0 + bsl_[j] * 8],
                &Bs[(j * 256 + wave * 64) * 8]);
    __syncthreads();
    short8 a[4];
#pragma unroll
    for (int rt = 0; rt < 4; rt++) {
      int row = rt * 16 + m16;
      a[rt] = *(const short8*)&As[row * 32 + ((kq ^ (row & 3)) * 8)];
    }
#pragma unroll
    for (int ct = 0; ct < 8; ct++) {
      int row = wave * 128 + ct * 16 + m16;
      short8 b = *(const short8*)&Bs[row * 32 + ((kq ^ (row & 3)) * 8)];
#pragma unroll
      for (int rt = 0; rt < 4; rt++)
        acc[rt][ct] = __builtin_amdgcn_mfma_f32_16x16x32_bf16(a[rt], b, acc[rt][ct], 0, 0, 0);
    }
    __syncthreads();
  }
  const float* b1k = b1 + wave * 128;
  const float* w2k = W2 + wave * 128;
  float p[4][4];
#pragma unroll
  for (int rt = 0; rt < 4; rt++)
#pragma unroll
    for (int reg = 0; reg < 4; reg++) p[rt][reg] = 0.f;
#pragma unroll
  for (int ct = 0; ct < 8; ct++) {
    int col = ct * 16 + m16;
    float b1v = b1k[col], w2v = w2k[col];
#pragma unroll
    for (int rt = 0; rt < 4; rt++)
#pragma unroll
      for (int reg = 0; reg < 4; reg++) {
        float xv = acc[rt][ct][reg] + b1v;
        xv = fminf(fmaxf(xv, -10.f), 10.f);
        float ex = __expf(2.f * xv);
        p[rt][reg] += (ex - 1.f) / (ex + 1.f) * w2v;
      }
  }
#pragma unroll
  for (int off = 1; off < 16; off <<= 1)
#pragma unroll
    for (int rt = 0; rt < 4; rt++)
#pragma unroll
      for (int reg = 0; reg < 4; reg++) p[rt][reg] += __shfl_xor(p[rt][reg], off, 64);
  if (m16 == 0) {
    float b2v = b2[wave];
#pragma unroll
    for (int rt = 0; rt < 4; rt++)
#pragma unroll
      for (int reg = 0; reg < 4; reg++) {
        int r = row0 + rt * 16 + kq * 4 + reg;
        if (r < NN) logitsT[(size_t)wave * NN + r] = p[rt][reg] + b2v;
      }
  }
}

// ---------------- softmax over N per head ----------------
__global__ void k_smax1(const float* __restrict__ logitsT, float* __restrict__ pmax,
                        float* __restrict__ psum) {
  int k = blockIdx.y;
  int tid = threadIdx.x;
  const float* L = logitsT + (size_t)k * NN;
  __shared__ float sm[256];
  float mx = -1e30f;
  for (int i = blockIdx.x * 256 + tid; i < NN; i += 128 * 256) mx = fmaxf(mx, L[i]);
  sm[tid] = mx; __syncthreads();
  for (int o = 128; o >= 1; o >>= 1) { if (tid < o) sm[tid] = fmaxf(sm[tid], sm[tid + o]); __syncthreads(); }
  float bmax = sm[0];
  __syncthreads();
  float s = 0.f;
  for (int i = blockIdx.x * 256 + tid; i < NN; i += 128 * 256) s += __expf(L[i] - bmax);
  sm[tid] = s; __syncthreads();
  for (int o = 128; o >= 1; o >>= 1) { if (tid < o) sm[tid] += sm[tid + o]; __syncthreads(); }
  if (tid == 0) { pmax[k * 128 + blockIdx.x] = bmax; psum[k * 128 + blockIdx.x] = sm[0]; }
}

__global__ void k_smax2(const float* __restrict__ pmax, const float* __restrict__ psum,
                        float* __restrict__ gs) {
  int k = blockIdx.x;
  int tid = threadIdx.x;  // 128
  __shared__ float sm[128], sv[128];
  float m = pmax[k * 128 + tid];
  sm[tid] = m; __syncthreads();
  for (int o = 64; o >= 1; o >>= 1) { if (tid < o) sm[tid] = fmaxf(sm[tid], sm[tid + o]); __syncthreads(); }
  float gm = sm[0];
  __syncthreads();
  sv[tid] = psum[k * 128 + tid] * __expf(m - gm);
  __syncthreads();
  for (int o = 64; o >= 1; o >>= 1) { if (tid < o) sv[tid] += sv[tid + o]; __syncthreads(); }
  if (tid == 0) { gs[k * 2] = gm; gs[k * 2 + 1] = sv[0]; }
}

// ------------- a = softmax, attn output, z[k][d] partials -------------
__global__ void k_attnz(const float* __restrict__ logitsT, const float* __restrict__ gs,
                        const unsigned short* __restrict__ hb, float* __restrict__ out_attn,
                        float* __restrict__ z) {
  int n0 = blockIdx.x * 128;
  int tid = threadIdx.x;
  __shared__ float a[4][128];
  for (int i = tid; i < 512; i += 256) {
    int k = i >> 7, n = i & 127;
    float v = 0.f;
    if (n0 + n < NN) v = __expf(logitsT[(size_t)k * NN + n0 + n] - gs[k * 2]) / gs[k * 2 + 1];
    a[k][n] = v;
  }
  __syncthreads();
  for (int i = tid; i < 512; i += 256) {
    int n = i >> 2, k = i & 3;
    if (n0 + n < NN) out_attn[(size_t)(n0 + n) * 4 + k] = a[k][n];
  }
  float z0 = 0.f, z1 = 0.f, z2 = 0.f, z3 = 0.f;
  int d = tid;  // 256 dims
  int nmax = NN - n0; if (nmax > 128) nmax = 128;
  for (int n = 0; n < nmax; n++) {
    float hv = bf2f(hb[(size_t)(n0 + n) * 256 + d]);
    z0 += a[0][n] * hv; z1 += a[1][n] * hv; z2 += a[2][n] * hv; z3 += a[3][n] * hv;
  }
  atomicAdd(&z[0 * 256 + d], z0);
  atomicAdd(&z[1 * 256 + d], z1);
  atomicAdd(&z[2 * 256 + d], z2);
  atomicAdd(&z[3 * 256 + d], z3);
}

// ---------------- tiny classifier ----------------
__global__ void k_cls(const float* __restrict__ z, const float* __restrict__ Wc1,
                      const float* __restrict__ bc1, const float* __restrict__ g1,
                      const float* __restrict__ b1, const float* __restrict__ Wc2,
                      const float* __restrict__ bc2, const float* __restrict__ g2,
                      const float* __restrict__ b2, const float* __restrict__ Wc3,
                      const float* __restrict__ bc3, float* __restrict__ out) {
  int tid = threadIdx.x;  // 256
  __shared__ float za[256];
  __shared__ float buf[256];
  __shared__ float c1s[128];
  __shared__ float c2s[64];
  za[tid] = 0.25f * (z[tid] + z[256 + tid] + z[512 + tid] + z[768 + tid]);
  __syncthreads();
  float v1 = 0.f;
  if (tid < 128) {
    for (int d = 0; d < 256; d++) v1 += za[d] * Wc1[d * 128 + tid];
    v1 += bc1[tid];
  }
  buf[tid] = (tid < 128) ? v1 : 0.f; __syncthreads();
  for (int o = 128; o >= 1; o >>= 1) { if (tid < o) buf[tid] += buf[tid + o]; __syncthreads(); }
  float mean1 = buf[0] * (1.f / 128.f);
  __syncthreads();
  buf[tid] = (tid < 128) ? (v1 - mean1) * (v1 - mean1) : 0.f; __syncthreads();
  for (int o = 128; o >= 1; o >>= 1) { if (tid < o) buf[tid] += buf[tid + o]; __syncthreads(); }
  float inv1 = rsqrtf(buf[0] * (1.f / 128.f) + 1e-5f);
  __syncthreads();
  if (tid < 128) c1s[tid] = fmaxf((v1 - mean1) * inv1 * g1[tid] + b1[tid], 0.f);
  __syncthreads();
  float v2 = 0.f;
  if (tid < 64) {
    for (int d = 0; d < 128; d++) v2 += c1s[d] * Wc2[d * 64 + tid];
    v2 += bc2[tid];
  }
  buf[tid] = (tid < 64) ? v2 : 0.f; __syncthreads();
  for (int o = 128; o >= 1; o >>= 1) { if (tid < o) buf[tid] += buf[tid + o]; __syncthreads(); }
  float mean2 = buf[0] * (1.f / 64.f);
  __syncthreads();
  buf[tid] = (tid < 64) ? (v2 - mean2) * (v2 - mean2) : 0.f; __syncthreads();
  for (int o = 128; o >= 1; o >>= 1) { if (tid < o) buf[tid] += buf[tid + o]; __syncthreads(); }
  float inv2 = rsqrtf(buf[0] * (1.f / 64.f) + 1e-5f);
  __syncthreads();
  if (tid < 64) c2s[tid] = fmaxf((v2 - mean2) * inv2 * g2[tid] + b2[tid], 0.f);
  __syncthreads();
  if (tid < 7) {
    float l = 0.f;
    for (int d = 0; d < 64; d++) l += c2s[d] * Wc3[d * 7 + tid];
    buf[tid] = l + bc3[tid];
  }
  __syncthreads();
  if (tid == 0) {
    float mx = -1e30f;
    for (int i = 0; i < 7; i++) mx = fmaxf(mx, buf[i]);
    float s = 0.f;
    for (int i = 0; i < 7; i++) s += __expf(buf[i] - mx);
    for (int i = 0; i < 7; i++) out[i] = __expf(buf[i] - mx) / s;
  }
}

extern "C" void kernel_launch(void* const* d_in, const int* in_sizes, int n_in,
                              void* d_out, int out_size, void* d_ws, size_t ws_size,
                              hipStream_t stream) {
  const float* x       = (const float*)d_in[0];
  const int*   ei      = (const int*)d_in[1];
  const float* W_in    = (const float*)d_in[2];
  const float* b_in    = (const float*)d_in[3];
  const float* gin_W1  = (const float*)d_in[4];
  const float* gin_b1  = (const float*)d_in[5];
  const float* gin_lng = (const float*)d_in[6];
  const float* gin_lnb = (const float*)d_in[7];
  const float* gin_W2  = (const float*)d_in[8];
  const float* gin_b2  = (const float*)d_in[9];
  const float* eps     = (const float*)d_in[10];
  const float* ln_g    = (const float*)d_in[11];
  const float* ln_b    = (const float*)d_in[12];
  const float* att_W1  = (const float*)d_in[13];
  const float* att_b1  = (const float*)d_in[14];
  const float* att_W2  = (const float*)d_in[15];
  const float* att_b2  = (const float*)d_in[16];
  const float* Wc1     = (const float*)d_in[17];
  const float* bc1     = (const float*)d_in[18];
  const float* lnc1_g  = (const float*)d_in[19];
  const float* lnc1_b  = (const float*)d_in[20];
  const float* Wc2     = (const float*)d_in[21];
  const float* bc2     = (const float*)d_in[22];
  const float* lnc2_g  = (const float*)d_in[23];
  const float* lnc2_b  = (const float*)d_in[24];
  const float* Wc3     = (const float*)d_in[25];
  const float* bc3     = (const float*)d_in[26];
  float* out = (float*)d_out;
  (void)in_sizes; (void)n_in; (void)out_size; (void)ws_size;

  char* wsb = (char*)d_ws;
  size_t off = 0;
  auto alloc = [&](size_t bytes) {
    char* p = wsb + off;
    off += (bytes + 255) & ~(size_t)255;
    return p;
  };
  float*          h       = (float*)alloc((size_t)NN * HH * 4);
  unsigned short* hb      = (unsigned short*)alloc((size_t)NN * HH * 2);
  unsigned short* mb1     = (unsigned short*)alloc((size_t)NN * HH * 2);
  unsigned short* mb2     = (unsigned short*)alloc((size_t)NN * HH * 2);
  unsigned short* WinT    = (unsigned short*)alloc((size_t)HH * FF * 2);
  unsigned short* g1T     = (unsigned short*)alloc((size_t)2 * HH * HH * 2);
  unsigned short* g2T     = (unsigned short*)alloc((size_t)2 * HH * HH * 2);
  unsigned short* aW1T    = (unsigned short*)alloc((size_t)4 * 128 * HH * 2);
  float*          logitsT = (float*)alloc((size_t)4 * NN * 4);
  int*            deg     = (int*)alloc((size_t)NN * 4);
  int*            rowptr  = (int*)alloc((size_t)(NN + 1) * 4);
  int*            cursor  = (int*)alloc((size_t)NN * 4);
  int*            csr_src = (int*)alloc((size_t)NE * 4);
  float*          pmax    = (float*)alloc(4 * 128 * 4);
  float*          psum    = (float*)alloc(4 * 128 * 4);
  float*          gs      = (float*)alloc(8 * 4);
  float*          z       = (float*)alloc(4 * 256 * 4);

  const int* srcv = ei;
  const int* dstv = ei + NE;

  // weight transposes + casts (tiny, batched over blockIdx.z)
  k_tcast<<<dim3((HH + 31) / 32, (FF + 31) / 32, 1), 256, 0, stream>>>(W_in, WinT, FF, HH);
  k_tcast<<<dim3(8, 8, 2), 256, 0, stream>>>(gin_W1, g1T, HH, HH);
  k_tcast<<<dim3(8, 8, 2), 256, 0, stream>>>(gin_W2, g2T, HH, HH);
  k_tcast<<<dim3(4, 8, 4), 256, 0, stream>>>(att_W1, aW1T, HH, 128);

  // CSR build
  hipMemsetAsync(deg, 0, (size_t)NN * 4, stream);
  hipMemsetAsync(z, 0, 4 * 256 * 4, stream);
  k_count<<<(NE + 255) / 256, 256, 0, stream>>>(dstv, deg);
  k_scan<<<1, 1024, 0, stream>>>(deg, rowptr);
  hipMemcpyAsync(cursor, rowptr, (size_t)NN * 4, hipMemcpyDeviceToDevice, stream);
  k_scatter<<<(NE + 255) / 256, 256, 0, stream>>>(srcv, dstv, cursor, csr_src);

  int gblocks = (NN + 63) / 64;  // 782
  // h = x @ W_in + b_in  (fp32 A cast to bf16 in staging); also emit hb
  k_mmff<<<gblocks, 256, 0, stream>>>(x, WinT, b_in, h, hb);

  for (int l = 0; l < 2; l++) {
    k_agg<<<(NN + 3) / 4, 256, 0, stream>>>(hb, rowptr, csr_src, eps, l, mb1);
    // mb2 = bf16(relu(LN(mb1 @ W1 + b1)))
    k_mmh<1, true><<<gblocks, 256, 0, stream>>>(mb1, g1T + (size_t)l * HH * HH,
        gin_b1 + l * HH, gin_lng + l * HH, gin_lnb + l * HH, nullptr, nullptr, mb2);
    // h = relu(LN(mb2 @ W2 + b2)) + h ; hb = bf16(h). Last layer: skip fp32 h write.
    if (l == 0)
      k_mmh<2, true><<<gblocks, 256, 0, stream>>>(mb2, g2T + (size_t)l * HH * HH,
          gin_b2 + l * HH, ln_g + l * HH, ln_b + l * HH, h, h, hb);
    else
      k_mmh<2, false><<<gblocks, 256, 0, stream>>>(mb2, g2T + (size_t)l * HH * HH,
          gin_b2 + l * HH, ln_g + l * HH, ln_b + l * HH, h, nullptr, hb);
  }

  k_att<<<gblocks, 256, 0, stream>>>(hb, aW1T, att_b1, att_W2, att_b2, logitsT);
  k_smax1<<<dim3(128, 4), 256, 0, stream>>>(logitsT, pmax, psum);
  k_smax2<<<4, 128, 0, stream>>>(pmax, psum, gs);
  k_attnz<<<(NN + 127) / 128, 256, 0, stream>>>(logitsT, gs, hb, out + 7, z);
  k_cls<<<1, 256, 0, stream>>>(z, Wc1, bc1, lnc1_g, lnc1_b, Wc2, bc2, lnc2_g, lnc2_b,
                               Wc3, bc3, out);
}

// Round 7
// 904.780 us; speedup vs baseline: 1.2957x; 1.0294x over previous
//
#include <hip/hip_runtime.h>
#include <math.h>

#define NN 50000
#define NE 800000
#define FF 768
#define HH 256

typedef __attribute__((ext_vector_type(8))) short short8;
typedef __attribute__((ext_vector_type(4))) float f32x4;

__device__ inline unsigned short f2bf(float f) {
  unsigned u = __float_as_uint(f);
  u = u + 0x7fffu + ((u >> 16) & 1u);
  return (unsigned short)(u >> 16);
}
__device__ inline float bf2f(unsigned short b) {
  return __uint_as_float(((unsigned)b) << 16);
}

// async global->LDS, 16B per lane. Dest is wave-uniform base + lane*16 (HW).
__device__ __forceinline__ void ldsload16(const unsigned short* g, unsigned short* l) {
  __builtin_amdgcn_global_load_lds(
      (const __attribute__((address_space(1))) void*)g,
      (__attribute__((address_space(3))) void*)l, 16, 0, 0);
}

// ---------------- CSR build ----------------
__global__ void k_count(const int* __restrict__ dstv, int* __restrict__ deg) {
  int e = blockIdx.x * 256 + threadIdx.x;
  if (e < NE) atomicAdd(&deg[dstv[e]], 1);
}

// single-block thread-coarsened scan: 1024 threads x 49 elems
__global__ void k_scan(const int* __restrict__ deg, int* __restrict__ rowptr) {
  const int CH = 49;  // 1024*49 = 50176 >= NN
  int tid = threadIdx.x;
  int lane = tid & 63, w = tid >> 6;
  int base = tid * CH;
  int sum = 0;
  for (int i = 0; i < CH; i++) {
    int idx = base + i;
    if (idx < NN) sum += deg[idx];
  }
  int incl = sum;
  for (int off = 1; off < 64; off <<= 1) {
    int tv = __shfl_up(incl, off, 64);
    if (lane >= off) incl += tv;
  }
  __shared__ int ws[16];
  if (lane == 63) ws[w] = incl;
  __syncthreads();
  if (tid == 0) {
    int c = 0;
    for (int i = 0; i < 16; i++) { int tv = ws[i]; ws[i] = c; c += tv; }
  }
  __syncthreads();
  int run = ws[w] + (incl - sum);
  if (tid == 0) rowptr[0] = 0;
  for (int i = 0; i < CH; i++) {
    int idx = base + i;
    if (idx < NN) { run += deg[idx]; rowptr[idx + 1] = run; }
  }
}

__global__ void k_scatter(const int* __restrict__ srcv, const int* __restrict__ dstv,
                          int* __restrict__ cursor, int* __restrict__ csr_src) {
  int e = blockIdx.x * 256 + threadIdx.x;
  if (e < NE) {
    int d = dstv[e];
    int pos = atomicAdd(&cursor[d], 1);
    csr_src[pos] = srcv[e];
  }
}

// ------------- aggregation (bf16 gather): mb = bf16((1+eps)*hb + sum hb[src]) -------------
__global__ void k_agg(const unsigned short* __restrict__ hb, const int* __restrict__ rowptr,
                      const int* __restrict__ csr_src, const float* __restrict__ eps,
                      int layer, unsigned short* __restrict__ mb) {
  int node = (blockIdx.x * blockDim.x + threadIdx.x) >> 6;
  int lane = threadIdx.x & 63;
  if (node >= NN) return;
  int beg = rowptr[node], end = rowptr[node + 1];
  const ushort4* hv = (const ushort4*)hb;
  float ax = 0.f, ay = 0.f, az = 0.f, aw = 0.f;
  for (int e = beg; e < end; ++e) {
    int s = csr_src[e];
    ushort4 v = hv[(size_t)s * 64 + lane];
    ax += bf2f(v.x); ay += bf2f(v.y); az += bf2f(v.z); aw += bf2f(v.w);
  }
  float ep = 1.0f + eps[layer];
  ushort4 h0 = hv[(size_t)node * 64 + lane];
  ax += ep * bf2f(h0.x); ay += ep * bf2f(h0.y);
  az += ep * bf2f(h0.z); aw += ep * bf2f(h0.w);
  ushort4 o;
  o.x = f2bf(ax); o.y = f2bf(ay); o.z = f2bf(az); o.w = f2bf(aw);
  *(ushort4*)&mb[(size_t)node * 256 + lane * 4] = o;
}

// ------------- transpose + cast: dst[c][r] = bf16(src[r][c]), src is R x C, batched over z -------------
__global__ void k_tcast(const float* __restrict__ src0, unsigned short* __restrict__ dst0,
                        int R, int C) {
  const float* src = src0 + (size_t)blockIdx.z * R * C;
  unsigned short* dst = dst0 + (size_t)blockIdx.z * R * C;
  __shared__ float tile[32][33];
  int bx = blockIdx.x * 32, by = blockIdx.y * 32;
  int tx = threadIdx.x & 31, ty = threadIdx.x >> 5;  // 32 x 8
  for (int i = 0; i < 32; i += 8) {
    int r = by + ty + i, c = bx + tx;
    tile[ty + i][tx] = (r < R && c < C) ? src[(size_t)r * C + c] : 0.f;
  }
  __syncthreads();
  for (int i = 0; i < 32; i += 8) {
    int c = bx + ty + i, r = by + tx;
    if (c < C && r < R) dst[(size_t)c * R + r] = f2bf(tile[tx][ty + i]);
  }
}

// ---------------- input projection GEMM: K=768, fp32 A cast in staging (R6 path) ----------------
__global__ __launch_bounds__(256) void k_mmff(
    const float* __restrict__ x, const unsigned short* __restrict__ Bt,
    const float* __restrict__ bias, float* __restrict__ outf,
    unsigned short* __restrict__ outb) {
  __shared__ unsigned short As[64 * 32];   // 4 KB, linear (swizzled slots)
  __shared__ unsigned short Bs[256 * 32];  // 16 KB, linear (swizzled slots)
  int t = threadIdx.x, lane = t & 63, wave = t >> 6;
  int row0 = blockIdx.x * 64;
  f32x4 acc[4][4];
#pragma unroll
  for (int i = 0; i < 4; i++)
#pragma unroll
    for (int j = 0; j < 4; j++) acc[i][j] = (f32x4)(0.f);
  int m16 = lane & 15, kq = lane >> 4;
  int arow = t >> 2, a2 = t & 3;
  int asl = a2 ^ (arow & 3);
  int agr = row0 + arow; if (agr >= NN) agr = NN - 1;
  int brow_[4], bsl_[4];
#pragma unroll
  for (int j = 0; j < 4; j++) {
    int s = j * 256 + t;
    brow_[j] = s >> 2;
    bsl_[j] = (s & 3) ^ (brow_[j] & 3);
  }
  for (int k0 = 0; k0 < FF; k0 += 32) {
    {
      const float* Af = x + (size_t)agr * FF + k0 + asl * 8;
      float4 f0 = *(const float4*)Af;
      float4 f1 = *(const float4*)(Af + 4);
      short8 v;
      v[0] = (short)f2bf(f0.x); v[1] = (short)f2bf(f0.y);
      v[2] = (short)f2bf(f0.z); v[3] = (short)f2bf(f0.w);
      v[4] = (short)f2bf(f1.x); v[5] = (short)f2bf(f1.y);
      v[6] = (short)f2bf(f1.z); v[7] = (short)f2bf(f1.w);
      *(short8*)&As[arow * 32 + a2 * 8] = v;
    }
#pragma unroll
    for (int j = 0; j < 4; j++)
      ldsload16(&Bt[(size_t)brow_[j] * FF + k0 + bsl_[j] * 8],
                &Bs[(j * 256 + wave * 64) * 8]);
    __syncthreads();
    short8 a[4], b[4];
#pragma unroll
    for (int rt = 0; rt < 4; rt++) {
      int row = rt * 16 + m16;
      a[rt] = *(const short8*)&As[row * 32 + ((kq ^ (row & 3)) * 8)];
    }
#pragma unroll
    for (int ct = 0; ct < 4; ct++) {
      int row = wave * 64 + ct * 16 + m16;
      b[ct] = *(const short8*)&Bs[row * 32 + ((kq ^ (row & 3)) * 8)];
    }
#pragma unroll
    for (int rt = 0; rt < 4; rt++)
#pragma unroll
      for (int ct = 0; ct < 4; ct++)
        acc[rt][ct] = __builtin_amdgcn_mfma_f32_16x16x32_bf16(a[rt], b[ct], acc[rt][ct], 0, 0, 0);
    __syncthreads();
  }
  int colbase = wave * 64 + m16;
  float bv[4];
#pragma unroll
  for (int ct = 0; ct < 4; ct++) bv[ct] = bias[colbase + ct * 16];
#pragma unroll
  for (int rt = 0; rt < 4; rt++)
#pragma unroll
    for (int reg = 0; reg < 4; reg++) {
      int r = row0 + rt * 16 + kq * 4 + reg;
      if (r < NN) {
#pragma unroll
        for (int ct = 0; ct < 4; ct++) {
          float v = acc[rt][ct][reg] + bv[ct];
          outf[(size_t)r * 256 + colbase + ct * 16] = v;
          outb[(size_t)r * 256 + colbase + ct * 16] = f2bf(v);
        }
      }
    }
}

// ---------------- fused GIN layer: GEMM1+LN+ReLU -> T1(LDS) -> GEMM2+LN+ReLU+resid ----------------
// Both K-loops use the R6 counted-vmcnt double-buffered gload_lds pipeline.
// T1 swizzle: row r, 16B-slot s stored at phys slot s^(r&31) -> <=2-way ds_read conflicts.
// WF: write fp32 h (needed as next layer's residual input).
template <bool WF>
__global__ __launch_bounds__(256) void k_gin(
    const unsigned short* __restrict__ Ab,
    const unsigned short* __restrict__ B1t, const float* __restrict__ bias1,
    const float* __restrict__ g1v, const float* __restrict__ be1,
    const unsigned short* __restrict__ B2t, const float* __restrict__ bias2,
    const float* __restrict__ g2v, const float* __restrict__ be2,
    const float* __restrict__ resid, float* __restrict__ outf,
    unsigned short* __restrict__ outb) {
  __shared__ unsigned short As[2][64 * 32];   // 2 x 4 KB
  __shared__ unsigned short Bs[2][256 * 32];  // 2 x 16 KB
  __shared__ unsigned short T1[64 * 256];     // 32 KB, slot-swizzled
  __shared__ float redS[4][64];
  __shared__ float redQ[4][64];
  __shared__ float mvM[64], mvI[64];
  int t = threadIdx.x, lane = t & 63, wave = t >> 6;
  int row0 = blockIdx.x * 64;
  int m16 = lane & 15, kq = lane >> 4;
  int colbase = wave * 64 + m16;
  int arow = t >> 2, a2 = t & 3;
  int asl = a2 ^ (arow & 3);
  int agr = row0 + arow; if (agr >= NN) agr = NN - 1;
  const unsigned short* Ag = Ab + (size_t)agr * 256 + asl * 8;
  int brow_[4], bsl_[4];
#pragma unroll
  for (int j = 0; j < 4; j++) {
    int s = j * 256 + t;
    brow_[j] = s >> 2;
    bsl_[j] = (s & 3) ^ (brow_[j] & 3);
  }
  auto stage1 = [&](int c, int p) {  // 5 loads: A chunk + B1 chunk
    int k0 = c * 32;
    ldsload16(Ag + k0, &As[p][wave * 512]);
#pragma unroll
    for (int j = 0; j < 4; j++)
      ldsload16(&B1t[(size_t)brow_[j] * 256 + k0 + bsl_[j] * 8],
                &Bs[p][(j * 256 + wave * 64) * 8]);
  };
  auto stage2 = [&](int c, int p) {  // 4 loads: B2 chunk only
    int k0 = c * 32;
#pragma unroll
    for (int j = 0; j < 4; j++)
      ldsload16(&B2t[(size_t)brow_[j] * 256 + k0 + bsl_[j] * 8],
                &Bs[p][(j * 256 + wave * 64) * 8]);
  };

  f32x4 acc[4][4];
#pragma unroll
  for (int i = 0; i < 4; i++)
#pragma unroll
    for (int j = 0; j < 4; j++) acc[i][j] = (f32x4)(0.f);

  // ---------------- GEMM1 K-loop ----------------
  stage1(0, 0);
  stage1(1, 1);
#pragma unroll
  for (int c = 0; c < 8; c++) {
    if (c < 7) asm volatile("s_waitcnt vmcnt(5)" ::: "memory");
    else       asm volatile("s_waitcnt vmcnt(0)" ::: "memory");
    __builtin_amdgcn_s_barrier();
    asm volatile("" ::: "memory");
    const unsigned short* Ap = As[c & 1];
    const unsigned short* Bp = Bs[c & 1];
    short8 a[4], b[4];
#pragma unroll
    for (int rt = 0; rt < 4; rt++) {
      int row = rt * 16 + m16;
      a[rt] = *(const short8*)&Ap[row * 32 + ((kq ^ (row & 3)) * 8)];
    }
#pragma unroll
    for (int ct = 0; ct < 4; ct++) {
      int row = wave * 64 + ct * 16 + m16;
      b[ct] = *(const short8*)&Bp[row * 32 + ((kq ^ (row & 3)) * 8)];
    }
#pragma unroll
    for (int rt = 0; rt < 4; rt++)
#pragma unroll
      for (int ct = 0; ct < 4; ct++)
        acc[rt][ct] = __builtin_amdgcn_mfma_f32_16x16x32_bf16(a[rt], b[ct], acc[rt][ct], 0, 0, 0);
    asm volatile("" ::: "memory");
    __builtin_amdgcn_s_barrier();
    asm volatile("" ::: "memory");
    if (c + 2 < 8) stage1(c + 2, c & 1);
  }

  // ---------------- epilogue 1: bias + LN + ReLU -> T1 (swizzled) ----------------
  {
    float bv[4];
#pragma unroll
    for (int ct = 0; ct < 4; ct++) bv[ct] = bias1[colbase + ct * 16];
    float s[4][4], q[4][4];
#pragma unroll
    for (int rt = 0; rt < 4; rt++)
#pragma unroll
      for (int reg = 0; reg < 4; reg++) { s[rt][reg] = 0.f; q[rt][reg] = 0.f; }
#pragma unroll
    for (int rt = 0; rt < 4; rt++)
#pragma unroll
      for (int ct = 0; ct < 4; ct++)
#pragma unroll
        for (int reg = 0; reg < 4; reg++) {
          float v = acc[rt][ct][reg] + bv[ct];
          acc[rt][ct][reg] = v;
          s[rt][reg] += v;
          q[rt][reg] += v * v;
        }
#pragma unroll
    for (int off = 1; off < 16; off <<= 1) {
#pragma unroll
      for (int rt = 0; rt < 4; rt++)
#pragma unroll
        for (int reg = 0; reg < 4; reg++) {
          s[rt][reg] += __shfl_xor(s[rt][reg], off, 64);
          q[rt][reg] += __shfl_xor(q[rt][reg], off, 64);
        }
    }
    if (m16 == 0) {
#pragma unroll
      for (int rt = 0; rt < 4; rt++)
#pragma unroll
        for (int reg = 0; reg < 4; reg++) {
          redS[wave][rt * 16 + kq * 4 + reg] = s[rt][reg];
          redQ[wave][rt * 16 + kq * 4 + reg] = q[rt][reg];
        }
    }
    __syncthreads();
    if (t < 64) {
      float ss = redS[0][t] + redS[1][t] + redS[2][t] + redS[3][t];
      float qq = redQ[0][t] + redQ[1][t] + redQ[2][t] + redQ[3][t];
      float mean = ss * (1.f / 256.f);
      float var = qq * (1.f / 256.f) - mean * mean;
      mvM[t] = mean;
      mvI[t] = rsqrtf(var + 1e-5f);
    }
    __syncthreads();
    float gv[4], bev[4];
#pragma unroll
    for (int ct = 0; ct < 4; ct++) { gv[ct] = g1v[colbase + ct * 16]; bev[ct] = be1[colbase + ct * 16]; }
#pragma unroll
    for (int rt = 0; rt < 4; rt++)
#pragma unroll
      for (int reg = 0; reg < 4; reg++) {
        int rr = rt * 16 + kq * 4 + reg;
        float mean = mvM[rr], inv = mvI[rr];
#pragma unroll
        for (int ct = 0; ct < 4; ct++) {
          int col = colbase + ct * 16;
          float val = fmaxf((acc[rt][ct][reg] - mean) * inv * gv[ct] + bev[ct], 0.f);
          T1[rr * 256 + (((col >> 3) ^ (rr & 31)) * 8) + (col & 7)] = f2bf(val);
        }
      }
    __syncthreads();
  }

  // ---------------- GEMM2 K-loop (A from T1, B2 pipelined) ----------------
#pragma unroll
  for (int i = 0; i < 4; i++)
#pragma unroll
    for (int j = 0; j < 4; j++) acc[i][j] = (f32x4)(0.f);
  stage2(0, 0);
  stage2(1, 1);
#pragma unroll
  for (int c = 0; c < 8; c++) {
    if (c < 7) asm volatile("s_waitcnt vmcnt(4)" ::: "memory");
    else       asm volatile("s_waitcnt vmcnt(0)" ::: "memory");
    __builtin_amdgcn_s_barrier();
    asm volatile("" ::: "memory");
    const unsigned short* Bp = Bs[c & 1];
    short8 a[4], b[4];
#pragma unroll
    for (int rt = 0; rt < 4; rt++) {
      int row = rt * 16 + m16;
      int sl = (c * 4 + kq) ^ (row & 31);
      a[rt] = *(const short8*)&T1[row * 256 + sl * 8];
    }
#pragma unroll
    for (int ct = 0; ct < 4; ct++) {
      int row = wave * 64 + ct * 16 + m16;
      b[ct] = *(const short8*)&Bp[row * 32 + ((kq ^ (row & 3)) * 8)];
    }
#pragma unroll
    for (int rt = 0; rt < 4; rt++)
#pragma unroll
      for (int ct = 0; ct < 4; ct++)
        acc[rt][ct] = __builtin_amdgcn_mfma_f32_16x16x32_bf16(a[rt], b[ct], acc[rt][ct], 0, 0, 0);
    asm volatile("" ::: "memory");
    __builtin_amdgcn_s_barrier();
    asm volatile("" ::: "memory");
    if (c + 2 < 8) stage2(c + 2, c & 1);
  }

  // ---------------- epilogue 2: bias + LN + ReLU + resid -> outf/outb ----------------
  {
    float bv[4];
#pragma unroll
    for (int ct = 0; ct < 4; ct++) bv[ct] = bias2[colbase + ct * 16];
    float s[4][4], q[4][4];
#pragma unroll
    for (int rt = 0; rt < 4; rt++)
#pragma unroll
      for (int reg = 0; reg < 4; reg++) { s[rt][reg] = 0.f; q[rt][reg] = 0.f; }
#pragma unroll
    for (int rt = 0; rt < 4; rt++)
#pragma unroll
      for (int ct = 0; ct < 4; ct++)
#pragma unroll
        for (int reg = 0; reg < 4; reg++) {
          float v = acc[rt][ct][reg] + bv[ct];
          acc[rt][ct][reg] = v;
          s[rt][reg] += v;
          q[rt][reg] += v * v;
        }
#pragma unroll
    for (int off = 1; off < 16; off <<= 1) {
#pragma unroll
      for (int rt = 0; rt < 4; rt++)
#pragma unroll
        for (int reg = 0; reg < 4; reg++) {
          s[rt][reg] += __shfl_xor(s[rt][reg], off, 64);
          q[rt][reg] += __shfl_xor(q[rt][reg], off, 64);
        }
    }
    if (m16 == 0) {
#pragma unroll
      for (int rt = 0; rt < 4; rt++)
#pragma unroll
        for (int reg = 0; reg < 4; reg++) {
          redS[wave][rt * 16 + kq * 4 + reg] = s[rt][reg];
          redQ[wave][rt * 16 + kq * 4 + reg] = q[rt][reg];
        }
    }
    __syncthreads();
    if (t < 64) {
      float ss = redS[0][t] + redS[1][t] + redS[2][t] + redS[3][t];
      float qq = redQ[0][t] + redQ[1][t] + redQ[2][t] + redQ[3][t];
      float mean = ss * (1.f / 256.f);
      float var = qq * (1.f / 256.f) - mean * mean;
      mvM[t] = mean;
      mvI[t] = rsqrtf(var + 1e-5f);
    }
    __syncthreads();
    float gv[4], bev[4];
#pragma unroll
    for (int ct = 0; ct < 4; ct++) { gv[ct] = g2v[colbase + ct * 16]; bev[ct] = be2[colbase + ct * 16]; }
#pragma unroll
    for (int rt = 0; rt < 4; rt++)
#pragma unroll
      for (int reg = 0; reg < 4; reg++) {
        int rr = rt * 16 + kq * 4 + reg;
        int r = row0 + rr;
        if (r >= NN) continue;
        float mean = mvM[rr], inv = mvI[rr];
#pragma unroll
        for (int ct = 0; ct < 4; ct++) {
          int col = colbase + ct * 16;
          float val = fmaxf((acc[rt][ct][reg] - mean) * inv * gv[ct] + bev[ct], 0.f);
          val += resid[(size_t)r * 256 + col];
          if (WF) outf[(size_t)r * 256 + col] = val;
          outb[(size_t)r * 256 + col] = f2bf(val);
        }
      }
  }
}

// ------------- attention logits, 4 heads fused (R6 path, gload_lds staging) -------------
__global__ __launch_bounds__(256) void k_att(const unsigned short* __restrict__ hb,
    const unsigned short* __restrict__ W1T, const float* __restrict__ b1,
    const float* __restrict__ W2, const float* __restrict__ b2,
    float* __restrict__ logitsT) {
  __shared__ unsigned short As[64 * 32];    // 4 KB
  __shared__ unsigned short Bs[512 * 32];   // 32 KB
  int t = threadIdx.x, lane = t & 63, wave = t >> 6;  // wave == head
  int row0 = blockIdx.x * 64;
  f32x4 acc[4][8];
#pragma unroll
  for (int i = 0; i < 4; i++)
#pragma unroll
    for (int j = 0; j < 8; j++) acc[i][j] = (f32x4)(0.f);
  int m16 = lane & 15, kq = lane >> 4;
  int arow = t >> 2, a2 = t & 3;
  int asl = a2 ^ (arow & 3);
  int agr = row0 + arow; if (agr >= NN) agr = NN - 1;
  unsigned short* AsDst = &As[wave * 512];
  int brow_[8], bsl_[8];
#pragma unroll
  for (int j = 0; j < 8; j++) {
    int s = j * 256 + t;
    brow_[j] = s >> 2;
    bsl_[j] = (s & 3) ^ (brow_[j] & 3);
  }
  for (int k0 = 0; k0 < 256; k0 += 32) {
    ldsload16(&hb[(size_t)agr * 256 + k0 + asl * 8], AsDst);
#pragma unroll
    for (int j = 0; j < 8; j++)
      ldsload16(&W1T[(size_t)brow_[j] * 256 + k0 + bsl_[j] * 8],
                &Bs[(j * 256 + wave * 64) * 8]);
    __syncthreads();
    short8 a[4];
#pragma unroll
    for (int rt = 0; rt < 4; rt++) {
      int row = rt * 16 + m16;
      a[rt] = *(const short8*)&As[row * 32 + ((kq ^ (row & 3)) * 8)];
    }
#pragma unroll
    for (int ct = 0; ct < 8; ct++) {
      int row = wave * 128 + ct * 16 + m16;
      short8 b = *(const short8*)&Bs[row * 32 + ((kq ^ (row & 3)) * 8)];
#pragma unroll
      for (int rt = 0; rt < 4; rt++)
        acc[rt][ct] = __builtin_amdgcn_mfma_f32_16x16x32_bf16(a[rt], b, acc[rt][ct], 0, 0, 0);
    }
    __syncthreads();
  }
  const float* b1k = b1 + wave * 128;
  const float* w2k = W2 + wave * 128;
  float p[4][4];
#pragma unroll
  for (int rt = 0; rt < 4; rt++)
#pragma unroll
    for (int reg = 0; reg < 4; reg++) p[rt][reg] = 0.f;
#pragma unroll
  for (int ct = 0; ct < 8; ct++) {
    int col = ct * 16 + m16;
    float b1v = b1k[col], w2v = w2k[col];
#pragma unroll
    for (int rt = 0; rt < 4; rt++)
#pragma unroll
      for (int reg = 0; reg < 4; reg++) {
        float xv = acc[rt][ct][reg] + b1v;
        xv = fminf(fmaxf(xv, -10.f), 10.f);
        float ex = __expf(2.f * xv);
        p[rt][reg] += (ex - 1.f) / (ex + 1.f) * w2v;
      }
  }
#pragma unroll
  for (int off = 1; off < 16; off <<= 1)
#pragma unroll
    for (int rt = 0; rt < 4; rt++)
#pragma unroll
      for (int reg = 0; reg < 4; reg++) p[rt][reg] += __shfl_xor(p[rt][reg], off, 64);
  if (m16 == 0) {
    float b2v = b2[wave];
#pragma unroll
    for (int rt = 0; rt < 4; rt++)
#pragma unroll
      for (int reg = 0; reg < 4; reg++) {
        int r = row0 + rt * 16 + kq * 4 + reg;
        if (r < NN) logitsT[(size_t)wave * NN + r] = p[rt][reg] + b2v;
      }
  }
}

// ---------------- softmax over N per head ----------------
__global__ void k_smax1(const float* __restrict__ logitsT, float* __restrict__ pmax,
                        float* __restrict__ psum) {
  int k = blockIdx.y;
  int tid = threadIdx.x;
  const float* L = logitsT + (size_t)k * NN;
  __shared__ float sm[256];
  float mx = -1e30f;
  for (int i = blockIdx.x * 256 + tid; i < NN; i += 128 * 256) mx = fmaxf(mx, L[i]);
  sm[tid] = mx; __syncthreads();
  for (int o = 128; o >= 1; o >>= 1) { if (tid < o) sm[tid] = fmaxf(sm[tid], sm[tid + o]); __syncthreads(); }
  float bmax = sm[0];
  __syncthreads();
  float s = 0.f;
  for (int i = blockIdx.x * 256 + tid; i < NN; i += 128 * 256) s += __expf(L[i] - bmax);
  sm[tid] = s; __syncthreads();
  for (int o = 128; o >= 1; o >>= 1) { if (tid < o) sm[tid] += sm[tid + o]; __syncthreads(); }
  if (tid == 0) { pmax[k * 128 + blockIdx.x] = bmax; psum[k * 128 + blockIdx.x] = sm[0]; }
}

__global__ void k_smax2(const float* __restrict__ pmax, const float* __restrict__ psum,
                        float* __restrict__ gs) {
  int k = blockIdx.x;
  int tid = threadIdx.x;  // 128
  __shared__ float sm[128], sv[128];
  float m = pmax[k * 128 + tid];
  sm[tid] = m; __syncthreads();
  for (int o = 64; o >= 1; o >>= 1) { if (tid < o) sm[tid] = fmaxf(sm[tid], sm[tid + o]); __syncthreads(); }
  float gm = sm[0];
  __syncthreads();
  sv[tid] = psum[k * 128 + tid] * __expf(m - gm);
  __syncthreads();
  for (int o = 64; o >= 1; o >>= 1) { if (tid < o) sv[tid] += sv[tid + o]; __syncthreads(); }
  if (tid == 0) { gs[k * 2] = gm; gs[k * 2 + 1] = sv[0]; }
}

// ------------- a = softmax, attn output, z[k][d] partials -------------
__global__ void k_attnz(const float* __restrict__ logitsT, const float* __restrict__ gs,
                        const unsigned short* __restrict__ hb, float* __restrict__ out_attn,
                        float* __restrict__ z) {
  int n0 = blockIdx.x * 128;
  int tid = threadIdx.x;
  __shared__ float a[4][128];
  for (int i = tid; i < 512; i += 256) {
    int k = i >> 7, n = i & 127;
    float v = 0.f;
    if (n0 + n < NN) v = __expf(logitsT[(size_t)k * NN + n0 + n] - gs[k * 2]) / gs[k * 2 + 1];
    a[k][n] = v;
  }
  __syncthreads();
  for (int i = tid; i < 512; i += 256) {
    int n = i >> 2, k = i & 3;
    if (n0 + n < NN) out_attn[(size_t)(n0 + n) * 4 + k] = a[k][n];
  }
  float z0 = 0.f, z1 = 0.f, z2 = 0.f, z3 = 0.f;
  int d = tid;  // 256 dims
  int nmax = NN - n0; if (nmax > 128) nmax = 128;
  for (int n = 0; n < nmax; n++) {
    float hv = bf2f(hb[(size_t)(n0 + n) * 256 + d]);
    z0 += a[0][n] * hv; z1 += a[1][n] * hv; z2 += a[2][n] * hv; z3 += a[3][n] * hv;
  }
  atomicAdd(&z[0 * 256 + d], z0);
  atomicAdd(&z[1 * 256 + d], z1);
  atomicAdd(&z[2 * 256 + d], z2);
  atomicAdd(&z[3 * 256 + d], z3);
}

// ---------------- tiny classifier ----------------
__global__ void k_cls(const float* __restrict__ z, const float* __restrict__ Wc1,
                      const float* __restrict__ bc1, const float* __restrict__ g1,
                      const float* __restrict__ b1, const float* __restrict__ Wc2,
                      const float* __restrict__ bc2, const float* __restrict__ g2,
                      const float* __restrict__ b2, const float* __restrict__ Wc3,
                      const float* __restrict__ bc3, float* __restrict__ out) {
  int tid = threadIdx.x;  // 256
  __shared__ float za[256];
  __shared__ float buf[256];
  __shared__ float c1s[128];
  __shared__ float c2s[64];
  za[tid] = 0.25f * (z[tid] + z[256 + tid] + z[512 + tid] + z[768 + tid]);
  __syncthreads();
  float v1 = 0.f;
  if (tid < 128) {
    for (int d = 0; d < 256; d++) v1 += za[d] * Wc1[d * 128 + tid];
    v1 += bc1[tid];
  }
  buf[tid] = (tid < 128) ? v1 : 0.f; __syncthreads();
  for (int o = 128; o >= 1; o >>= 1) { if (tid < o) buf[tid] += buf[tid + o]; __syncthreads(); }
  float mean1 = buf[0] * (1.f / 128.f);
  __syncthreads();
  buf[tid] = (tid < 128) ? (v1 - mean1) * (v1 - mean1) : 0.f; __syncthreads();
  for (int o = 128; o >= 1; o >>= 1) { if (tid < o) buf[tid] += buf[tid + o]; __syncthreads(); }
  float inv1 = rsqrtf(buf[0] * (1.f / 128.f) + 1e-5f);
  __syncthreads();
  if (tid < 128) c1s[tid] = fmaxf((v1 - mean1) * inv1 * g1[tid] + b1[tid], 0.f);
  __syncthreads();
  float v2 = 0.f;
  if (tid < 64) {
    for (int d = 0; d < 128; d++) v2 += c1s[d] * Wc2[d * 64 + tid];
    v2 += bc2[tid];
  }
  buf[tid] = (tid < 64) ? v2 : 0.f; __syncthreads();
  for (int o = 128; o >= 1; o >>= 1) { if (tid < o) buf[tid] += buf[tid + o]; __syncthreads(); }
  float mean2 = buf[0] * (1.f / 64.f);
  __syncthreads();
  buf[tid] = (tid < 64) ? (v2 - mean2) * (v2 - mean2) : 0.f; __syncthreads();
  for (int o = 128; o >= 1; o >>= 1) { if (tid < o) buf[tid] += buf[tid + o]; __syncthreads(); }
  float inv2 = rsqrtf(buf[0] * (1.f / 64.f) + 1e-5f);
  __syncthreads();
  if (tid < 64) c2s[tid] = fmaxf((v2 - mean2) * inv2 * g2[tid] + b2[tid], 0.f);
  __syncthreads();
  if (tid < 7) {
    float l = 0.f;
    for (int d = 0; d < 64; d++) l += c2s[d] * Wc3[d * 7 + tid];
    buf[tid] = l + bc3[tid];
  }
  __syncthreads();
  if (tid == 0) {
    float mx = -1e30f;
    for (int i = 0; i < 7; i++) mx = fmaxf(mx, buf[i]);
    float s = 0.f;
    for (int i = 0; i < 7; i++) s += __expf(buf[i] - mx);
    for (int i = 0; i < 7; i++) out[i] = __expf(buf[i] - mx) / s;
  }
}

extern "C" void kernel_launch(void* const* d_in, const int* in_sizes, int n_in,
                              void* d_out, int out_size, void* d_ws, size_t ws_size,
                              hipStream_t stream) {
  const float* x       = (const float*)d_in[0];
  const int*   ei      = (const int*)d_in[1];
  const float* W_in    = (const float*)d_in[2];
  const float* b_in    = (const float*)d_in[3];
  const float* gin_W1  = (const float*)d_in[4];
  const float* gin_b1  = (const float*)d_in[5];
  const float* gin_lng = (const float*)d_in[6];
  const float* gin_lnb = (const float*)d_in[7];
  const float* gin_W2  = (const float*)d_in[8];
  const float* gin_b2  = (const float*)d_in[9];
  const float* eps     = (const float*)d_in[10];
  const float* ln_g    = (const float*)d_in[11];
  const float* ln_b    = (const float*)d_in[12];
  const float* att_W1  = (const float*)d_in[13];
  const float* att_b1  = (const float*)d_in[14];
  const float* att_W2  = (const float*)d_in[15];
  const float* att_b2  = (const float*)d_in[16];
  const float* Wc1     = (const float*)d_in[17];
  const float* bc1     = (const float*)d_in[18];
  const float* lnc1_g  = (const float*)d_in[19];
  const float* lnc1_b  = (const float*)d_in[20];
  const float* Wc2     = (const float*)d_in[21];
  const float* bc2     = (const float*)d_in[22];
  const float* lnc2_g  = (const float*)d_in[23];
  const float* lnc2_b  = (const float*)d_in[24];
  const float* Wc3     = (const float*)d_in[25];
  const float* bc3     = (const float*)d_in[26];
  float* out = (float*)d_out;
  (void)in_sizes; (void)n_in; (void)out_size; (void)ws_size;

  char* wsb = (char*)d_ws;
  size_t off = 0;
  auto alloc = [&](size_t bytes) {
    char* p = wsb + off;
    off += (bytes + 255) & ~(size_t)255;
    return p;
  };
  float*          h       = (float*)alloc((size_t)NN * HH * 4);
  unsigned short* hb      = (unsigned short*)alloc((size_t)NN * HH * 2);
  unsigned short* mb1     = (unsigned short*)alloc((size_t)NN * HH * 2);
  unsigned short* WinT    = (unsigned short*)alloc((size_t)HH * FF * 2);
  unsigned short* g1T     = (unsigned short*)alloc((size_t)2 * HH * HH * 2);
  unsigned short* g2T     = (unsigned short*)alloc((size_t)2 * HH * HH * 2);
  unsigned short* aW1T    = (unsigned short*)alloc((size_t)4 * 128 * HH * 2);
  float*          logitsT = (float*)alloc((size_t)4 * NN * 4);
  int*            deg     = (int*)alloc((size_t)NN * 4);
  int*            rowptr  = (int*)alloc((size_t)(NN + 1) * 4);
  int*            cursor  = (int*)alloc((size_t)NN * 4);
  int*            csr_src = (int*)alloc((size_t)NE * 4);
  float*          pmax    = (float*)alloc(4 * 128 * 4);
  float*          psum    = (float*)alloc(4 * 128 * 4);
  float*          gs      = (float*)alloc(8 * 4);
  float*          z       = (float*)alloc(4 * 256 * 4);

  const int* srcv = ei;
  const int* dstv = ei + NE;

  // weight transposes + casts (tiny, batched over blockIdx.z)
  k_tcast<<<dim3((HH + 31) / 32, (FF + 31) / 32, 1), 256, 0, stream>>>(W_in, WinT, FF, HH);
  k_tcast<<<dim3(8, 8, 2), 256, 0, stream>>>(gin_W1, g1T, HH, HH);
  k_tcast<<<dim3(8, 8, 2), 256, 0, stream>>>(gin_W2, g2T, HH, HH);
  k_tcast<<<dim3(4, 8, 4), 256, 0, stream>>>(att_W1, aW1T, HH, 128);

  // CSR build
  hipMemsetAsync(deg, 0, (size_t)NN * 4, stream);
  hipMemsetAsync(z, 0, 4 * 256 * 4, stream);
  k_count<<<(NE + 255) / 256, 256, 0, stream>>>(dstv, deg);
  k_scan<<<1, 1024, 0, stream>>>(deg, rowptr);
  hipMemcpyAsync(cursor, rowptr, (size_t)NN * 4, hipMemcpyDeviceToDevice, stream);
  k_scatter<<<(NE + 255) / 256, 256, 0, stream>>>(srcv, dstv, cursor, csr_src);

  int gblocks = (NN + 63) / 64;  // 782
  // h = x @ W_in + b_in  (fp32 A cast to bf16 in staging); also emit hb
  k_mmff<<<gblocks, 256, 0, stream>>>(x, WinT, b_in, h, hb);

  for (int l = 0; l < 2; l++) {
    k_agg<<<(NN + 3) / 4, 256, 0, stream>>>(hb, rowptr, csr_src, eps, l, mb1);
    // fused GIN layer: GEMM1+LN+ReLU -> (LDS) -> GEMM2+LN+ReLU+resid -> h/hb
    if (l == 0)
      k_gin<true><<<gblocks, 256, 0, stream>>>(
          mb1, g1T + (size_t)l * HH * HH, gin_b1 + l * HH, gin_lng + l * HH, gin_lnb + l * HH,
          g2T + (size_t)l * HH * HH, gin_b2 + l * HH, ln_g + l * HH, ln_b + l * HH,
          h, h, hb);
    else
      k_gin<false><<<gblocks, 256, 0, stream>>>(
          mb1, g1T + (size_t)l * HH * HH, gin_b1 + l * HH, gin_lng + l * HH, gin_lnb + l * HH,
          g2T + (size_t)l * HH * HH, gin_b2 + l * HH, ln_g + l * HH, ln_b + l * HH,
          h, nullptr, hb);
  }

  k_att<<<gblocks, 256, 0, stream>>>(hb, aW1T, att_b1, att_W2, att_b2, logitsT);
  k_smax1<<<dim3(128, 4), 256, 0, stream>>>(logitsT, pmax, psum);
  k_smax2<<<4, 128, 0, stream>>>(pmax, psum, gs);
  k_attnz<<<(NN + 127) / 128, 256, 0, stream>>>(logitsT, gs, hb, out + 7, z);
  k_cls<<<1, 256, 0, stream>>>(z, Wc1, bc1, lnc1_g, lnc1_b, Wc2, bc2, lnc2_g, lnc2_b,
                               Wc3, bc3, out);
}

// Round 8
// 874.911 us; speedup vs baseline: 1.3399x; 1.0341x over previous
//
#include <hip/hip_runtime.h>
#include <math.h>

#define NN 50000
#define NE 800000
#define FF 768
#define HH 256

typedef __attribute__((ext_vector_type(8))) short short8;
typedef __attribute__((ext_vector_type(4))) float f32x4;

__device__ inline unsigned short f2bf(float f) {
  unsigned u = __float_as_uint(f);
  u = u + 0x7fffu + ((u >> 16) & 1u);
  return (unsigned short)(u >> 16);
}
__device__ inline float bf2f(unsigned short b) {
  return __uint_as_float(((unsigned)b) << 16);
}

// async global->LDS, 16B per lane. Dest is wave-uniform base + lane*16 (HW).
__device__ __forceinline__ void ldsload16(const unsigned short* g, unsigned short* l) {
  __builtin_amdgcn_global_load_lds(
      (const __attribute__((address_space(1))) void*)g,
      (__attribute__((address_space(3))) void*)l, 16, 0, 0);
}

// ---------------- CSR build ----------------
__global__ void k_count(const int* __restrict__ dstv, int* __restrict__ deg) {
  int e = blockIdx.x * 256 + threadIdx.x;
  if (e < NE) atomicAdd(&deg[dstv[e]], 1);
}

// single-block thread-coarsened scan: 1024 threads x 49 elems
__global__ void k_scan(const int* __restrict__ deg, int* __restrict__ rowptr) {
  const int CH = 49;  // 1024*49 = 50176 >= NN
  int tid = threadIdx.x;
  int lane = tid & 63, w = tid >> 6;
  int base = tid * CH;
  int sum = 0;
  for (int i = 0; i < CH; i++) {
    int idx = base + i;
    if (idx < NN) sum += deg[idx];
  }
  int incl = sum;
  for (int off = 1; off < 64; off <<= 1) {
    int tv = __shfl_up(incl, off, 64);
    if (lane >= off) incl += tv;
  }
  __shared__ int ws[16];
  if (lane == 63) ws[w] = incl;
  __syncthreads();
  if (tid == 0) {
    int c = 0;
    for (int i = 0; i < 16; i++) { int tv = ws[i]; ws[i] = c; c += tv; }
  }
  __syncthreads();
  int run = ws[w] + (incl - sum);
  if (tid == 0) rowptr[0] = 0;
  for (int i = 0; i < CH; i++) {
    int idx = base + i;
    if (idx < NN) { run += deg[idx]; rowptr[idx + 1] = run; }
  }
}

__global__ void k_scatter(const int* __restrict__ srcv, const int* __restrict__ dstv,
                          int* __restrict__ cursor, int* __restrict__ csr_src) {
  int e = blockIdx.x * 256 + threadIdx.x;
  if (e < NE) {
    int d = dstv[e];
    int pos = atomicAdd(&cursor[d], 1);
    csr_src[pos] = srcv[e];
  }
}

// ------------- aggregation (bf16 gather): mb = bf16((1+eps)*hb + sum hb[src]) -------------
// 4-wide edge batching: break the index->gather dependent chain (4 gathers in flight).
__global__ void k_agg(const unsigned short* __restrict__ hb, const int* __restrict__ rowptr,
                      const int* __restrict__ csr_src, const float* __restrict__ eps,
                      int layer, unsigned short* __restrict__ mb) {
  int node = (blockIdx.x * blockDim.x + threadIdx.x) >> 6;
  int lane = threadIdx.x & 63;
  if (node >= NN) return;
  int beg = rowptr[node], end = rowptr[node + 1];
  const ushort4* hv = (const ushort4*)hb;
  float ax = 0.f, ay = 0.f, az = 0.f, aw = 0.f;
  int e = beg;
  for (; e + 3 < end; e += 4) {
    int s0 = csr_src[e], s1 = csr_src[e + 1], s2 = csr_src[e + 2], s3 = csr_src[e + 3];
    ushort4 v0 = hv[(size_t)s0 * 64 + lane];
    ushort4 v1 = hv[(size_t)s1 * 64 + lane];
    ushort4 v2 = hv[(size_t)s2 * 64 + lane];
    ushort4 v3 = hv[(size_t)s3 * 64 + lane];
    ax += bf2f(v0.x) + bf2f(v1.x) + bf2f(v2.x) + bf2f(v3.x);
    ay += bf2f(v0.y) + bf2f(v1.y) + bf2f(v2.y) + bf2f(v3.y);
    az += bf2f(v0.z) + bf2f(v1.z) + bf2f(v2.z) + bf2f(v3.z);
    aw += bf2f(v0.w) + bf2f(v1.w) + bf2f(v2.w) + bf2f(v3.w);
  }
  for (; e < end; ++e) {
    int s = csr_src[e];
    ushort4 v = hv[(size_t)s * 64 + lane];
    ax += bf2f(v.x); ay += bf2f(v.y); az += bf2f(v.z); aw += bf2f(v.w);
  }
  float ep = 1.0f + eps[layer];
  ushort4 h0 = hv[(size_t)node * 64 + lane];
  ax += ep * bf2f(h0.x); ay += ep * bf2f(h0.y);
  az += ep * bf2f(h0.z); aw += ep * bf2f(h0.w);
  ushort4 o;
  o.x = f2bf(ax); o.y = f2bf(ay); o.z = f2bf(az); o.w = f2bf(aw);
  *(ushort4*)&mb[(size_t)node * 256 + lane * 4] = o;
}

// ------------- transpose + cast: dst[c][r] = bf16(src[r][c]), src is R x C, batched over z -------------
__global__ void k_tcast(const float* __restrict__ src0, unsigned short* __restrict__ dst0,
                        int R, int C) {
  const float* src = src0 + (size_t)blockIdx.z * R * C;
  unsigned short* dst = dst0 + (size_t)blockIdx.z * R * C;
  __shared__ float tile[32][33];
  int bx = blockIdx.x * 32, by = blockIdx.y * 32;
  int tx = threadIdx.x & 31, ty = threadIdx.x >> 5;  // 32 x 8
  for (int i = 0; i < 32; i += 8) {
    int r = by + ty + i, c = bx + tx;
    tile[ty + i][tx] = (r < R && c < C) ? src[(size_t)r * C + c] : 0.f;
  }
  __syncthreads();
  for (int i = 0; i < 32; i += 8) {
    int c = bx + ty + i, r = by + tx;
    if (c < C && r < R) dst[(size_t)c * R + r] = f2bf(tile[tx][ty + i]);
  }
}

// ---------------- input projection GEMM: K=768, fp32 A cast in staging (R6 path) ----------------
__global__ __launch_bounds__(256) void k_mmff(
    const float* __restrict__ x, const unsigned short* __restrict__ Bt,
    const float* __restrict__ bias, float* __restrict__ outf,
    unsigned short* __restrict__ outb) {
  __shared__ unsigned short As[64 * 32];   // 4 KB, linear (swizzled slots)
  __shared__ unsigned short Bs[256 * 32];  // 16 KB, linear (swizzled slots)
  int t = threadIdx.x, lane = t & 63, wave = t >> 6;
  int row0 = blockIdx.x * 64;
  f32x4 acc[4][4];
#pragma unroll
  for (int i = 0; i < 4; i++)
#pragma unroll
    for (int j = 0; j < 4; j++) acc[i][j] = (f32x4)(0.f);
  int m16 = lane & 15, kq = lane >> 4;
  int arow = t >> 2, a2 = t & 3;
  int asl = a2 ^ (arow & 3);
  int agr = row0 + arow; if (agr >= NN) agr = NN - 1;
  int brow_[4], bsl_[4];
#pragma unroll
  for (int j = 0; j < 4; j++) {
    int s = j * 256 + t;
    brow_[j] = s >> 2;
    bsl_[j] = (s & 3) ^ (brow_[j] & 3);
  }
  for (int k0 = 0; k0 < FF; k0 += 32) {
    {
      const float* Af = x + (size_t)agr * FF + k0 + asl * 8;
      float4 f0 = *(const float4*)Af;
      float4 f1 = *(const float4*)(Af + 4);
      short8 v;
      v[0] = (short)f2bf(f0.x); v[1] = (short)f2bf(f0.y);
      v[2] = (short)f2bf(f0.z); v[3] = (short)f2bf(f0.w);
      v[4] = (short)f2bf(f1.x); v[5] = (short)f2bf(f1.y);
      v[6] = (short)f2bf(f1.z); v[7] = (short)f2bf(f1.w);
      *(short8*)&As[arow * 32 + a2 * 8] = v;
    }
#pragma unroll
    for (int j = 0; j < 4; j++)
      ldsload16(&Bt[(size_t)brow_[j] * FF + k0 + bsl_[j] * 8],
                &Bs[(j * 256 + wave * 64) * 8]);
    __syncthreads();
    short8 a[4], b[4];
#pragma unroll
    for (int rt = 0; rt < 4; rt++) {
      int row = rt * 16 + m16;
      a[rt] = *(const short8*)&As[row * 32 + ((kq ^ (row & 3)) * 8)];
    }
#pragma unroll
    for (int ct = 0; ct < 4; ct++) {
      int row = wave * 64 + ct * 16 + m16;
      b[ct] = *(const short8*)&Bs[row * 32 + ((kq ^ (row & 3)) * 8)];
    }
#pragma unroll
    for (int rt = 0; rt < 4; rt++)
#pragma unroll
      for (int ct = 0; ct < 4; ct++)
        acc[rt][ct] = __builtin_amdgcn_mfma_f32_16x16x32_bf16(a[rt], b[ct], acc[rt][ct], 0, 0, 0);
    __syncthreads();
  }
  int colbase = wave * 64 + m16;
  float bv[4];
#pragma unroll
  for (int ct = 0; ct < 4; ct++) bv[ct] = bias[colbase + ct * 16];
#pragma unroll
  for (int rt = 0; rt < 4; rt++)
#pragma unroll
    for (int reg = 0; reg < 4; reg++) {
      int r = row0 + rt * 16 + kq * 4 + reg;
      if (r < NN) {
#pragma unroll
        for (int ct = 0; ct < 4; ct++) {
          float v = acc[rt][ct][reg] + bv[ct];
          outf[(size_t)r * 256 + colbase + ct * 16] = v;
          outb[(size_t)r * 256 + colbase + ct * 16] = f2bf(v);
        }
      }
    }
}

// ---------------- fused GIN layer (+ optional attention logits) ----------------
// GEMM1+LN+ReLU -> T1(LDS) -> GEMM2+LN+ReLU+resid -> h/hb [-> T1 -> att logits if ATT]
// All K-loops use the counted-vmcnt double-buffered gload_lds pipeline.
// T1 swizzle: row r, 16B-slot s stored at phys slot s^(r&31).
template <bool WF, bool ATT>
__global__ __launch_bounds__(256) void k_gin(
    const unsigned short* __restrict__ Ab,
    const unsigned short* __restrict__ B1t, const float* __restrict__ bias1,
    const float* __restrict__ g1v, const float* __restrict__ be1,
    const unsigned short* __restrict__ B2t, const float* __restrict__ bias2,
    const float* __restrict__ g2v, const float* __restrict__ be2,
    const float* __restrict__ resid, float* __restrict__ outf,
    unsigned short* __restrict__ outb,
    const unsigned short* __restrict__ aW1T, const float* __restrict__ ab1,
    const float* __restrict__ aW2v, const float* __restrict__ ab2,
    float* __restrict__ logitsT) {
  __shared__ unsigned short As[2][64 * 32];   // 2 x 4 KB
  __shared__ unsigned short Bs[2][256 * 32];  // 2 x 16 KB
  __shared__ unsigned short T1[64 * 256];     // 32 KB, slot-swizzled
  __shared__ float redS[4][64];
  __shared__ float redQ[4][64];
  __shared__ float mvM[64], mvI[64];
  __shared__ float lg[4][64];
  int t = threadIdx.x, lane = t & 63, wave = t >> 6;
  int row0 = blockIdx.x * 64;
  int m16 = lane & 15, kq = lane >> 4;
  int colbase = wave * 64 + m16;
  int arow = t >> 2, a2 = t & 3;
  int asl = a2 ^ (arow & 3);
  int agr = row0 + arow; if (agr >= NN) agr = NN - 1;
  const unsigned short* Ag = Ab + (size_t)agr * 256 + asl * 8;
  int brow_[4], bsl_[4];
#pragma unroll
  for (int j = 0; j < 4; j++) {
    int s = j * 256 + t;
    brow_[j] = s >> 2;
    bsl_[j] = (s & 3) ^ (brow_[j] & 3);
  }
  auto stage1 = [&](int c, int p) {  // 5 loads: A chunk + B1 chunk
    int k0 = c * 32;
    ldsload16(Ag + k0, &As[p][wave * 512]);
#pragma unroll
    for (int j = 0; j < 4; j++)
      ldsload16(&B1t[(size_t)brow_[j] * 256 + k0 + bsl_[j] * 8],
                &Bs[p][(j * 256 + wave * 64) * 8]);
  };
  auto stageB = [&](const unsigned short* Bp_, int c, int p) {  // 4 loads: B chunk only
    int k0 = c * 32;
#pragma unroll
    for (int j = 0; j < 4; j++)
      ldsload16(&Bp_[(size_t)brow_[j] * 256 + k0 + bsl_[j] * 8],
                &Bs[p][(j * 256 + wave * 64) * 8]);
  };

  f32x4 acc[4][4];
#pragma unroll
  for (int i = 0; i < 4; i++)
#pragma unroll
    for (int j = 0; j < 4; j++) acc[i][j] = (f32x4)(0.f);

  // ---------------- GEMM1 K-loop ----------------
  stage1(0, 0);
  stage1(1, 1);
#pragma unroll
  for (int c = 0; c < 8; c++) {
    if (c < 7) asm volatile("s_waitcnt vmcnt(5)" ::: "memory");
    else       asm volatile("s_waitcnt vmcnt(0)" ::: "memory");
    __builtin_amdgcn_s_barrier();
    asm volatile("" ::: "memory");
    const unsigned short* Ap = As[c & 1];
    const unsigned short* Bp = Bs[c & 1];
    short8 a[4], b[4];
#pragma unroll
    for (int rt = 0; rt < 4; rt++) {
      int row = rt * 16 + m16;
      a[rt] = *(const short8*)&Ap[row * 32 + ((kq ^ (row & 3)) * 8)];
    }
#pragma unroll
    for (int ct = 0; ct < 4; ct++) {
      int row = wave * 64 + ct * 16 + m16;
      b[ct] = *(const short8*)&Bp[row * 32 + ((kq ^ (row & 3)) * 8)];
    }
#pragma unroll
    for (int rt = 0; rt < 4; rt++)
#pragma unroll
      for (int ct = 0; ct < 4; ct++)
        acc[rt][ct] = __builtin_amdgcn_mfma_f32_16x16x32_bf16(a[rt], b[ct], acc[rt][ct], 0, 0, 0);
    asm volatile("" ::: "memory");
    __builtin_amdgcn_s_barrier();
    asm volatile("" ::: "memory");
    if (c + 2 < 8) stage1(c + 2, c & 1);
  }

  // ---------------- epilogue 1: bias + LN + ReLU -> T1 (swizzled) ----------------
  {
    float bv[4];
#pragma unroll
    for (int ct = 0; ct < 4; ct++) bv[ct] = bias1[colbase + ct * 16];
    float s[4][4], q[4][4];
#pragma unroll
    for (int rt = 0; rt < 4; rt++)
#pragma unroll
      for (int reg = 0; reg < 4; reg++) { s[rt][reg] = 0.f; q[rt][reg] = 0.f; }
#pragma unroll
    for (int rt = 0; rt < 4; rt++)
#pragma unroll
      for (int ct = 0; ct < 4; ct++)
#pragma unroll
        for (int reg = 0; reg < 4; reg++) {
          float v = acc[rt][ct][reg] + bv[ct];
          acc[rt][ct][reg] = v;
          s[rt][reg] += v;
          q[rt][reg] += v * v;
        }
#pragma unroll
    for (int off = 1; off < 16; off <<= 1) {
#pragma unroll
      for (int rt = 0; rt < 4; rt++)
#pragma unroll
        for (int reg = 0; reg < 4; reg++) {
          s[rt][reg] += __shfl_xor(s[rt][reg], off, 64);
          q[rt][reg] += __shfl_xor(q[rt][reg], off, 64);
        }
    }
    if (m16 == 0) {
#pragma unroll
      for (int rt = 0; rt < 4; rt++)
#pragma unroll
        for (int reg = 0; reg < 4; reg++) {
          redS[wave][rt * 16 + kq * 4 + reg] = s[rt][reg];
          redQ[wave][rt * 16 + kq * 4 + reg] = q[rt][reg];
        }
    }
    __syncthreads();
    if (t < 64) {
      float ss = redS[0][t] + redS[1][t] + redS[2][t] + redS[3][t];
      float qq = redQ[0][t] + redQ[1][t] + redQ[2][t] + redQ[3][t];
      float mean = ss * (1.f / 256.f);
      float var = qq * (1.f / 256.f) - mean * mean;
      mvM[t] = mean;
      mvI[t] = rsqrtf(var + 1e-5f);
    }
    __syncthreads();
    float gv[4], bev[4];
#pragma unroll
    for (int ct = 0; ct < 4; ct++) { gv[ct] = g1v[colbase + ct * 16]; bev[ct] = be1[colbase + ct * 16]; }
#pragma unroll
    for (int rt = 0; rt < 4; rt++)
#pragma unroll
      for (int reg = 0; reg < 4; reg++) {
        int rr = rt * 16 + kq * 4 + reg;
        float mean = mvM[rr], inv = mvI[rr];
#pragma unroll
        for (int ct = 0; ct < 4; ct++) {
          int col = colbase + ct * 16;
          float val = fmaxf((acc[rt][ct][reg] - mean) * inv * gv[ct] + bev[ct], 0.f);
          T1[rr * 256 + (((col >> 3) ^ (rr & 31)) * 8) + (col & 7)] = f2bf(val);
        }
      }
    __syncthreads();
  }

  // ---------------- GEMM2 K-loop (A from T1, B2 pipelined) ----------------
#pragma unroll
  for (int i = 0; i < 4; i++)
#pragma unroll
    for (int j = 0; j < 4; j++) acc[i][j] = (f32x4)(0.f);
  stageB(B2t, 0, 0);
  stageB(B2t, 1, 1);
#pragma unroll
  for (int c = 0; c < 8; c++) {
    if (c < 7) asm volatile("s_waitcnt vmcnt(4)" ::: "memory");
    else       asm volatile("s_waitcnt vmcnt(0)" ::: "memory");
    __builtin_amdgcn_s_barrier();
    asm volatile("" ::: "memory");
    const unsigned short* Bp = Bs[c & 1];
    short8 a[4], b[4];
#pragma unroll
    for (int rt = 0; rt < 4; rt++) {
      int row = rt * 16 + m16;
      int sl = (c * 4 + kq) ^ (row & 31);
      a[rt] = *(const short8*)&T1[row * 256 + sl * 8];
    }
#pragma unroll
    for (int ct = 0; ct < 4; ct++) {
      int row = wave * 64 + ct * 16 + m16;
      b[ct] = *(const short8*)&Bp[row * 32 + ((kq ^ (row & 3)) * 8)];
    }
#pragma unroll
    for (int rt = 0; rt < 4; rt++)
#pragma unroll
      for (int ct = 0; ct < 4; ct++)
        acc[rt][ct] = __builtin_amdgcn_mfma_f32_16x16x32_bf16(a[rt], b[ct], acc[rt][ct], 0, 0, 0);
    asm volatile("" ::: "memory");
    __builtin_amdgcn_s_barrier();
    asm volatile("" ::: "memory");
    if (c + 2 < 8) stageB(B2t, c + 2, c & 1);
  }

  // ---------------- epilogue 2: bias + LN + ReLU + resid -> outf/outb (+T1 if ATT) ----------------
  {
    float bv[4];
#pragma unroll
    for (int ct = 0; ct < 4; ct++) bv[ct] = bias2[colbase + ct * 16];
    float s[4][4], q[4][4];
#pragma unroll
    for (int rt = 0; rt < 4; rt++)
#pragma unroll
      for (int reg = 0; reg < 4; reg++) { s[rt][reg] = 0.f; q[rt][reg] = 0.f; }
#pragma unroll
    for (int rt = 0; rt < 4; rt++)
#pragma unroll
      for (int ct = 0; ct < 4; ct++)
#pragma unroll
        for (int reg = 0; reg < 4; reg++) {
          float v = acc[rt][ct][reg] + bv[ct];
          acc[rt][ct][reg] = v;
          s[rt][reg] += v;
          q[rt][reg] += v * v;
        }
#pragma unroll
    for (int off = 1; off < 16; off <<= 1) {
#pragma unroll
      for (int rt = 0; rt < 4; rt++)
#pragma unroll
        for (int reg = 0; reg < 4; reg++) {
          s[rt][reg] += __shfl_xor(s[rt][reg], off, 64);
          q[rt][reg] += __shfl_xor(q[rt][reg], off, 64);
        }
    }
    if (m16 == 0) {
#pragma unroll
      for (int rt = 0; rt < 4; rt++)
#pragma unroll
        for (int reg = 0; reg < 4; reg++) {
          redS[wave][rt * 16 + kq * 4 + reg] = s[rt][reg];
          redQ[wave][rt * 16 + kq * 4 + reg] = q[rt][reg];
        }
    }
    __syncthreads();
    if (t < 64) {
      float ss = redS[0][t] + redS[1][t] + redS[2][t] + redS[3][t];
      float qq = redQ[0][t] + redQ[1][t] + redQ[2][t] + redQ[3][t];
      float mean = ss * (1.f / 256.f);
      float var = qq * (1.f / 256.f) - mean * mean;
      mvM[t] = mean;
      mvI[t] = rsqrtf(var + 1e-5f);
    }
    __syncthreads();
    float gv[4], bev[4];
#pragma unroll
    for (int ct = 0; ct < 4; ct++) { gv[ct] = g2v[colbase + ct * 16]; bev[ct] = be2[colbase + ct * 16]; }
#pragma unroll
    for (int rt = 0; rt < 4; rt++)
#pragma unroll
      for (int reg = 0; reg < 4; reg++) {
        int rr = rt * 16 + kq * 4 + reg;
        int r = row0 + rr;
        if (r >= NN) continue;
        float mean = mvM[rr], inv = mvI[rr];
#pragma unroll
        for (int ct = 0; ct < 4; ct++) {
          int col = colbase + ct * 16;
          float val = fmaxf((acc[rt][ct][reg] - mean) * inv * gv[ct] + bev[ct], 0.f);
          val += resid[(size_t)r * 256 + col];
          if (WF) outf[(size_t)r * 256 + col] = val;
          outb[(size_t)r * 256 + col] = f2bf(val);
          if (ATT) T1[rr * 256 + (((col >> 3) ^ (rr & 31)) * 8) + (col & 7)] = f2bf(val);
        }
      }
  }

  // ---------------- attention logits (fused; R2-verified mapping) ----------------
  if (ATT) {
    ((float*)lg)[t] = 0.f;  // 4 heads x 64 rows
    __syncthreads();        // orders T1 writes + lg zero before pass reads/adds
#pragma unroll
    for (int pass = 0; pass < 2; pass++) {
#pragma unroll
      for (int i = 0; i < 4; i++)
#pragma unroll
        for (int j = 0; j < 4; j++) acc[i][j] = (f32x4)(0.f);
      const unsigned short* Wp = aW1T + (size_t)pass * 256 * 256;
      stageB(Wp, 0, 0);
      stageB(Wp, 1, 1);
#pragma unroll
      for (int c = 0; c < 8; c++) {
        if (c < 7) asm volatile("s_waitcnt vmcnt(4)" ::: "memory");
        else       asm volatile("s_waitcnt vmcnt(0)" ::: "memory");
        __builtin_amdgcn_s_barrier();
        asm volatile("" ::: "memory");
        const unsigned short* Bp = Bs[c & 1];
        short8 a[4], b[4];
#pragma unroll
        for (int rt = 0; rt < 4; rt++) {
          int row = rt * 16 + m16;
          int sl = (c * 4 + kq) ^ (row & 31);
          a[rt] = *(const short8*)&T1[row * 256 + sl * 8];
        }
#pragma unroll
        for (int ct = 0; ct < 4; ct++) {
          int row = wave * 64 + ct * 16 + m16;
          b[ct] = *(const short8*)&Bp[row * 32 + ((kq ^ (row & 3)) * 8)];
        }
#pragma unroll
        for (int rt = 0; rt < 4; rt++)
#pragma unroll
          for (int ct = 0; ct < 4; ct++)
            acc[rt][ct] = __builtin_amdgcn_mfma_f32_16x16x32_bf16(a[rt], b[ct], acc[rt][ct], 0, 0, 0);
        asm volatile("" ::: "memory");
        __builtin_amdgcn_s_barrier();
        asm volatile("" ::: "memory");
        if (c + 2 < 8) stageB(Wp, c + 2, c & 1);
      }
      int head = pass * 2 + (wave >> 1);
      const float* b1k = ab1 + head * 128;
      const float* w2k = aW2v + head * 128;
      float p[4][4];
#pragma unroll
      for (int rt = 0; rt < 4; rt++)
#pragma unroll
        for (int reg = 0; reg < 4; reg++) p[rt][reg] = 0.f;
#pragma unroll
      for (int ct = 0; ct < 4; ct++) {
        int hcol = (wave & 1) * 64 + ct * 16 + m16;
        float b1v = b1k[hcol], w2v = w2k[hcol];
#pragma unroll
        for (int rt = 0; rt < 4; rt++)
#pragma unroll
          for (int reg = 0; reg < 4; reg++) {
            float xv = acc[rt][ct][reg] + b1v;
            xv = fminf(fmaxf(xv, -10.f), 10.f);
            float ex = __expf(2.f * xv);
            p[rt][reg] += (ex - 1.f) / (ex + 1.f) * w2v;
          }
      }
#pragma unroll
      for (int off = 1; off < 16; off <<= 1)
#pragma unroll
        for (int rt = 0; rt < 4; rt++)
#pragma unroll
          for (int reg = 0; reg < 4; reg++) p[rt][reg] += __shfl_xor(p[rt][reg], off, 64);
      if (m16 == 0) {
#pragma unroll
        for (int rt = 0; rt < 4; rt++)
#pragma unroll
          for (int reg = 0; reg < 4; reg++)
            atomicAdd(&lg[head][rt * 16 + kq * 4 + reg], p[rt][reg]);
      }
    }
    __syncthreads();
    int hh = t >> 6, rr2 = t & 63;
    int r = row0 + rr2;
    if (r < NN) logitsT[(size_t)hh * NN + r] = lg[hh][rr2] + ab2[hh];
  }
}

// ---------------- softmax over N per head ----------------
__global__ void k_smax1(const float* __restrict__ logitsT, float* __restrict__ pmax,
                        float* __restrict__ psum) {
  int k = blockIdx.y;
  int tid = threadIdx.x;
  const float* L = logitsT + (size_t)k * NN;
  __shared__ float sm[256];
  float mx = -1e30f;
  for (int i = blockIdx.x * 256 + tid; i < NN; i += 128 * 256) mx = fmaxf(mx, L[i]);
  sm[tid] = mx; __syncthreads();
  for (int o = 128; o >= 1; o >>= 1) { if (tid < o) sm[tid] = fmaxf(sm[tid], sm[tid + o]); __syncthreads(); }
  float bmax = sm[0];
  __syncthreads();
  float s = 0.f;
  for (int i = blockIdx.x * 256 + tid; i < NN; i += 128 * 256) s += __expf(L[i] - bmax);
  sm[tid] = s; __syncthreads();
  for (int o = 128; o >= 1; o >>= 1) { if (tid < o) sm[tid] += sm[tid + o]; __syncthreads(); }
  if (tid == 0) { pmax[k * 128 + blockIdx.x] = bmax; psum[k * 128 + blockIdx.x] = sm[0]; }
}

__global__ void k_smax2(const float* __restrict__ pmax, const float* __restrict__ psum,
                        float* __restrict__ gs) {
  int k = blockIdx.x;
  int tid = threadIdx.x;  // 128
  __shared__ float sm[128], sv[128];
  float m = pmax[k * 128 + tid];
  sm[tid] = m; __syncthreads();
  for (int o = 64; o >= 1; o >>= 1) { if (tid < o) sm[tid] = fmaxf(sm[tid], sm[tid + o]); __syncthreads(); }
  float gm = sm[0];
  __syncthreads();
  sv[tid] = psum[k * 128 + tid] * __expf(m - gm);
  __syncthreads();
  for (int o = 64; o >= 1; o >>= 1) { if (tid < o) sv[tid] += sv[tid + o]; __syncthreads(); }
  if (tid == 0) { gs[k * 2] = gm; gs[k * 2 + 1] = sv[0]; }
}

// ------------- a = softmax, attn output, z[k][d] partials -------------
__global__ void k_attnz(const float* __restrict__ logitsT, const float* __restrict__ gs,
                        const unsigned short* __restrict__ hb, float* __restrict__ out_attn,
                        float* __restrict__ z) {
  int n0 = blockIdx.x * 128;
  int tid = threadIdx.x;
  __shared__ float a[4][128];
  for (int i = tid; i < 512; i += 256) {
    int k = i >> 7, n = i & 127;
    float v = 0.f;
    if (n0 + n < NN) v = __expf(logitsT[(size_t)k * NN + n0 + n] - gs[k * 2]) / gs[k * 2 + 1];
    a[k][n] = v;
  }
  __syncthreads();
  for (int i = tid; i < 512; i += 256) {
    int n = i >> 2, k = i & 3;
    if (n0 + n < NN) out_attn[(size_t)(n0 + n) * 4 + k] = a[k][n];
  }
  float z0 = 0.f, z1 = 0.f, z2 = 0.f, z3 = 0.f;
  int d = tid;  // 256 dims
  int nmax = NN - n0; if (nmax > 128) nmax = 128;
  for (int n = 0; n < nmax; n++) {
    float hv = bf2f(hb[(size_t)(n0 + n) * 256 + d]);
    z0 += a[0][n] * hv; z1 += a[1][n] * hv; z2 += a[2][n] * hv; z3 += a[3][n] * hv;
  }
  atomicAdd(&z[0 * 256 + d], z0);
  atomicAdd(&z[1 * 256 + d], z1);
  atomicAdd(&z[2 * 256 + d], z2);
  atomicAdd(&z[3 * 256 + d], z3);
}

// ---------------- tiny classifier ----------------
__global__ void k_cls(const float* __restrict__ z, const float* __restrict__ Wc1,
                      const float* __restrict__ bc1, const float* __restrict__ g1,
                      const float* __restrict__ b1, const float* __restrict__ Wc2,
                      const float* __restrict__ bc2, const float* __restrict__ g2,
                      const float* __restrict__ b2, const float* __restrict__ Wc3,
                      const float* __restrict__ bc3, float* __restrict__ out) {
  int tid = threadIdx.x;  // 256
  __shared__ float za[256];
  __shared__ float buf[256];
  __shared__ float c1s[128];
  __shared__ float c2s[64];
  za[tid] = 0.25f * (z[tid] + z[256 + tid] + z[512 + tid] + z[768 + tid]);
  __syncthreads();
  float v1 = 0.f;
  if (tid < 128) {
    for (int d = 0; d < 256; d++) v1 += za[d] * Wc1[d * 128 + tid];
    v1 += bc1[tid];
  }
  buf[tid] = (tid < 128) ? v1 : 0.f; __syncthreads();
  for (int o = 128; o >= 1; o >>= 1) { if (tid < o) buf[tid] += buf[tid + o]; __syncthreads(); }
  float mean1 = buf[0] * (1.f / 128.f);
  __syncthreads();
  buf[tid] = (tid < 128) ? (v1 - mean1) * (v1 - mean1) : 0.f; __syncthreads();
  for (int o = 128; o >= 1; o >>= 1) { if (tid < o) buf[tid] += buf[tid + o]; __syncthreads(); }
  float inv1 = rsqrtf(buf[0] * (1.f / 128.f) + 1e-5f);
  __syncthreads();
  if (tid < 128) c1s[tid] = fmaxf((v1 - mean1) * inv1 * g1[tid] + b1[tid], 0.f);
  __syncthreads();
  float v2 = 0.f;
  if (tid < 64) {
    for (int d = 0; d < 128; d++) v2 += c1s[d] * Wc2[d * 64 + tid];
    v2 += bc2[tid];
  }
  buf[tid] = (tid < 64) ? v2 : 0.f; __syncthreads();
  for (int o = 128; o >= 1; o >>= 1) { if (tid < o) buf[tid] += buf[tid + o]; __syncthreads(); }
  float mean2 = buf[0] * (1.f / 64.f);
  __syncthreads();
  buf[tid] = (tid < 64) ? (v2 - mean2) * (v2 - mean2) : 0.f; __syncthreads();
  for (int o = 128; o >= 1; o >>= 1) { if (tid < o) buf[tid] += buf[tid + o]; __syncthreads(); }
  float inv2 = rsqrtf(buf[0] * (1.f / 64.f) + 1e-5f);
  __syncthreads();
  if (tid < 64) c2s[tid] = fmaxf((v2 - mean2) * inv2 * g2[tid] + b2[tid], 0.f);
  __syncthreads();
  if (tid < 7) {
    float l = 0.f;
    for (int d = 0; d < 64; d++) l += c2s[d] * Wc3[d * 7 + tid];
    buf[tid] = l + bc3[tid];
  }
  __syncthreads();
  if (tid == 0) {
    float mx = -1e30f;
    for (int i = 0; i < 7; i++) mx = fmaxf(mx, buf[i]);
    float s = 0.f;
    for (int i = 0; i < 7; i++) s += __expf(buf[i] - mx);
    for (int i = 0; i < 7; i++) out[i] = __expf(buf[i] - mx) / s;
  }
}

extern "C" void kernel_launch(void* const* d_in, const int* in_sizes, int n_in,
                              void* d_out, int out_size, void* d_ws, size_t ws_size,
                              hipStream_t stream) {
  const float* x       = (const float*)d_in[0];
  const int*   ei      = (const int*)d_in[1];
  const float* W_in    = (const float*)d_in[2];
  const float* b_in    = (const float*)d_in[3];
  const float* gin_W1  = (const float*)d_in[4];
  const float* gin_b1  = (const float*)d_in[5];
  const float* gin_lng = (const float*)d_in[6];
  const float* gin_lnb = (const float*)d_in[7];
  const float* gin_W2  = (const float*)d_in[8];
  const float* gin_b2  = (const float*)d_in[9];
  const float* eps     = (const float*)d_in[10];
  const float* ln_g    = (const float*)d_in[11];
  const float* ln_b    = (const float*)d_in[12];
  const float* att_W1  = (const float*)d_in[13];
  const float* att_b1  = (const float*)d_in[14];
  const float* att_W2  = (const float*)d_in[15];
  const float* att_b2  = (const float*)d_in[16];
  const float* Wc1     = (const float*)d_in[17];
  const float* bc1     = (const float*)d_in[18];
  const float* lnc1_g  = (const float*)d_in[19];
  const float* lnc1_b  = (const float*)d_in[20];
  const float* Wc2     = (const float*)d_in[21];
  const float* bc2     = (const float*)d_in[22];
  const float* lnc2_g  = (const float*)d_in[23];
  const float* lnc2_b  = (const float*)d_in[24];
  const float* Wc3     = (const float*)d_in[25];
  const float* bc3     = (const float*)d_in[26];
  float* out = (float*)d_out;
  (void)in_sizes; (void)n_in; (void)out_size; (void)ws_size;

  char* wsb = (char*)d_ws;
  size_t off = 0;
  auto alloc = [&](size_t bytes) {
    char* p = wsb + off;
    off += (bytes + 255) & ~(size_t)255;
    return p;
  };
  float*          h       = (float*)alloc((size_t)NN * HH * 4);
  unsigned short* hb      = (unsigned short*)alloc((size_t)NN * HH * 2);
  unsigned short* mb1     = (unsigned short*)alloc((size_t)NN * HH * 2);
  unsigned short* WinT    = (unsigned short*)alloc((size_t)HH * FF * 2);
  unsigned short* g1T     = (unsigned short*)alloc((size_t)2 * HH * HH * 2);
  unsigned short* g2T     = (unsigned short*)alloc((size_t)2 * HH * HH * 2);
  unsigned short* aW1T    = (unsigned short*)alloc((size_t)4 * 128 * HH * 2);
  float*          logitsT = (float*)alloc((size_t)4 * NN * 4);
  int*            deg     = (int*)alloc((size_t)NN * 4);
  int*            rowptr  = (int*)alloc((size_t)(NN + 1) * 4);
  int*            cursor  = (int*)alloc((size_t)NN * 4);
  int*            csr_src = (int*)alloc((size_t)NE * 4);
  float*          pmax    = (float*)alloc(4 * 128 * 4);
  float*          psum    = (float*)alloc(4 * 128 * 4);
  float*          gs      = (float*)alloc(8 * 4);
  float*          z       = (float*)alloc(4 * 256 * 4);

  const int* srcv = ei;
  const int* dstv = ei + NE;

  // weight transposes + casts (tiny, batched over blockIdx.z)
  k_tcast<<<dim3((HH + 31) / 32, (FF + 31) / 32, 1), 256, 0, stream>>>(W_in, WinT, FF, HH);
  k_tcast<<<dim3(8, 8, 2), 256, 0, stream>>>(gin_W1, g1T, HH, HH);
  k_tcast<<<dim3(8, 8, 2), 256, 0, stream>>>(gin_W2, g2T, HH, HH);
  k_tcast<<<dim3(4, 8, 4), 256, 0, stream>>>(att_W1, aW1T, HH, 128);

  // CSR build
  hipMemsetAsync(deg, 0, (size_t)NN * 4, stream);
  hipMemsetAsync(z, 0, 4 * 256 * 4, stream);
  k_count<<<(NE + 255) / 256, 256, 0, stream>>>(dstv, deg);
  k_scan<<<1, 1024, 0, stream>>>(deg, rowptr);
  hipMemcpyAsync(cursor, rowptr, (size_t)NN * 4, hipMemcpyDeviceToDevice, stream);
  k_scatter<<<(NE + 255) / 256, 256, 0, stream>>>(srcv, dstv, cursor, csr_src);

  int gblocks = (NN + 63) / 64;  // 782
  // h = x @ W_in + b_in  (fp32 A cast to bf16 in staging); also emit hb
  k_mmff<<<gblocks, 256, 0, stream>>>(x, WinT, b_in, h, hb);

  for (int l = 0; l < 2; l++) {
    k_agg<<<(NN + 3) / 4, 256, 0, stream>>>(hb, rowptr, csr_src, eps, l, mb1);
    // fused GIN layer: GEMM1+LN+ReLU -> (LDS) -> GEMM2+LN+ReLU+resid -> h/hb [+att logits]
    if (l == 0)
      k_gin<true, false><<<gblocks, 256, 0, stream>>>(
          mb1, g1T + (size_t)l * HH * HH, gin_b1 + l * HH, gin_lng + l * HH, gin_lnb + l * HH,
          g2T + (size_t)l * HH * HH, gin_b2 + l * HH, ln_g + l * HH, ln_b + l * HH,
          h, h, hb, nullptr, nullptr, nullptr, nullptr, nullptr);
    else
      k_gin<false, true><<<gblocks, 256, 0, stream>>>(
          mb1, g1T + (size_t)l * HH * HH, gin_b1 + l * HH, gin_lng + l * HH, gin_lnb + l * HH,
          g2T + (size_t)l * HH * HH, gin_b2 + l * HH, ln_g + l * HH, ln_b + l * HH,
          h, nullptr, hb, aW1T, att_b1, att_W2, att_b2, logitsT);
  }

  k_smax1<<<dim3(128, 4), 256, 0, stream>>>(logitsT, pmax, psum);
  k_smax2<<<4, 128, 0, stream>>>(pmax, psum, gs);
  k_attnz<<<(NN + 127) / 128, 256, 0, stream>>>(logitsT, gs, hb, out + 7, z);
  k_cls<<<1, 256, 0, stream>>>(z, Wc1, bc1, lnc1_g, lnc1_b, Wc2, bc2, lnc2_g, lnc2_b,
                               Wc3, bc3, out);
}